// Round 9
// baseline (221.913 us; speedup 1.0000x reference)
//
#include <hip/hip_runtime.h>
#include <stdint.h>

#define SS 64
#define NN 4096
#define FF 32
#define HH 64
#define OO 2
#define G3 192

typedef float f32x4 __attribute__((ext_vector_type(4)));
typedef short bf16x8 __attribute__((ext_vector_type(8)));
typedef unsigned short u16x8 __attribute__((ext_vector_type(8)));

#define AS1 __attribute__((address_space(1)))
#define AS3 __attribute__((address_space(3)))

__device__ __forceinline__ unsigned short f2bf(float f) {
  union { float f; uint32_t u; } v; v.f = f;
  uint32_t u = v.u;
  uint32_t r = (u + 0x7FFFu + ((u >> 16) & 1u)) >> 16;
  return (unsigned short)r;
}
__device__ __forceinline__ float bf2f(unsigned short s) {
  union { uint32_t u; float f; } v; v.u = ((uint32_t)s) << 16;
  return v.f;
}

// ---------------- prep: adj f32->bf16 + rowsum (blocks 0..4095, 1 row each)
// ----------------       x transpose -> Xt[s*32+f][j] bf16 (blocks 4096..8191)
__global__ __launch_bounds__(256) void k_prep(const float* __restrict__ adj,
                                              unsigned short* __restrict__ adjb,
                                              float* __restrict__ rowsum,
                                              const float* __restrict__ x,
                                              unsigned short* __restrict__ Xt) {
  __shared__ float xl[64][33];
  __shared__ float ps[4];
  int tid = threadIdx.x;
  if (blockIdx.x < 4096) {
    int row = blockIdx.x;
    const float4* src = (const float4*)(adj + (size_t)row * 4096);
    ushort4* dst = (ushort4*)(adjb + (size_t)row * 4096);
    float sum = 0.f;
    #pragma unroll
    for (int q = 0; q < 4; ++q) {
      int idx = q * 256 + tid;
      float4 v = src[idx];
      ushort4 r;
      r.x = f2bf(v.x); r.y = f2bf(v.y); r.z = f2bf(v.z); r.w = f2bf(v.w);
      dst[idx] = r;
      sum += (v.x + v.y) + (v.z + v.w);
    }
    #pragma unroll
    for (int off = 1; off < 64; off <<= 1) sum += __shfl_xor(sum, off);
    if ((tid & 63) == 0) ps[tid >> 6] = sum;
    __syncthreads();
    if (tid == 0) rowsum[row] = (ps[0] + ps[1]) + (ps[2] + ps[3]);
    return;
  }
  int bs = blockIdx.x - 4096;
  int s = bs >> 6, jb = (bs & 63) << 6;
  const float4* xg = (const float4*)(x + ((size_t)s * NN + jb) * FF);
  #pragma unroll
  for (int ii = 0; ii < 2; ++ii) {
    int idx = tid + ii * 256;
    float4 v = xg[idx];
    int j = idx >> 3, f = (idx & 7) << 2;
    xl[j][f] = v.x; xl[j][f + 1] = v.y; xl[j][f + 2] = v.z; xl[j][f + 3] = v.w;
  }
  __syncthreads();
  int f = tid >> 3, jc = tid & 7;
  u16x8 ov;
  #pragma unroll
  for (int jj = 0; jj < 8; ++jj) ov[jj] = (short)f2bf(xl[jc * 8 + jj][f]);
  *(u16x8*)(Xt + (size_t)(s * 32 + f) * 4096 + jb + jc * 8) = ov;
}

// =====================================================================
// GEMM-AX fused: C1 = adj @ Xt^T (round-6 proven K-loop: single frag
// set, triple-buffered LDS, vmcnt(6), 1 barrier/K-tile), then in-block
// GCN layers with CHUNKED h-accumulation (4x16) to stay under the
// VGPR grant (round-8 spill fix): h = relu(C1@W1 + rowsum*b1);
// B2t = h@W2 + b2.
// =====================================================================
#define SBAR()   asm volatile("s_barrier" ::: "memory")
#define VMCNT6() asm volatile("s_waitcnt vmcnt(6)" ::: "memory")
#define VMCNT0() asm volatile("s_waitcnt vmcnt(0)" ::: "memory")

__global__ __launch_bounds__(512, 2) void k_gemmAX(
    const unsigned short* __restrict__ A,
    const unsigned short* __restrict__ B,
    const float* __restrict__ rowsum,
    const float* __restrict__ W1f,
    const float* __restrict__ b1f,
    const float* __restrict__ W2f,
    const float* __restrict__ b2f,
    unsigned short* __restrict__ B2t) {
  __shared__ __align__(16) char lds[147456];
  __shared__ float w1l[2048];
  __shared__ float w2l[128];
  __shared__ float b1l[64];
  __shared__ float b2l[2];
  const int tid = threadIdx.x;
  const int wid = tid >> 6, l = tid & 63;
  const int wr2 = wid >> 2, wc2 = wid & 3;

  // stage small weights (drained by the first __syncthreads)
  *(float4*)&w1l[tid * 4] = ((const float4*)W1f)[tid];
  if (tid < 32) *(float4*)&w2l[tid * 4] = ((const float4*)W2f)[tid];
  if (tid < 16) *(float4*)&b1l[tid * 4] = ((const float4*)b1f)[tid];
  if (tid < 2) b2l[tid] = b2f[tid];
  __syncthreads();

  int bid = blockIdx.x;
  int swz = (bid & 7) * 32 + (bid >> 3);   // bijective XCD swizzle (256 = 8*32)
  const int i0 = (swz >> 3) * 128;         // 32 i-tiles
  const int c0 = (swz & 7) * 256;          // 8 sf-tiles

  const int aOffC = wr2 * 8192 + (l & 15) * 128;
  const int bOffC = 16384 + wc2 * 8192 + (l & 15) * 128;
  const int colKK0 = (((l >> 4) * 16)) ^ ((l & 7) << 4);
  const int colKK1 = ((64 + (l >> 4) * 16)) ^ ((l & 7) << 4);

  const int srow = tid >> 3;
  const int scol = (((tid & 7) ^ (srow & 7)) << 4);
  const char* gA = (const char*)A + (size_t)(i0 + srow) * 8192 + scol;
  const char* gB = (const char*)B + (size_t)(c0 + srow) * 8192 + scol;
  char* ldsW = (char*)lds + wid * 1024;
  const char* ldsR = (const char*)lds;

  f32x4 acc[4][4];
  #pragma unroll
  for (int m = 0; m < 4; ++m)
    #pragma unroll
    for (int n = 0; n < 4; ++n) acc[m][n] = {0.f, 0.f, 0.f, 0.f};

  bf16x8 af[4][2], bfr[2][2];

#define STAGE6(K2, BOFS) do {                                                        \
    __builtin_amdgcn_global_load_lds((const AS1 void*)(gA + (K2)),                   \
        (AS3 void*)(ldsW + (BOFS)), 16, 0, 0);                                       \
    __builtin_amdgcn_global_load_lds((const AS1 void*)(gA + 524288 + (K2)),          \
        (AS3 void*)(ldsW + (BOFS) + 8192), 16, 0, 0);                                \
    __builtin_amdgcn_global_load_lds((const AS1 void*)(gB + (K2)),                   \
        (AS3 void*)(ldsW + (BOFS) + 16384), 16, 0, 0);                               \
    __builtin_amdgcn_global_load_lds((const AS1 void*)(gB + 524288 + (K2)),          \
        (AS3 void*)(ldsW + (BOFS) + 24576), 16, 0, 0);                               \
    __builtin_amdgcn_global_load_lds((const AS1 void*)(gB + 1048576 + (K2)),         \
        (AS3 void*)(ldsW + (BOFS) + 32768), 16, 0, 0);                               \
    __builtin_amdgcn_global_load_lds((const AS1 void*)(gB + 1572864 + (K2)),         \
        (AS3 void*)(ldsW + (BOFS) + 40960), 16, 0, 0);                               \
  } while (0)

#define READ_AF(BOFS) do {                                                           \
    _Pragma("unroll")                                                                \
    for (int _m = 0; _m < 4; ++_m) {                                                 \
      const char* _p = ldsR + (BOFS) + aOffC + _m * 2048;                            \
      af[_m][0] = *(const bf16x8*)(_p + colKK0);                                     \
      af[_m][1] = *(const bf16x8*)(_p + colKK1);                                     \
    } } while (0)

#define READ_B(BOFS, NH) do {                                                        \
    _Pragma("unroll")                                                                \
    for (int _j = 0; _j < 2; ++_j) {                                                 \
      const char* _p = ldsR + (BOFS) + bOffC + ((NH) * 2 + _j) * 2048;               \
      bfr[_j][0] = *(const bf16x8*)(_p + colKK0);                                    \
      bfr[_j][1] = *(const bf16x8*)(_p + colKK1);                                    \
    } } while (0)

#define MFMA_H(NH) do {                                                              \
    __builtin_amdgcn_s_setprio(1);                                                   \
    _Pragma("unroll")                                                                \
    for (int _kk = 0; _kk < 2; ++_kk)                                                \
      _Pragma("unroll")                                                              \
      for (int _m = 0; _m < 4; ++_m)                                                 \
        _Pragma("unroll")                                                            \
        for (int _j = 0; _j < 2; ++_j)                                               \
          acc[_m][(NH) * 2 + _j] = __builtin_amdgcn_mfma_f32_16x16x32_bf16(          \
              af[_m][_kk], bfr[_j][_kk], acc[_m][(NH) * 2 + _j], 0, 0, 0);           \
    __builtin_amdgcn_s_setprio(0);                                                   \
  } while (0)

  STAGE6(0, 0);
  STAGE6(128, 49152);
  VMCNT6();
  SBAR();

  int bofs = 0, bofs2 = 98304;
  for (int kt = 0; kt < 64; ++kt) {
    const int k2 = ((kt + 2) & 63) * 128;
    READ_AF(bofs);
    READ_B(bofs, 0);
    STAGE6(k2, bofs2);
    MFMA_H(0);
    READ_B(bofs, 1);
    MFMA_H(1);
    VMCNT6();
    SBAR();
    bofs = (bofs == 98304) ? 0 : bofs + 49152;
    bofs2 = (bofs2 == 98304) ? 0 : bofs2 + 49152;
  }
  VMCNT0();
  __syncthreads();   // LDS now reusable

  // ---- fused GCN output epilogue (chunked h: max live ~60 regs) ----
  unsigned short* C1L = (unsigned short*)lds;
  {
    const int rb = wr2 * 64 + (l >> 4) * 4;
    const int cbL = wc2 * 64 + (l & 15);
    #pragma unroll
    for (int m = 0; m < 4; ++m)
      #pragma unroll
      for (int r = 0; r < 4; ++r) {
        const int row = rb + m * 16 + r;
        #pragma unroll
        for (int n = 0; n < 4; ++n)
          C1L[row * 264 + cbL + n * 16] = f2bf(acc[m][n][r]);
      }
  }
  __syncthreads();
  #pragma unroll
  for (int pp = 0; pp < 2; ++pp) {
    const int p = tid + pp * 512;
    const int s = p >> 7, il = p & 127;
    const u16x8* cp = (const u16x8*)(C1L + il * 264 + s * 32);
    float cf[32];
    #pragma unroll
    for (int q = 0; q < 4; ++q) {
      u16x8 v = cp[q];
      #pragma unroll
      for (int e = 0; e < 8; ++e) cf[q * 8 + e] = bf2f((unsigned short)v[e]);
    }
    const float rs = rowsum[i0 + il];
    const f32x4* b1v = (const f32x4*)b1l;
    float o0 = b2l[0], o1 = b2l[1];
    #pragma unroll
    for (int hc = 0; hc < 4; ++hc) {
      f32x4 h4[4];
      #pragma unroll
      for (int t = 0; t < 4; ++t) h4[t] = rs * b1v[hc * 4 + t];
      #pragma unroll
      for (int f = 0; f < 32; ++f) {
        const float c = cf[f];
        const f32x4* wrow = (const f32x4*)(w1l + f * 64);
        #pragma unroll
        for (int t = 0; t < 4; ++t) h4[t] += c * wrow[hc * 4 + t];
      }
      #pragma unroll
      for (int t = 0; t < 4; ++t)
        #pragma unroll
        for (int e = 0; e < 4; ++e) {
          float a = h4[t][e];
          a = a > 0.f ? a : 0.f;
          const int hidx = (hc * 4 + t) * 4 + e;
          o0 += a * w2l[hidx * 2];
          o1 += a * w2l[hidx * 2 + 1];
        }
    }
    B2t[(size_t)(((c0 >> 5) + s) * 2 + 0) * 4096 + i0 + il] = f2bf(o0);
    B2t[(size_t)(((c0 >> 5) + s) * 2 + 1) * 4096 + i0 + il] = f2bf(o1);
  }
}

// ---------------- shared MFMA GEMM core (m97-style, used by gemm2) ----------------
__device__ __forceinline__ void gemm_core(const unsigned short* __restrict__ A,
                                          const unsigned short* __restrict__ B,
                                          int i0, int c0, int k0base, int ksteps,
                                          f32x4 acc[4][4],
                                          unsigned short* Als, unsigned short* Bls) {
  const int tid = threadIdx.x;
  const int w = tid >> 6, l = tid & 63;
  const int srow = (l >> 2);
  const int scol = (l & 3) * 16;
  for (int kt = 0; kt < ksteps; ++kt) {
    int k0 = k0base + kt * 32;
    #pragma unroll
    for (int q = 0; q < 2; ++q) {
      int r = w * 32 + q * 16 + srow;
      const char* ga = (const char*)(A + (size_t)(i0 + r) * 4096 + k0) + scol;
      __builtin_amdgcn_global_load_lds(
          (const AS1 void*)ga,
          (AS3 void*)((char*)Als + w * 2048 + q * 1024), 16, 0, 0);
      const char* gb = (const char*)(B + (size_t)(c0 + r) * 4096 + k0) + scol;
      __builtin_amdgcn_global_load_lds(
          (const AS1 void*)gb,
          (AS3 void*)((char*)Bls + w * 2048 + q * 1024), 16, 0, 0);
    }
    __syncthreads();
    const int wr = w >> 1, wc = w & 1;
    bf16x8 af[4], bff[4];
    #pragma unroll
    for (int m = 0; m < 4; ++m)
      af[m] = *(const bf16x8*)(Als + (wr * 64 + m * 16 + (l & 15)) * 32 + (l >> 4) * 8);
    #pragma unroll
    for (int n = 0; n < 4; ++n)
      bff[n] = *(const bf16x8*)(Bls + (wc * 64 + n * 16 + (l & 15)) * 32 + (l >> 4) * 8);
    #pragma unroll
    for (int m = 0; m < 4; ++m)
      #pragma unroll
      for (int n = 0; n < 4; ++n)
        acc[m][n] = __builtin_amdgcn_mfma_f32_16x16x32_bf16(af[m], bff[n], acc[m][n], 0, 0, 0);
    __syncthreads();
  }
}

// ---------------- GEMM2 split-K: Gp[ks][i][c2] partial f32 ----------------
__global__ __launch_bounds__(256) void k_gemm2(const unsigned short* __restrict__ A,
                                               const unsigned short* __restrict__ B,
                                               float* __restrict__ Gp) {
  __shared__ unsigned short Als[128 * 32], Bls[128 * 32];
  int id = blockIdx.x;
  int bi = id & 31, ks = id >> 5;
  int i0 = bi * 128;
  f32x4 acc[4][4];
  #pragma unroll
  for (int m = 0; m < 4; ++m)
    #pragma unroll
    for (int n = 0; n < 4; ++n) acc[m][n] = {0.f, 0.f, 0.f, 0.f};
  gemm_core(A, B, i0, 0, ks * 512, 16, acc, Als, Bls);
  float* outp = Gp + (size_t)ks * 4096 * 128;
  int l = threadIdx.x & 63, w = threadIdx.x >> 6;
  int wr = w >> 1, wc = w & 1;
  int rbase = i0 + wr * 64 + (l >> 4) * 4;
  int cbase = wc * 64 + (l & 15);
  #pragma unroll
  for (int m = 0; m < 4; ++m)
    #pragma unroll
    for (int n = 0; n < 4; ++n)
      #pragma unroll
      for (int r = 0; r < 4; ++r)
        outp[(size_t)(rbase + m * 16 + r) * 128 + cbase + n * 16] = acc[m][n][r];
}

// ---------------- reduce split-K + log_softmax -> R[s][i*2+o] f32 ----------------
__global__ __launch_bounds__(256) void k_lsm(const float* __restrict__ Gp,
                                             float* __restrict__ Rm) {
  __shared__ float Gacc[32][130];
  int i0 = blockIdx.x * 32;
  int tid = threadIdx.x;
  float4 v[4];
  #pragma unroll
  for (int i = 0; i < 4; ++i) v[i] = {0.f, 0.f, 0.f, 0.f};
  for (int ks = 0; ks < 8; ++ks) {
    const float4* gp4 = ((const float4*)Gp) + (size_t)ks * 131072 + (size_t)i0 * 32;
    #pragma unroll
    for (int i = 0; i < 4; ++i) {
      float4 t = gp4[tid + i * 256];
      v[i].x += t.x; v[i].y += t.y; v[i].z += t.z; v[i].w += t.w;
    }
  }
  #pragma unroll
  for (int i = 0; i < 4; ++i) {
    int f4i = tid + i * 256, row = f4i >> 5, c = (f4i & 31) * 4;
    Gacc[row][c] = v[i].x; Gacc[row][c + 1] = v[i].y;
    Gacc[row][c + 2] = v[i].z; Gacc[row][c + 3] = v[i].w;
  }
  __syncthreads();
  #pragma unroll
  for (int j = 0; j < 8; ++j) {
    int p = j * 256 + tid;
    int ii = p & 31, s = p >> 5;
    float g0 = Gacc[ii][s * 2], g1 = Gacc[ii][s * 2 + 1];
    float m = fmaxf(g0, g1);
    float lse = m + logf(expf(g0 - m) + expf(g1 - m));
    float2 o_; o_.x = g0 - lse; o_.y = g1 - lse;
    *((float2*)(Rm + (size_t)s * 8192 + (size_t)(i0 + ii) * 2)) = o_;
  }
}

// ---------------- gi0 partial: part[ks][t][g] = R[t] . Wih0[g] over c-range ----------------
__global__ __launch_bounds__(256) void k_gi0(const float* __restrict__ Rm,
                                             const float* __restrict__ Wih0,
                                             float* __restrict__ part) {
  __shared__ float4 Wl[4 * 128];
  int gb = blockIdx.x % 48, ks = blockIdx.x / 48;
  int c0 = ks * 512;
  int tid = threadIdx.x;
  #pragma unroll
  for (int i = 0; i < 2; ++i) {
    int idx = tid + i * 256;
    int g = idx >> 7, c4 = idx & 127;
    Wl[g * 128 + c4] = ((const float4*)(Wih0 + (size_t)(gb * 4 + g) * 8192 + c0))[c4];
  }
  __syncthreads();
  int w = tid >> 6, lane = tid & 63;
  for (int pass = 0; pass < 16; ++pass) {
    int t = pass * 4 + w;
    float a0 = 0.f, a1 = 0.f, a2 = 0.f, a3 = 0.f;
    const float4* rg = (const float4*)(Rm + (size_t)t * 8192 + c0);
    #pragma unroll
    for (int i = 0; i < 2; ++i) {
      int c4 = i * 64 + lane;
      float4 r4 = rg[c4];
      float4 w0 = Wl[c4], w1 = Wl[128 + c4], w2 = Wl[256 + c4], w3 = Wl[384 + c4];
      a0 += r4.x * w0.x + r4.y * w0.y + r4.z * w0.z + r4.w * w0.w;
      a1 += r4.x * w1.x + r4.y * w1.y + r4.z * w1.z + r4.w * w1.w;
      a2 += r4.x * w2.x + r4.y * w2.y + r4.z * w2.z + r4.w * w2.w;
      a3 += r4.x * w3.x + r4.y * w3.y + r4.z * w3.z + r4.w * w3.w;
    }
    #pragma unroll
    for (int off = 1; off < 64; off <<= 1) {
      a0 += __shfl_xor(a0, off);
      a1 += __shfl_xor(a1, off);
      a2 += __shfl_xor(a2, off);
      a3 += __shfl_xor(a3, off);
    }
    if (lane == 0) {
      float4 o_; o_.x = a0; o_.y = a1; o_.z = a2; o_.w = a3;
      *((float4*)(part + ((size_t)ks * 64 + t) * 192 + gb * 4)) = o_;
    }
  }
}

__global__ __launch_bounds__(256) void k_gi0red(const float* __restrict__ part,
                                                const float* __restrict__ bih0,
                                                float* __restrict__ gi0) {
  int idx = blockIdx.x * 256 + threadIdx.x;
  if (idx < 12288) {
    float s_ = bih0[idx % 192];
    for (int ks = 0; ks < 16; ++ks) s_ += part[ks * 12288 + idx];
    gi0[idx] = s_;
  }
}

// =====================================================================
// MFMA GRU (unchanged — proven round 6)
// =====================================================================
__device__ __forceinline__ float fsigm(float x) {
  return __builtin_amdgcn_rcpf(1.f + __expf(-x));
}
__device__ __forceinline__ float ftanh(float x) {
  return 1.f - 2.f * __builtin_amdgcn_rcpf(1.f + __expf(2.f * x));
}

__global__ __launch_bounds__(384) void k_gru(const float* __restrict__ gi0,
                                             const float* __restrict__ Whh0,
                                             const float* __restrict__ bhh0,
                                             const float* __restrict__ Wih1,
                                             const float* __restrict__ Whh1,
                                             const float* __restrict__ bih1,
                                             const float* __restrict__ bhh1,
                                             float* __restrict__ out) {
  __shared__ float gil[64][192];
  __shared__ float gout[576];
  __shared__ __align__(16) unsigned short hv[2][64];
  const int tid = threadIdx.x;
  const int w = tid >> 6, l = tid & 63;
  const int matw = w >> 1, half = w & 1;
  const float* Wm = (matw == 0) ? Whh0 : (matw == 1 ? Wih1 : Whh1);
  const int mi = (matw == 2) ? 1 : 0;

  bf16x8 afr[6][2];
  #pragma unroll
  for (int rbi = 0; rbi < 6; ++rbi) {
    int g = (half * 6 + rbi) * 16 + (l & 15);
    #pragma unroll
    for (int kh = 0; kh < 2; ++kh) {
      int k0 = kh * 32 + (l >> 4) * 8;
      const float4* src = (const float4*)(Wm + (size_t)g * 64 + k0);
      float4 v0 = src[0], v1 = src[1];
      bf16x8 a;
      a[0] = (short)f2bf(v0.x); a[1] = (short)f2bf(v0.y);
      a[2] = (short)f2bf(v0.z); a[3] = (short)f2bf(v0.w);
      a[4] = (short)f2bf(v1.x); a[5] = (short)f2bf(v1.y);
      a[6] = (short)f2bf(v1.z); a[7] = (short)f2bf(v1.w);
      afr[rbi][kh] = a;
    }
  }
  {
    float4* gf = (float4*)&gil[0][0];
    const float4* gs = (const float4*)gi0;
    #pragma unroll
    for (int i = 0; i < 8; ++i) gf[i * 384 + tid] = gs[i * 384 + tid];
  }
  if (tid < 128) hv[tid >> 6][tid & 63] = 0;

  float hreg = 0.f;
  float bR = 0.f, bZ = 0.f, bNa = 0.f, bNb = 0.f;
  if (tid < 64) {
    bR = bhh0[tid]; bZ = bhh0[64 + tid]; bNa = bhh0[128 + tid];
  } else if (tid < 128) {
    int g = tid - 64;
    bR = bih1[g] + bhh1[g];
    bZ = bih1[64 + g] + bhh1[64 + g];
    bNa = bih1[128 + g];
    bNb = bhh1[128 + g];
  }
  asm volatile("s_waitcnt lgkmcnt(0)\n\ts_barrier" ::: "memory");

  const int gwb = matw * 192 + half * 96 + (l >> 4) * 4;
  const f32x4 zacc = {0.f, 0.f, 0.f, 0.f};

  for (int i = 0; i <= 64; ++i) {
    bf16x8 b0 = *(const bf16x8*)&hv[mi][(l >> 4) * 8];
    bf16x8 b1 = *(const bf16x8*)&hv[mi][32 + (l >> 4) * 8];
    #pragma unroll
    for (int rbi = 0; rbi < 6; ++rbi) {
      f32x4 a_ = __builtin_amdgcn_mfma_f32_16x16x32_bf16(afr[rbi][0], b0, zacc, 0, 0, 0);
      a_ = __builtin_amdgcn_mfma_f32_16x16x32_bf16(afr[rbi][1], b1, a_, 0, 0, 0);
      if (!(l & 15)) *(f32x4*)&gout[gwb + rbi * 16] = a_;
    }
    asm volatile("s_waitcnt lgkmcnt(0)\n\ts_barrier" ::: "memory");
    if (tid < 64) {
      if (i < 64) {
        float r = fsigm(gil[i][tid] + gout[tid] + bR);
        float z = fsigm(gil[i][64 + tid] + gout[64 + tid] + bZ);
        float n = ftanh(gil[i][128 + tid] + r * (gout[128 + tid] + bNa));
        hreg = (1.f - z) * n + z * hreg;
        hv[0][tid] = f2bf(hreg);
      }
    } else if (tid < 128 && i > 0) {
      int g = tid - 64;
      float r = fsigm(gout[192 + g] + gout[384 + g] + bR);
      float z = fsigm(gout[256 + g] + gout[448 + g] + bZ);
      float n = ftanh((gout[320 + g] + bNa) + r * (gout[512 + g] + bNb));
      hreg = (1.f - z) * n + z * hreg;
      hv[1][g] = f2bf(hreg);
      out[(i - 1) * 64 + g] = hreg;
    }
    asm volatile("s_waitcnt lgkmcnt(0)\n\ts_barrier" ::: "memory");
  }
  if (tid < 64) out[4096 + tid] = hreg;
  else if (tid < 128) out[4096 + 64 + (tid - 64)] = hreg;
}

extern "C" void kernel_launch(void* const* d_in, const int* in_sizes, int n_in,
                              void* d_out, int out_size, void* d_ws, size_t ws_size,
                              hipStream_t stream) {
  const float* x    = (const float*)d_in[0];
  const float* adj  = (const float*)d_in[1];
  const float* W1   = (const float*)d_in[2];
  const float* b1   = (const float*)d_in[3];
  const float* W2   = (const float*)d_in[4];
  const float* b2   = (const float*)d_in[5];
  const float* Wih0 = (const float*)d_in[6];
  const float* Whh0 = (const float*)d_in[7];
  const float* bih0 = (const float*)d_in[8];
  const float* bhh0 = (const float*)d_in[9];
  const float* Wih1 = (const float*)d_in[10];
  const float* Whh1 = (const float*)d_in[11];
  const float* bih1 = (const float*)d_in[12];
  const float* bhh1 = (const float*)d_in[13];
  float* out = (float*)d_out;

  char* ws = (char*)d_ws;
  unsigned short* adjb = (unsigned short*)ws;                      // 33.55MB
  unsigned short* Xt   = (unsigned short*)(ws + 33554432);         // 16.78MB
  float* rowsum        = (float*)(ws + 67108864);                  // 16KB
  float* Gp            = (float*)(ws + 67125248);                  // 16.78MB
  float* Rm            = (float*)(ws + 83902464);                  // 2MB
  float* part          = (float*)(ws + 85999616);                  // 768KB
  float* gi0           = (float*)(ws + 86786048);                  // 48KB
  unsigned short* B2t  = (unsigned short*)(ws + 86835200);         // 1MB

  k_prep<<<8192, 256, 0, stream>>>(adj, adjb, rowsum, x, Xt);
  k_gemmAX<<<256, 512, 0, stream>>>(adjb, Xt, rowsum, W1, b1, W2, b2, B2t);
  k_gemm2<<<256, 256, 0, stream>>>(adjb, B2t, Gp);
  k_lsm<<<128, 256, 0, stream>>>(Gp, Rm);
  k_gi0<<<768, 256, 0, stream>>>(Rm, Wih0, part);
  k_gi0red<<<48, 256, 0, stream>>>(part, bih0, gi0);
  k_gru<<<1, 384, 0, stream>>>(gi0, Whh0, bhh0, Wih1, Whh1, bih1, bhh1, out);
}

// Round 10
// 213.780 us; speedup vs baseline: 1.0380x; 1.0380x over previous
//
#include <hip/hip_runtime.h>
#include <stdint.h>

#define SS 64
#define NN 4096
#define FF 32
#define HH 64
#define OO 2
#define G3 192

typedef float f32x4 __attribute__((ext_vector_type(4)));
typedef short bf16x8 __attribute__((ext_vector_type(8)));
typedef unsigned short u16x8 __attribute__((ext_vector_type(8)));

#define AS1 __attribute__((address_space(1)))
#define AS3 __attribute__((address_space(3)))

__device__ __forceinline__ unsigned short f2bf(float f) {
  union { float f; uint32_t u; } v; v.f = f;
  uint32_t u = v.u;
  uint32_t r = (u + 0x7FFFu + ((u >> 16) & 1u)) >> 16;
  return (unsigned short)r;
}
__device__ __forceinline__ float bf2f(unsigned short s) {
  union { uint32_t u; float f; } v; v.u = ((uint32_t)s) << 16;
  return v.f;
}

// ---------------- prep: adj f32->bf16 + rowsum (blocks 0..4095, 1 row each)
// ----------------       x transpose -> Xt[s*32+f][j] bf16 (blocks 4096..8191)
__global__ __launch_bounds__(256) void k_prep(const float* __restrict__ adj,
                                              unsigned short* __restrict__ adjb,
                                              float* __restrict__ rowsum,
                                              const float* __restrict__ x,
                                              unsigned short* __restrict__ Xt) {
  __shared__ float xl[64][33];
  __shared__ float ps[4];
  int tid = threadIdx.x;
  if (blockIdx.x < 4096) {
    int row = blockIdx.x;
    const float4* src = (const float4*)(adj + (size_t)row * 4096);
    ushort4* dst = (ushort4*)(adjb + (size_t)row * 4096);
    float sum = 0.f;
    #pragma unroll
    for (int q = 0; q < 4; ++q) {
      int idx = q * 256 + tid;
      float4 v = src[idx];
      ushort4 r;
      r.x = f2bf(v.x); r.y = f2bf(v.y); r.z = f2bf(v.z); r.w = f2bf(v.w);
      dst[idx] = r;
      sum += (v.x + v.y) + (v.z + v.w);
    }
    #pragma unroll
    for (int off = 1; off < 64; off <<= 1) sum += __shfl_xor(sum, off);
    if ((tid & 63) == 0) ps[tid >> 6] = sum;
    __syncthreads();
    if (tid == 0) rowsum[row] = (ps[0] + ps[1]) + (ps[2] + ps[3]);
    return;
  }
  int bs = blockIdx.x - 4096;
  int s = bs >> 6, jb = (bs & 63) << 6;
  const float4* xg = (const float4*)(x + ((size_t)s * NN + jb) * FF);
  #pragma unroll
  for (int ii = 0; ii < 2; ++ii) {
    int idx = tid + ii * 256;
    float4 v = xg[idx];
    int j = idx >> 3, f = (idx & 7) << 2;
    xl[j][f] = v.x; xl[j][f + 1] = v.y; xl[j][f + 2] = v.z; xl[j][f + 3] = v.w;
  }
  __syncthreads();
  int f = tid >> 3, jc = tid & 7;
  u16x8 ov;
  #pragma unroll
  for (int jj = 0; jj < 8; ++jj) ov[jj] = (short)f2bf(xl[jc * 8 + jj][f]);
  *(u16x8*)(Xt + (size_t)(s * 32 + f) * 4096 + jb + jc * 8) = ov;
}

// =====================================================================
// GEMM-AX fused: C1 = adj @ Xt^T (round-6 proven K-loop) + in-block GCN
// layers: h = relu(C1@W1 + rowsum*b1); B2t = h@W2 + b2.
// __launch_bounds__(512, 1): LDS already limits to 1 block/CU (8 waves),
// which supports up to 256 VGPR/wave — remove the 128-reg cap that was
// spilling the epilogue (rounds 7-9: WRITE_SIZE 38-80MB scratch).
// =====================================================================
#define SBAR()   asm volatile("s_barrier" ::: "memory")
#define VMCNT6() asm volatile("s_waitcnt vmcnt(6)" ::: "memory")
#define VMCNT0() asm volatile("s_waitcnt vmcnt(0)" ::: "memory")

__global__ __launch_bounds__(512, 1) void k_gemmAX(
    const unsigned short* __restrict__ A,
    const unsigned short* __restrict__ B,
    const float* __restrict__ rowsum,
    const float* __restrict__ W1f,
    const float* __restrict__ b1f,
    const float* __restrict__ W2f,
    const float* __restrict__ b2f,
    unsigned short* __restrict__ B2t) {
  __shared__ __align__(16) char lds[147456];
  __shared__ float w1l[2048];
  __shared__ float w2l[128];
  __shared__ float b1l[64];
  __shared__ float b2l[2];
  const int tid = threadIdx.x;
  const int wid = tid >> 6, l = tid & 63;
  const int wr2 = wid >> 2, wc2 = wid & 3;

  // stage small weights (drained by the first __syncthreads)
  *(float4*)&w1l[tid * 4] = ((const float4*)W1f)[tid];
  if (tid < 32) *(float4*)&w2l[tid * 4] = ((const float4*)W2f)[tid];
  if (tid < 16) *(float4*)&b1l[tid * 4] = ((const float4*)b1f)[tid];
  if (tid < 2) b2l[tid] = b2f[tid];
  __syncthreads();

  int bid = blockIdx.x;
  int swz = (bid & 7) * 32 + (bid >> 3);   // bijective XCD swizzle (256 = 8*32)
  const int i0 = (swz >> 3) * 128;         // 32 i-tiles
  const int c0 = (swz & 7) * 256;          // 8 sf-tiles

  const int aOffC = wr2 * 8192 + (l & 15) * 128;
  const int bOffC = 16384 + wc2 * 8192 + (l & 15) * 128;
  const int colKK0 = (((l >> 4) * 16)) ^ ((l & 7) << 4);
  const int colKK1 = ((64 + (l >> 4) * 16)) ^ ((l & 7) << 4);

  const int srow = tid >> 3;
  const int scol = (((tid & 7) ^ (srow & 7)) << 4);
  const char* gA = (const char*)A + (size_t)(i0 + srow) * 8192 + scol;
  const char* gB = (const char*)B + (size_t)(c0 + srow) * 8192 + scol;
  char* ldsW = (char*)lds + wid * 1024;
  const char* ldsR = (const char*)lds;

  f32x4 acc[4][4];
  #pragma unroll
  for (int m = 0; m < 4; ++m)
    #pragma unroll
    for (int n = 0; n < 4; ++n) acc[m][n] = {0.f, 0.f, 0.f, 0.f};

  bf16x8 af[4][2], bfr[2][2];

#define STAGE6(K2, BOFS) do {                                                        \
    __builtin_amdgcn_global_load_lds((const AS1 void*)(gA + (K2)),                   \
        (AS3 void*)(ldsW + (BOFS)), 16, 0, 0);                                       \
    __builtin_amdgcn_global_load_lds((const AS1 void*)(gA + 524288 + (K2)),          \
        (AS3 void*)(ldsW + (BOFS) + 8192), 16, 0, 0);                                \
    __builtin_amdgcn_global_load_lds((const AS1 void*)(gB + (K2)),                   \
        (AS3 void*)(ldsW + (BOFS) + 16384), 16, 0, 0);                               \
    __builtin_amdgcn_global_load_lds((const AS1 void*)(gB + 524288 + (K2)),          \
        (AS3 void*)(ldsW + (BOFS) + 24576), 16, 0, 0);                               \
    __builtin_amdgcn_global_load_lds((const AS1 void*)(gB + 1048576 + (K2)),         \
        (AS3 void*)(ldsW + (BOFS) + 32768), 16, 0, 0);                               \
    __builtin_amdgcn_global_load_lds((const AS1 void*)(gB + 1572864 + (K2)),         \
        (AS3 void*)(ldsW + (BOFS) + 40960), 16, 0, 0);                               \
  } while (0)

#define READ_AF(BOFS) do {                                                           \
    _Pragma("unroll")                                                                \
    for (int _m = 0; _m < 4; ++_m) {                                                 \
      const char* _p = ldsR + (BOFS) + aOffC + _m * 2048;                            \
      af[_m][0] = *(const bf16x8*)(_p + colKK0);                                     \
      af[_m][1] = *(const bf16x8*)(_p + colKK1);                                     \
    } } while (0)

#define READ_B(BOFS, NH) do {                                                        \
    _Pragma("unroll")                                                                \
    for (int _j = 0; _j < 2; ++_j) {                                                 \
      const char* _p = ldsR + (BOFS) + bOffC + ((NH) * 2 + _j) * 2048;               \
      bfr[_j][0] = *(const bf16x8*)(_p + colKK0);                                    \
      bfr[_j][1] = *(const bf16x8*)(_p + colKK1);                                    \
    } } while (0)

#define MFMA_H(NH) do {                                                              \
    __builtin_amdgcn_s_setprio(1);                                                   \
    _Pragma("unroll")                                                                \
    for (int _kk = 0; _kk < 2; ++_kk)                                                \
      _Pragma("unroll")                                                              \
      for (int _m = 0; _m < 4; ++_m)                                                 \
        _Pragma("unroll")                                                            \
        for (int _j = 0; _j < 2; ++_j)                                               \
          acc[_m][(NH) * 2 + _j] = __builtin_amdgcn_mfma_f32_16x16x32_bf16(          \
              af[_m][_kk], bfr[_j][_kk], acc[_m][(NH) * 2 + _j], 0, 0, 0);           \
    __builtin_amdgcn_s_setprio(0);                                                   \
  } while (0)

  STAGE6(0, 0);
  STAGE6(128, 49152);
  VMCNT6();
  SBAR();

  int bofs = 0, bofs2 = 98304;
  for (int kt = 0; kt < 64; ++kt) {
    const int k2 = ((kt + 2) & 63) * 128;
    READ_AF(bofs);
    READ_B(bofs, 0);
    STAGE6(k2, bofs2);
    MFMA_H(0);
    READ_B(bofs, 1);
    MFMA_H(1);
    VMCNT6();
    SBAR();
    bofs = (bofs == 98304) ? 0 : bofs + 49152;
    bofs2 = (bofs2 == 98304) ? 0 : bofs2 + 49152;
  }
  VMCNT0();
  __syncthreads();   // LDS now reusable

  // ---- fused GCN output epilogue ----
  unsigned short* C1L = (unsigned short*)lds;
  {
    const int rb = wr2 * 64 + (l >> 4) * 4;
    const int cbL = wc2 * 64 + (l & 15);
    #pragma unroll
    for (int m = 0; m < 4; ++m)
      #pragma unroll
      for (int r = 0; r < 4; ++r) {
        const int row = rb + m * 16 + r;
        #pragma unroll
        for (int n = 0; n < 4; ++n)
          C1L[row * 264 + cbL + n * 16] = f2bf(acc[m][n][r]);
      }
  }
  __syncthreads();
  #pragma unroll
  for (int pp = 0; pp < 2; ++pp) {
    const int p = tid + pp * 512;
    const int s = p >> 7, il = p & 127;
    const u16x8* cp = (const u16x8*)(C1L + il * 264 + s * 32);
    float cf[32];
    #pragma unroll
    for (int q = 0; q < 4; ++q) {
      u16x8 v = cp[q];
      #pragma unroll
      for (int e = 0; e < 8; ++e) cf[q * 8 + e] = bf2f((unsigned short)v[e]);
    }
    const float rs = rowsum[i0 + il];
    const f32x4* b1v = (const f32x4*)b1l;
    f32x4 h[16];
    #pragma unroll
    for (int t = 0; t < 16; ++t) h[t] = rs * b1v[t];
    #pragma unroll
    for (int f = 0; f < 32; ++f) {
      const float c = cf[f];
      const f32x4* wrow = (const f32x4*)(w1l + f * 64);
      #pragma unroll
      for (int t = 0; t < 16; ++t) h[t] += c * wrow[t];
    }
    float o0 = b2l[0], o1 = b2l[1];
    #pragma unroll
    for (int t = 0; t < 16; ++t)
      #pragma unroll
      for (int e = 0; e < 4; ++e) {
        float a = h[t][e];
        a = a > 0.f ? a : 0.f;
        o0 += a * w2l[(t * 4 + e) * 2];
        o1 += a * w2l[(t * 4 + e) * 2 + 1];
      }
    B2t[(size_t)(((c0 >> 5) + s) * 2 + 0) * 4096 + i0 + il] = f2bf(o0);
    B2t[(size_t)(((c0 >> 5) + s) * 2 + 1) * 4096 + i0 + il] = f2bf(o1);
  }
}

// ---------------- shared MFMA GEMM core (m97-style, used by gemm2) ----------------
__device__ __forceinline__ void gemm_core(const unsigned short* __restrict__ A,
                                          const unsigned short* __restrict__ B,
                                          int i0, int c0, int k0base, int ksteps,
                                          f32x4 acc[4][4],
                                          unsigned short* Als, unsigned short* Bls) {
  const int tid = threadIdx.x;
  const int w = tid >> 6, l = tid & 63;
  const int srow = (l >> 2);
  const int scol = (l & 3) * 16;
  for (int kt = 0; kt < ksteps; ++kt) {
    int k0 = k0base + kt * 32;
    #pragma unroll
    for (int q = 0; q < 2; ++q) {
      int r = w * 32 + q * 16 + srow;
      const char* ga = (const char*)(A + (size_t)(i0 + r) * 4096 + k0) + scol;
      __builtin_amdgcn_global_load_lds(
          (const AS1 void*)ga,
          (AS3 void*)((char*)Als + w * 2048 + q * 1024), 16, 0, 0);
      const char* gb = (const char*)(B + (size_t)(c0 + r) * 4096 + k0) + scol;
      __builtin_amdgcn_global_load_lds(
          (const AS1 void*)gb,
          (AS3 void*)((char*)Bls + w * 2048 + q * 1024), 16, 0, 0);
    }
    __syncthreads();
    const int wr = w >> 1, wc = w & 1;
    bf16x8 af[4], bff[4];
    #pragma unroll
    for (int m = 0; m < 4; ++m)
      af[m] = *(const bf16x8*)(Als + (wr * 64 + m * 16 + (l & 15)) * 32 + (l >> 4) * 8);
    #pragma unroll
    for (int n = 0; n < 4; ++n)
      bff[n] = *(const bf16x8*)(Bls + (wc * 64 + n * 16 + (l & 15)) * 32 + (l >> 4) * 8);
    #pragma unroll
    for (int m = 0; m < 4; ++m)
      #pragma unroll
      for (int n = 0; n < 4; ++n)
        acc[m][n] = __builtin_amdgcn_mfma_f32_16x16x32_bf16(af[m], bff[n], acc[m][n], 0, 0, 0);
    __syncthreads();
  }
}

// ---------------- GEMM2 split-K: Gp[ks][i][c2] partial f32 ----------------
__global__ __launch_bounds__(256) void k_gemm2(const unsigned short* __restrict__ A,
                                               const unsigned short* __restrict__ B,
                                               float* __restrict__ Gp) {
  __shared__ unsigned short Als[128 * 32], Bls[128 * 32];
  int id = blockIdx.x;
  int bi = id & 31, ks = id >> 5;
  int i0 = bi * 128;
  f32x4 acc[4][4];
  #pragma unroll
  for (int m = 0; m < 4; ++m)
    #pragma unroll
    for (int n = 0; n < 4; ++n) acc[m][n] = {0.f, 0.f, 0.f, 0.f};
  gemm_core(A, B, i0, 0, ks * 512, 16, acc, Als, Bls);
  float* outp = Gp + (size_t)ks * 4096 * 128;
  int l = threadIdx.x & 63, w = threadIdx.x >> 6;
  int wr = w >> 1, wc = w & 1;
  int rbase = i0 + wr * 64 + (l >> 4) * 4;
  int cbase = wc * 64 + (l & 15);
  #pragma unroll
  for (int m = 0; m < 4; ++m)
    #pragma unroll
    for (int n = 0; n < 4; ++n)
      #pragma unroll
      for (int r = 0; r < 4; ++r)
        outp[(size_t)(rbase + m * 16 + r) * 128 + cbase + n * 16] = acc[m][n][r];
}

// ---------------- reduce split-K + log_softmax -> R[s][i*2+o] f32 ----------------
__global__ __launch_bounds__(256) void k_lsm(const float* __restrict__ Gp,
                                             float* __restrict__ Rm) {
  __shared__ float Gacc[32][130];
  int i0 = blockIdx.x * 32;
  int tid = threadIdx.x;
  float4 v[4];
  #pragma unroll
  for (int i = 0; i < 4; ++i) v[i] = {0.f, 0.f, 0.f, 0.f};
  for (int ks = 0; ks < 8; ++ks) {
    const float4* gp4 = ((const float4*)Gp) + (size_t)ks * 131072 + (size_t)i0 * 32;
    #pragma unroll
    for (int i = 0; i < 4; ++i) {
      float4 t = gp4[tid + i * 256];
      v[i].x += t.x; v[i].y += t.y; v[i].z += t.z; v[i].w += t.w;
    }
  }
  #pragma unroll
  for (int i = 0; i < 4; ++i) {
    int f4i = tid + i * 256, row = f4i >> 5, c = (f4i & 31) * 4;
    Gacc[row][c] = v[i].x; Gacc[row][c + 1] = v[i].y;
    Gacc[row][c + 2] = v[i].z; Gacc[row][c + 3] = v[i].w;
  }
  __syncthreads();
  #pragma unroll
  for (int j = 0; j < 8; ++j) {
    int p = j * 256 + tid;
    int ii = p & 31, s = p >> 5;
    float g0 = Gacc[ii][s * 2], g1 = Gacc[ii][s * 2 + 1];
    float m = fmaxf(g0, g1);
    float lse = m + logf(expf(g0 - m) + expf(g1 - m));
    float2 o_; o_.x = g0 - lse; o_.y = g1 - lse;
    *((float2*)(Rm + (size_t)s * 8192 + (size_t)(i0 + ii) * 2)) = o_;
  }
}

// ---------------- gi0 partial: part[ks][t][g] = R[t] . Wih0[g] over c-range ----------------
__global__ __launch_bounds__(256) void k_gi0(const float* __restrict__ Rm,
                                             const float* __restrict__ Wih0,
                                             float* __restrict__ part) {
  __shared__ float4 Wl[4 * 128];
  int gb = blockIdx.x % 48, ks = blockIdx.x / 48;
  int c0 = ks * 512;
  int tid = threadIdx.x;
  #pragma unroll
  for (int i = 0; i < 2; ++i) {
    int idx = tid + i * 256;
    int g = idx >> 7, c4 = idx & 127;
    Wl[g * 128 + c4] = ((const float4*)(Wih0 + (size_t)(gb * 4 + g) * 8192 + c0))[c4];
  }
  __syncthreads();
  int w = tid >> 6, lane = tid & 63;
  for (int pass = 0; pass < 16; ++pass) {
    int t = pass * 4 + w;
    float a0 = 0.f, a1 = 0.f, a2 = 0.f, a3 = 0.f;
    const float4* rg = (const float4*)(Rm + (size_t)t * 8192 + c0);
    #pragma unroll
    for (int i = 0; i < 2; ++i) {
      int c4 = i * 64 + lane;
      float4 r4 = rg[c4];
      float4 w0 = Wl[c4], w1 = Wl[128 + c4], w2 = Wl[256 + c4], w3 = Wl[384 + c4];
      a0 += r4.x * w0.x + r4.y * w0.y + r4.z * w0.z + r4.w * w0.w;
      a1 += r4.x * w1.x + r4.y * w1.y + r4.z * w1.z + r4.w * w1.w;
      a2 += r4.x * w2.x + r4.y * w2.y + r4.z * w2.z + r4.w * w2.w;
      a3 += r4.x * w3.x + r4.y * w3.y + r4.z * w3.z + r4.w * w3.w;
    }
    #pragma unroll
    for (int off = 1; off < 64; off <<= 1) {
      a0 += __shfl_xor(a0, off);
      a1 += __shfl_xor(a1, off);
      a2 += __shfl_xor(a2, off);
      a3 += __shfl_xor(a3, off);
    }
    if (lane == 0) {
      float4 o_; o_.x = a0; o_.y = a1; o_.z = a2; o_.w = a3;
      *((float4*)(part + ((size_t)ks * 64 + t) * 192 + gb * 4)) = o_;
    }
  }
}

__global__ __launch_bounds__(256) void k_gi0red(const float* __restrict__ part,
                                                const float* __restrict__ bih0,
                                                float* __restrict__ gi0) {
  int idx = blockIdx.x * 256 + threadIdx.x;
  if (idx < 12288) {
    float s_ = bih0[idx % 192];
    for (int ks = 0; ks < 16; ++ks) s_ += part[ks * 12288 + idx];
    gi0[idx] = s_;
  }
}

// =====================================================================
// MFMA GRU (unchanged — proven round 6)
// =====================================================================
__device__ __forceinline__ float fsigm(float x) {
  return __builtin_amdgcn_rcpf(1.f + __expf(-x));
}
__device__ __forceinline__ float ftanh(float x) {
  return 1.f - 2.f * __builtin_amdgcn_rcpf(1.f + __expf(2.f * x));
}

__global__ __launch_bounds__(384) void k_gru(const float* __restrict__ gi0,
                                             const float* __restrict__ Whh0,
                                             const float* __restrict__ bhh0,
                                             const float* __restrict__ Wih1,
                                             const float* __restrict__ Whh1,
                                             const float* __restrict__ bih1,
                                             const float* __restrict__ bhh1,
                                             float* __restrict__ out) {
  __shared__ float gil[64][192];
  __shared__ float gout[576];
  __shared__ __align__(16) unsigned short hv[2][64];
  const int tid = threadIdx.x;
  const int w = tid >> 6, l = tid & 63;
  const int matw = w >> 1, half = w & 1;
  const float* Wm = (matw == 0) ? Whh0 : (matw == 1 ? Wih1 : Whh1);
  const int mi = (matw == 2) ? 1 : 0;

  bf16x8 afr[6][2];
  #pragma unroll
  for (int rbi = 0; rbi < 6; ++rbi) {
    int g = (half * 6 + rbi) * 16 + (l & 15);
    #pragma unroll
    for (int kh = 0; kh < 2; ++kh) {
      int k0 = kh * 32 + (l >> 4) * 8;
      const float4* src = (const float4*)(Wm + (size_t)g * 64 + k0);
      float4 v0 = src[0], v1 = src[1];
      bf16x8 a;
      a[0] = (short)f2bf(v0.x); a[1] = (short)f2bf(v0.y);
      a[2] = (short)f2bf(v0.z); a[3] = (short)f2bf(v0.w);
      a[4] = (short)f2bf(v1.x); a[5] = (short)f2bf(v1.y);
      a[6] = (short)f2bf(v1.z); a[7] = (short)f2bf(v1.w);
      afr[rbi][kh] = a;
    }
  }
  {
    float4* gf = (float4*)&gil[0][0];
    const float4* gs = (const float4*)gi0;
    #pragma unroll
    for (int i = 0; i < 8; ++i) gf[i * 384 + tid] = gs[i * 384 + tid];
  }
  if (tid < 128) hv[tid >> 6][tid & 63] = 0;

  float hreg = 0.f;
  float bR = 0.f, bZ = 0.f, bNa = 0.f, bNb = 0.f;
  if (tid < 64) {
    bR = bhh0[tid]; bZ = bhh0[64 + tid]; bNa = bhh0[128 + tid];
  } else if (tid < 128) {
    int g = tid - 64;
    bR = bih1[g] + bhh1[g];
    bZ = bih1[64 + g] + bhh1[64 + g];
    bNa = bih1[128 + g];
    bNb = bhh1[128 + g];
  }
  asm volatile("s_waitcnt lgkmcnt(0)\n\ts_barrier" ::: "memory");

  const int gwb = matw * 192 + half * 96 + (l >> 4) * 4;
  const f32x4 zacc = {0.f, 0.f, 0.f, 0.f};

  for (int i = 0; i <= 64; ++i) {
    bf16x8 b0 = *(const bf16x8*)&hv[mi][(l >> 4) * 8];
    bf16x8 b1 = *(const bf16x8*)&hv[mi][32 + (l >> 4) * 8];
    #pragma unroll
    for (int rbi = 0; rbi < 6; ++rbi) {
      f32x4 a_ = __builtin_amdgcn_mfma_f32_16x16x32_bf16(afr[rbi][0], b0, zacc, 0, 0, 0);
      a_ = __builtin_amdgcn_mfma_f32_16x16x32_bf16(afr[rbi][1], b1, a_, 0, 0, 0);
      if (!(l & 15)) *(f32x4*)&gout[gwb + rbi * 16] = a_;
    }
    asm volatile("s_waitcnt lgkmcnt(0)\n\ts_barrier" ::: "memory");
    if (tid < 64) {
      if (i < 64) {
        float r = fsigm(gil[i][tid] + gout[tid] + bR);
        float z = fsigm(gil[i][64 + tid] + gout[64 + tid] + bZ);
        float n = ftanh(gil[i][128 + tid] + r * (gout[128 + tid] + bNa));
        hreg = (1.f - z) * n + z * hreg;
        hv[0][tid] = f2bf(hreg);
      }
    } else if (tid < 128 && i > 0) {
      int g = tid - 64;
      float r = fsigm(gout[192 + g] + gout[384 + g] + bR);
      float z = fsigm(gout[256 + g] + gout[448 + g] + bZ);
      float n = ftanh((gout[320 + g] + bNa) + r * (gout[512 + g] + bNb));
      hreg = (1.f - z) * n + z * hreg;
      hv[1][g] = f2bf(hreg);
      out[(i - 1) * 64 + g] = hreg;
    }
    asm volatile("s_waitcnt lgkmcnt(0)\n\ts_barrier" ::: "memory");
  }
  if (tid < 64) out[4096 + tid] = hreg;
  else if (tid < 128) out[4096 + 64 + (tid - 64)] = hreg;
}

extern "C" void kernel_launch(void* const* d_in, const int* in_sizes, int n_in,
                              void* d_out, int out_size, void* d_ws, size_t ws_size,
                              hipStream_t stream) {
  const float* x    = (const float*)d_in[0];
  const float* adj  = (const float*)d_in[1];
  const float* W1   = (const float*)d_in[2];
  const float* b1   = (const float*)d_in[3];
  const float* W2   = (const float*)d_in[4];
  const float* b2   = (const float*)d_in[5];
  const float* Wih0 = (const float*)d_in[6];
  const float* Whh0 = (const float*)d_in[7];
  const float* bih0 = (const float*)d_in[8];
  const float* bhh0 = (const float*)d_in[9];
  const float* Wih1 = (const float*)d_in[10];
  const float* Whh1 = (const float*)d_in[11];
  const float* bih1 = (const float*)d_in[12];
  const float* bhh1 = (const float*)d_in[13];
  float* out = (float*)d_out;

  char* ws = (char*)d_ws;
  unsigned short* adjb = (unsigned short*)ws;                      // 33.55MB
  unsigned short* Xt   = (unsigned short*)(ws + 33554432);         // 16.78MB
  float* rowsum        = (float*)(ws + 67108864);                  // 16KB
  float* Gp            = (float*)(ws + 67125248);                  // 16.78MB
  float* Rm            = (float*)(ws + 83902464);                  // 2MB
  float* part          = (float*)(ws + 85999616);                  // 768KB
  float* gi0           = (float*)(ws + 86786048);                  // 48KB
  unsigned short* B2t  = (unsigned short*)(ws + 86835200);         // 1MB

  k_prep<<<8192, 256, 0, stream>>>(adj, adjb, rowsum, x, Xt);
  k_gemmAX<<<256, 512, 0, stream>>>(adjb, Xt, rowsum, W1, b1, W2, b2, B2t);
  k_gemm2<<<256, 256, 0, stream>>>(adjb, B2t, Gp);
  k_lsm<<<128, 256, 0, stream>>>(Gp, Rm);
  k_gi0<<<768, 256, 0, stream>>>(Rm, Wih0, part);
  k_gi0red<<<48, 256, 0, stream>>>(part, bih0, gi0);
  k_gru<<<1, 384, 0, stream>>>(gi0, Whh0, bhh0, Wih1, Whh1, bih1, bhh1, out);
}

// Round 11
// 176.038 us; speedup vs baseline: 1.2606x; 1.2144x over previous
//
#include <hip/hip_runtime.h>
#include <stdint.h>

#define SS 64
#define NN 4096
#define FF 32
#define HH 64
#define OO 2
#define G3 192

typedef float f32x4 __attribute__((ext_vector_type(4)));
typedef short bf16x8 __attribute__((ext_vector_type(8)));
typedef unsigned short u16x8 __attribute__((ext_vector_type(8)));

#define AS1 __attribute__((address_space(1)))
#define AS3 __attribute__((address_space(3)))

__device__ __forceinline__ unsigned short f2bf(float f) {
  union { float f; uint32_t u; } v; v.f = f;
  uint32_t u = v.u;
  uint32_t r = (u + 0x7FFFu + ((u >> 16) & 1u)) >> 16;
  return (unsigned short)r;
}
__device__ __forceinline__ float bf2f(unsigned short s) {
  union { uint32_t u; float f; } v; v.u = ((uint32_t)s) << 16;
  return v.f;
}

// ---------------- prep: adj f32->bf16 + rowsum (blocks 0..4095, 1 row each)
// ----------------       x transpose -> Xt[s*32+f][j] bf16 (blocks 4096..8191)
__global__ __launch_bounds__(256) void k_prep(const float* __restrict__ adj,
                                              unsigned short* __restrict__ adjb,
                                              float* __restrict__ rowsum,
                                              const float* __restrict__ x,
                                              unsigned short* __restrict__ Xt) {
  __shared__ float xl[64][33];
  __shared__ float ps[4];
  int tid = threadIdx.x;
  if (blockIdx.x < 4096) {
    int row = blockIdx.x;
    const float4* src = (const float4*)(adj + (size_t)row * 4096);
    ushort4* dst = (ushort4*)(adjb + (size_t)row * 4096);
    float sum = 0.f;
    #pragma unroll
    for (int q = 0; q < 4; ++q) {
      int idx = q * 256 + tid;
      float4 v = src[idx];
      ushort4 r;
      r.x = f2bf(v.x); r.y = f2bf(v.y); r.z = f2bf(v.z); r.w = f2bf(v.w);
      dst[idx] = r;
      sum += (v.x + v.y) + (v.z + v.w);
    }
    #pragma unroll
    for (int off = 1; off < 64; off <<= 1) sum += __shfl_xor(sum, off);
    if ((tid & 63) == 0) ps[tid >> 6] = sum;
    __syncthreads();
    if (tid == 0) rowsum[row] = (ps[0] + ps[1]) + (ps[2] + ps[3]);
    return;
  }
  int bs = blockIdx.x - 4096;
  int s = bs >> 6, jb = (bs & 63) << 6;
  const float4* xg = (const float4*)(x + ((size_t)s * NN + jb) * FF);
  #pragma unroll
  for (int ii = 0; ii < 2; ++ii) {
    int idx = tid + ii * 256;
    float4 v = xg[idx];
    int j = idx >> 3, f = (idx & 7) << 2;
    xl[j][f] = v.x; xl[j][f + 1] = v.y; xl[j][f + 2] = v.z; xl[j][f + 3] = v.w;
  }
  __syncthreads();
  int f = tid >> 3, jc = tid & 7;
  u16x8 ov;
  #pragma unroll
  for (int jj = 0; jj < 8; ++jj) ov[jj] = (short)f2bf(xl[jc * 8 + jj][f]);
  *(u16x8*)(Xt + (size_t)(s * 32 + f) * 4096 + jb + jc * 8) = ov;
}

// =====================================================================
// GEMM-AX fused: C1 = adj @ Xt^T (round-6 proven K-loop) + MFMA-based
// GCN epilogue: h = relu(C1@W1 + rowsum*b1) via mfma 16x16x32 (K=32=F),
// then o = h@W2 + b2 via VALU + 16-lane shfl reduce. Epilogue live-set
// ~50 VGPR -> fits the 128-reg grant, no scratch (rounds 7-10 spilled
// the VALU epilogue's 96-float working set).
// =====================================================================
#define SBAR()   asm volatile("s_barrier" ::: "memory")
#define VMCNT6() asm volatile("s_waitcnt vmcnt(6)" ::: "memory")
#define VMCNT0() asm volatile("s_waitcnt vmcnt(0)" ::: "memory")

__global__ __launch_bounds__(512, 2) void k_gemmAX(
    const unsigned short* __restrict__ A,
    const unsigned short* __restrict__ B,
    const float* __restrict__ rowsum,
    const float* __restrict__ W1f,
    const float* __restrict__ b1f,
    const float* __restrict__ W2f,
    const float* __restrict__ b2f,
    unsigned short* __restrict__ B2t) {
  __shared__ __align__(16) char lds[147456];
  __shared__ __align__(16) unsigned short w1t[64 * 40];  // W1^T bf16, pad 40
  __shared__ float w2l[128];
  __shared__ float b1l[64];
  __shared__ float b2l[2];
  const int tid = threadIdx.x;
  const int wid = tid >> 6, l = tid & 63;
  const int wr2 = wid >> 2, wc2 = wid & 3;

  // build w1t[h][f] = bf16(W1[f][h]); stage small weights
  {
    float4 v = ((const float4*)W1f)[tid];     // f = tid>>4, h = (tid&15)*4
    int f = tid >> 4, h = (tid & 15) * 4;
    w1t[(h + 0) * 40 + f] = f2bf(v.x);
    w1t[(h + 1) * 40 + f] = f2bf(v.y);
    w1t[(h + 2) * 40 + f] = f2bf(v.z);
    w1t[(h + 3) * 40 + f] = f2bf(v.w);
  }
  if (tid < 32) *(float4*)&w2l[tid * 4] = ((const float4*)W2f)[tid];
  if (tid < 16) *(float4*)&b1l[tid * 4] = ((const float4*)b1f)[tid];
  if (tid < 2) b2l[tid] = b2f[tid];
  __syncthreads();

  int bid = blockIdx.x;
  int swz = (bid & 7) * 32 + (bid >> 3);   // bijective XCD swizzle (256 = 8*32)
  const int i0 = (swz >> 3) * 128;         // 32 i-tiles
  const int c0 = (swz & 7) * 256;          // 8 sf-tiles

  const int aOffC = wr2 * 8192 + (l & 15) * 128;
  const int bOffC = 16384 + wc2 * 8192 + (l & 15) * 128;
  const int colKK0 = (((l >> 4) * 16)) ^ ((l & 7) << 4);
  const int colKK1 = ((64 + (l >> 4) * 16)) ^ ((l & 7) << 4);

  const int srow = tid >> 3;
  const int scol = (((tid & 7) ^ (srow & 7)) << 4);
  const char* gA = (const char*)A + (size_t)(i0 + srow) * 8192 + scol;
  const char* gB = (const char*)B + (size_t)(c0 + srow) * 8192 + scol;
  char* ldsW = (char*)lds + wid * 1024;
  const char* ldsR = (const char*)lds;

  f32x4 acc[4][4];
  #pragma unroll
  for (int m = 0; m < 4; ++m)
    #pragma unroll
    for (int n = 0; n < 4; ++n) acc[m][n] = {0.f, 0.f, 0.f, 0.f};

  bf16x8 af[4][2], bfr[2][2];

#define STAGE6(K2, BOFS) do {                                                        \
    __builtin_amdgcn_global_load_lds((const AS1 void*)(gA + (K2)),                   \
        (AS3 void*)(ldsW + (BOFS)), 16, 0, 0);                                       \
    __builtin_amdgcn_global_load_lds((const AS1 void*)(gA + 524288 + (K2)),          \
        (AS3 void*)(ldsW + (BOFS) + 8192), 16, 0, 0);                                \
    __builtin_amdgcn_global_load_lds((const AS1 void*)(gB + (K2)),                   \
        (AS3 void*)(ldsW + (BOFS) + 16384), 16, 0, 0);                               \
    __builtin_amdgcn_global_load_lds((const AS1 void*)(gB + 524288 + (K2)),          \
        (AS3 void*)(ldsW + (BOFS) + 24576), 16, 0, 0);                               \
    __builtin_amdgcn_global_load_lds((const AS1 void*)(gB + 1048576 + (K2)),         \
        (AS3 void*)(ldsW + (BOFS) + 32768), 16, 0, 0);                               \
    __builtin_amdgcn_global_load_lds((const AS1 void*)(gB + 1572864 + (K2)),         \
        (AS3 void*)(ldsW + (BOFS) + 40960), 16, 0, 0);                               \
  } while (0)

#define READ_AF(BOFS) do {                                                           \
    _Pragma("unroll")                                                                \
    for (int _m = 0; _m < 4; ++_m) {                                                 \
      const char* _p = ldsR + (BOFS) + aOffC + _m * 2048;                            \
      af[_m][0] = *(const bf16x8*)(_p + colKK0);                                     \
      af[_m][1] = *(const bf16x8*)(_p + colKK1);                                     \
    } } while (0)

#define READ_B(BOFS, NH) do {                                                        \
    _Pragma("unroll")                                                                \
    for (int _j = 0; _j < 2; ++_j) {                                                 \
      const char* _p = ldsR + (BOFS) + bOffC + ((NH) * 2 + _j) * 2048;               \
      bfr[_j][0] = *(const bf16x8*)(_p + colKK0);                                    \
      bfr[_j][1] = *(const bf16x8*)(_p + colKK1);                                    \
    } } while (0)

#define MFMA_H(NH) do {                                                              \
    __builtin_amdgcn_s_setprio(1);                                                   \
    _Pragma("unroll")                                                                \
    for (int _kk = 0; _kk < 2; ++_kk)                                                \
      _Pragma("unroll")                                                              \
      for (int _m = 0; _m < 4; ++_m)                                                 \
        _Pragma("unroll")                                                            \
        for (int _j = 0; _j < 2; ++_j)                                               \
          acc[_m][(NH) * 2 + _j] = __builtin_amdgcn_mfma_f32_16x16x32_bf16(          \
              af[_m][_kk], bfr[_j][_kk], acc[_m][(NH) * 2 + _j], 0, 0, 0);           \
    __builtin_amdgcn_s_setprio(0);                                                   \
  } while (0)

  STAGE6(0, 0);
  STAGE6(128, 49152);
  VMCNT6();
  SBAR();

  int bofs = 0, bofs2 = 98304;
  for (int kt = 0; kt < 64; ++kt) {
    const int k2 = ((kt + 2) & 63) * 128;
    READ_AF(bofs);
    READ_B(bofs, 0);
    STAGE6(k2, bofs2);
    MFMA_H(0);
    READ_B(bofs, 1);
    MFMA_H(1);
    VMCNT6();
    SBAR();
    bofs = (bofs == 98304) ? 0 : bofs + 49152;
    bofs2 = (bofs2 == 98304) ? 0 : bofs2 + 49152;
  }
  VMCNT0();
  __syncthreads();   // LDS now reusable

  // ---- acc -> C1 tile bf16 in LDS [128 rows][264 u16] ----
  unsigned short* C1L = (unsigned short*)lds;
  {
    const int rb = wr2 * 64 + (l >> 4) * 4;
    const int cbL = wc2 * 64 + (l & 15);
    #pragma unroll
    for (int m = 0; m < 4; ++m)
      #pragma unroll
      for (int r = 0; r < 4; ++r) {
        const int row = rb + m * 16 + r;
        #pragma unroll
        for (int n = 0; n < 4; ++n)
          C1L[row * 264 + cbL + n * 16] = f2bf(acc[m][n][r]);
      }
  }
  __syncthreads();

  // ---- MFMA GCN epilogue: wave wid owns rows [wid*16, wid*16+16) ----
  {
    const f32x4 zacc = {0.f, 0.f, 0.f, 0.f};
    const int lc = l & 15, lq = l >> 4;
    // B-frags from w1t (col h = n*16+lc, k f = lq*8+j) + per-h constants
    bf16x8 bw[4];
    float b1v[4], w2a[4], w2b[4];
    #pragma unroll
    for (int n = 0; n < 4; ++n) {
      const int h = n * 16 + lc;
      bw[n] = *(const bf16x8*)((const char*)w1t + h * 80 + lq * 16);
      b1v[n] = b1l[h];
      w2a[n] = w2l[h * 2];
      w2b[n] = w2l[h * 2 + 1];
    }
    const int rbase = wid * 16 + lq * 4;
    const float4 rs4 = *(const float4*)&rowsum[i0 + rbase];
    const float bo0 = b2l[0], bo1 = b2l[1];
    #pragma unroll
    for (int s = 0; s < 8; ++s) {
      // A-frag: C1L row (wid*16+lc), f = lq*8+j, col-block s*32
      bf16x8 afr = *(const bf16x8*)((const char*)C1L +
                     (wid * 16 + lc) * 528 + s * 64 + lq * 16);
      float o0r[4] = {0.f, 0.f, 0.f, 0.f};
      float o1r[4] = {0.f, 0.f, 0.f, 0.f};
      #pragma unroll
      for (int n = 0; n < 4; ++n) {
        f32x4 hq = __builtin_amdgcn_mfma_f32_16x16x32_bf16(afr, bw[n], zacc, 0, 0, 0);
        #pragma unroll
        for (int r = 0; r < 4; ++r) {
          float hv = hq[r] + rs4[r] * b1v[n];
          hv = hv > 0.f ? hv : 0.f;
          o0r[r] += hv * w2a[n];
          o1r[r] += hv * w2b[n];
        }
      }
      #pragma unroll
      for (int off = 1; off < 16; off <<= 1)
        #pragma unroll
        for (int r = 0; r < 4; ++r) {
          o0r[r] += __shfl_xor(o0r[r], off);
          o1r[r] += __shfl_xor(o1r[r], off);
        }
      if (lc == 0) {
        const int sg = (c0 >> 5) + s;
        #pragma unroll
        for (int r = 0; r < 4; ++r) {
          B2t[(size_t)(sg * 2 + 0) * 4096 + i0 + rbase + r] = f2bf(o0r[r] + bo0);
          B2t[(size_t)(sg * 2 + 1) * 4096 + i0 + rbase + r] = f2bf(o1r[r] + bo1);
        }
      }
    }
  }
}

// ---------------- shared MFMA GEMM core (m97-style, used by gemm2) ----------------
__device__ __forceinline__ void gemm_core(const unsigned short* __restrict__ A,
                                          const unsigned short* __restrict__ B,
                                          int i0, int c0, int k0base, int ksteps,
                                          f32x4 acc[4][4],
                                          unsigned short* Als, unsigned short* Bls) {
  const int tid = threadIdx.x;
  const int w = tid >> 6, l = tid & 63;
  const int srow = (l >> 2);
  const int scol = (l & 3) * 16;
  for (int kt = 0; kt < ksteps; ++kt) {
    int k0 = k0base + kt * 32;
    #pragma unroll
    for (int q = 0; q < 2; ++q) {
      int r = w * 32 + q * 16 + srow;
      const char* ga = (const char*)(A + (size_t)(i0 + r) * 4096 + k0) + scol;
      __builtin_amdgcn_global_load_lds(
          (const AS1 void*)ga,
          (AS3 void*)((char*)Als + w * 2048 + q * 1024), 16, 0, 0);
      const char* gb = (const char*)(B + (size_t)(c0 + r) * 4096 + k0) + scol;
      __builtin_amdgcn_global_load_lds(
          (const AS1 void*)gb,
          (AS3 void*)((char*)Bls + w * 2048 + q * 1024), 16, 0, 0);
    }
    __syncthreads();
    const int wr = w >> 1, wc = w & 1;
    bf16x8 af[4], bff[4];
    #pragma unroll
    for (int m = 0; m < 4; ++m)
      af[m] = *(const bf16x8*)(Als + (wr * 64 + m * 16 + (l & 15)) * 32 + (l >> 4) * 8);
    #pragma unroll
    for (int n = 0; n < 4; ++n)
      bff[n] = *(const bf16x8*)(Bls + (wc * 64 + n * 16 + (l & 15)) * 32 + (l >> 4) * 8);
    #pragma unroll
    for (int m = 0; m < 4; ++m)
      #pragma unroll
      for (int n = 0; n < 4; ++n)
        acc[m][n] = __builtin_amdgcn_mfma_f32_16x16x32_bf16(af[m], bff[n], acc[m][n], 0, 0, 0);
    __syncthreads();
  }
}

// ---------------- GEMM2 split-K: Gp[ks][i][c2] partial f32 ----------------
__global__ __launch_bounds__(256) void k_gemm2(const unsigned short* __restrict__ A,
                                               const unsigned short* __restrict__ B,
                                               float* __restrict__ Gp) {
  __shared__ unsigned short Als[128 * 32], Bls[128 * 32];
  int id = blockIdx.x;
  int bi = id & 31, ks = id >> 5;
  int i0 = bi * 128;
  f32x4 acc[4][4];
  #pragma unroll
  for (int m = 0; m < 4; ++m)
    #pragma unroll
    for (int n = 0; n < 4; ++n) acc[m][n] = {0.f, 0.f, 0.f, 0.f};
  gemm_core(A, B, i0, 0, ks * 512, 16, acc, Als, Bls);
  float* outp = Gp + (size_t)ks * 4096 * 128;
  int l = threadIdx.x & 63, w = threadIdx.x >> 6;
  int wr = w >> 1, wc = w & 1;
  int rbase = i0 + wr * 64 + (l >> 4) * 4;
  int cbase = wc * 64 + (l & 15);
  #pragma unroll
  for (int m = 0; m < 4; ++m)
    #pragma unroll
    for (int n = 0; n < 4; ++n)
      #pragma unroll
      for (int r = 0; r < 4; ++r)
        outp[(size_t)(rbase + m * 16 + r) * 128 + cbase + n * 16] = acc[m][n][r];
}

// ---------------- reduce split-K + log_softmax -> R[s][i*2+o] f32 ----------------
__global__ __launch_bounds__(256) void k_lsm(const float* __restrict__ Gp,
                                             float* __restrict__ Rm) {
  __shared__ float Gacc[32][130];
  int i0 = blockIdx.x * 32;
  int tid = threadIdx.x;
  float4 v[4];
  #pragma unroll
  for (int i = 0; i < 4; ++i) v[i] = {0.f, 0.f, 0.f, 0.f};
  for (int ks = 0; ks < 8; ++ks) {
    const float4* gp4 = ((const float4*)Gp) + (size_t)ks * 131072 + (size_t)i0 * 32;
    #pragma unroll
    for (int i = 0; i < 4; ++i) {
      float4 t = gp4[tid + i * 256];
      v[i].x += t.x; v[i].y += t.y; v[i].z += t.z; v[i].w += t.w;
    }
  }
  #pragma unroll
  for (int i = 0; i < 4; ++i) {
    int f4i = tid + i * 256, row = f4i >> 5, c = (f4i & 31) * 4;
    Gacc[row][c] = v[i].x; Gacc[row][c + 1] = v[i].y;
    Gacc[row][c + 2] = v[i].z; Gacc[row][c + 3] = v[i].w;
  }
  __syncthreads();
  #pragma unroll
  for (int j = 0; j < 8; ++j) {
    int p = j * 256 + tid;
    int ii = p & 31, s = p >> 5;
    float g0 = Gacc[ii][s * 2], g1 = Gacc[ii][s * 2 + 1];
    float m = fmaxf(g0, g1);
    float lse = m + logf(expf(g0 - m) + expf(g1 - m));
    float2 o_; o_.x = g0 - lse; o_.y = g1 - lse;
    *((float2*)(Rm + (size_t)s * 8192 + (size_t)(i0 + ii) * 2)) = o_;
  }
}

// ---------------- gi0 partial: part[ks][t][g] = R[t] . Wih0[g] over c-range ----------------
__global__ __launch_bounds__(256) void k_gi0(const float* __restrict__ Rm,
                                             const float* __restrict__ Wih0,
                                             float* __restrict__ part) {
  __shared__ float4 Wl[4 * 128];
  int gb = blockIdx.x % 48, ks = blockIdx.x / 48;
  int c0 = ks * 512;
  int tid = threadIdx.x;
  #pragma unroll
  for (int i = 0; i < 2; ++i) {
    int idx = tid + i * 256;
    int g = idx >> 7, c4 = idx & 127;
    Wl[g * 128 + c4] = ((const float4*)(Wih0 + (size_t)(gb * 4 + g) * 8192 + c0))[c4];
  }
  __syncthreads();
  int w = tid >> 6, lane = tid & 63;
  for (int pass = 0; pass < 16; ++pass) {
    int t = pass * 4 + w;
    float a0 = 0.f, a1 = 0.f, a2 = 0.f, a3 = 0.f;
    const float4* rg = (const float4*)(Rm + (size_t)t * 8192 + c0);
    #pragma unroll
    for (int i = 0; i < 2; ++i) {
      int c4 = i * 64 + lane;
      float4 r4 = rg[c4];
      float4 w0 = Wl[c4], w1 = Wl[128 + c4], w2 = Wl[256 + c4], w3 = Wl[384 + c4];
      a0 += r4.x * w0.x + r4.y * w0.y + r4.z * w0.z + r4.w * w0.w;
      a1 += r4.x * w1.x + r4.y * w1.y + r4.z * w1.z + r4.w * w1.w;
      a2 += r4.x * w2.x + r4.y * w2.y + r4.z * w2.z + r4.w * w2.w;
      a3 += r4.x * w3.x + r4.y * w3.y + r4.z * w3.z + r4.w * w3.w;
    }
    #pragma unroll
    for (int off = 1; off < 64; off <<= 1) {
      a0 += __shfl_xor(a0, off);
      a1 += __shfl_xor(a1, off);
      a2 += __shfl_xor(a2, off);
      a3 += __shfl_xor(a3, off);
    }
    if (lane == 0) {
      float4 o_; o_.x = a0; o_.y = a1; o_.z = a2; o_.w = a3;
      *((float4*)(part + ((size_t)ks * 64 + t) * 192 + gb * 4)) = o_;
    }
  }
}

__global__ __launch_bounds__(256) void k_gi0red(const float* __restrict__ part,
                                                const float* __restrict__ bih0,
                                                float* __restrict__ gi0) {
  int idx = blockIdx.x * 256 + threadIdx.x;
  if (idx < 12288) {
    float s_ = bih0[idx % 192];
    for (int ks = 0; ks < 16; ++ks) s_ += part[ks * 12288 + idx];
    gi0[idx] = s_;
  }
}

// =====================================================================
// MFMA GRU (unchanged — proven round 6)
// =====================================================================
__device__ __forceinline__ float fsigm(float x) {
  return __builtin_amdgcn_rcpf(1.f + __expf(-x));
}
__device__ __forceinline__ float ftanh(float x) {
  return 1.f - 2.f * __builtin_amdgcn_rcpf(1.f + __expf(2.f * x));
}

__global__ __launch_bounds__(384) void k_gru(const float* __restrict__ gi0,
                                             const float* __restrict__ Whh0,
                                             const float* __restrict__ bhh0,
                                             const float* __restrict__ Wih1,
                                             const float* __restrict__ Whh1,
                                             const float* __restrict__ bih1,
                                             const float* __restrict__ bhh1,
                                             float* __restrict__ out) {
  __shared__ float gil[64][192];
  __shared__ float gout[576];
  __shared__ __align__(16) unsigned short hv[2][64];
  const int tid = threadIdx.x;
  const int w = tid >> 6, l = tid & 63;
  const int matw = w >> 1, half = w & 1;
  const float* Wm = (matw == 0) ? Whh0 : (matw == 1 ? Wih1 : Whh1);
  const int mi = (matw == 2) ? 1 : 0;

  bf16x8 afr[6][2];
  #pragma unroll
  for (int rbi = 0; rbi < 6; ++rbi) {
    int g = (half * 6 + rbi) * 16 + (l & 15);
    #pragma unroll
    for (int kh = 0; kh < 2; ++kh) {
      int k0 = kh * 32 + (l >> 4) * 8;
      const float4* src = (const float4*)(Wm + (size_t)g * 64 + k0);
      float4 v0 = src[0], v1 = src[1];
      bf16x8 a;
      a[0] = (short)f2bf(v0.x); a[1] = (short)f2bf(v0.y);
      a[2] = (short)f2bf(v0.z); a[3] = (short)f2bf(v0.w);
      a[4] = (short)f2bf(v1.x); a[5] = (short)f2bf(v1.y);
      a[6] = (short)f2bf(v1.z); a[7] = (short)f2bf(v1.w);
      afr[rbi][kh] = a;
    }
  }
  {
    float4* gf = (float4*)&gil[0][0];
    const float4* gs = (const float4*)gi0;
    #pragma unroll
    for (int i = 0; i < 8; ++i) gf[i * 384 + tid] = gs[i * 384 + tid];
  }
  if (tid < 128) hv[tid >> 6][tid & 63] = 0;

  float hreg = 0.f;
  float bR = 0.f, bZ = 0.f, bNa = 0.f, bNb = 0.f;
  if (tid < 64) {
    bR = bhh0[tid]; bZ = bhh0[64 + tid]; bNa = bhh0[128 + tid];
  } else if (tid < 128) {
    int g = tid - 64;
    bR = bih1[g] + bhh1[g];
    bZ = bih1[64 + g] + bhh1[64 + g];
    bNa = bih1[128 + g];
    bNb = bhh1[128 + g];
  }
  asm volatile("s_waitcnt lgkmcnt(0)\n\ts_barrier" ::: "memory");

  const int gwb = matw * 192 + half * 96 + (l >> 4) * 4;
  const f32x4 zacc = {0.f, 0.f, 0.f, 0.f};

  for (int i = 0; i <= 64; ++i) {
    bf16x8 b0 = *(const bf16x8*)&hv[mi][(l >> 4) * 8];
    bf16x8 b1 = *(const bf16x8*)&hv[mi][32 + (l >> 4) * 8];
    #pragma unroll
    for (int rbi = 0; rbi < 6; ++rbi) {
      f32x4 a_ = __builtin_amdgcn_mfma_f32_16x16x32_bf16(afr[rbi][0], b0, zacc, 0, 0, 0);
      a_ = __builtin_amdgcn_mfma_f32_16x16x32_bf16(afr[rbi][1], b1, a_, 0, 0, 0);
      if (!(l & 15)) *(f32x4*)&gout[gwb + rbi * 16] = a_;
    }
    asm volatile("s_waitcnt lgkmcnt(0)\n\ts_barrier" ::: "memory");
    if (tid < 64) {
      if (i < 64) {
        float r = fsigm(gil[i][tid] + gout[tid] + bR);
        float z = fsigm(gil[i][64 + tid] + gout[64 + tid] + bZ);
        float n = ftanh(gil[i][128 + tid] + r * (gout[128 + tid] + bNa));
        hreg = (1.f - z) * n + z * hreg;
        hv[0][tid] = f2bf(hreg);
      }
    } else if (tid < 128 && i > 0) {
      int g = tid - 64;
      float r = fsigm(gout[192 + g] + gout[384 + g] + bR);
      float z = fsigm(gout[256 + g] + gout[448 + g] + bZ);
      float n = ftanh((gout[320 + g] + bNa) + r * (gout[512 + g] + bNb));
      hreg = (1.f - z) * n + z * hreg;
      hv[1][g] = f2bf(hreg);
      out[(i - 1) * 64 + g] = hreg;
    }
    asm volatile("s_waitcnt lgkmcnt(0)\n\ts_barrier" ::: "memory");
  }
  if (tid < 64) out[4096 + tid] = hreg;
  else if (tid < 128) out[4096 + 64 + (tid - 64)] = hreg;
}

extern "C" void kernel_launch(void* const* d_in, const int* in_sizes, int n_in,
                              void* d_out, int out_size, void* d_ws, size_t ws_size,
                              hipStream_t stream) {
  const float* x    = (const float*)d_in[0];
  const float* adj  = (const float*)d_in[1];
  const float* W1   = (const float*)d_in[2];
  const float* b1   = (const float*)d_in[3];
  const float* W2   = (const float*)d_in[4];
  const float* b2   = (const float*)d_in[5];
  const float* Wih0 = (const float*)d_in[6];
  const float* Whh0 = (const float*)d_in[7];
  const float* bih0 = (const float*)d_in[8];
  const float* bhh0 = (const float*)d_in[9];
  const float* Wih1 = (const float*)d_in[10];
  const float* Whh1 = (const float*)d_in[11];
  const float* bih1 = (const float*)d_in[12];
  const float* bhh1 = (const float*)d_in[13];
  float* out = (float*)d_out;

  char* ws = (char*)d_ws;
  unsigned short* adjb = (unsigned short*)ws;                      // 33.55MB
  unsigned short* Xt   = (unsigned short*)(ws + 33554432);         // 16.78MB
  float* rowsum        = (float*)(ws + 67108864);                  // 16KB
  float* Gp            = (float*)(ws + 67125248);                  // 16.78MB
  float* Rm            = (float*)(ws + 83902464);                  // 2MB
  float* part          = (float*)(ws + 85999616);                  // 768KB
  float* gi0           = (float*)(ws + 86786048);                  // 48KB
  unsigned short* B2t  = (unsigned short*)(ws + 86835200);         // 1MB

  k_prep<<<8192, 256, 0, stream>>>(adj, adjb, rowsum, x, Xt);
  k_gemmAX<<<256, 512, 0, stream>>>(adjb, Xt, rowsum, W1, b1, W2, b2, B2t);
  k_gemm2<<<256, 256, 0, stream>>>(adjb, B2t, Gp);
  k_lsm<<<128, 256, 0, stream>>>(Gp, Rm);
  k_gi0<<<768, 256, 0, stream>>>(Rm, Wih0, part);
  k_gi0red<<<48, 256, 0, stream>>>(part, bih0, gi0);
  k_gru<<<1, 384, 0, stream>>>(gi0, Whh0, bhh0, Wih1, Whh1, bih1, bhh1, out);
}

// Round 12
// 165.518 us; speedup vs baseline: 1.3407x; 1.0636x over previous
//
#include <hip/hip_runtime.h>
#include <stdint.h>

#define SS 64
#define NN 4096
#define FF 32
#define HH 64
#define OO 2
#define G3 192

typedef float f32x4 __attribute__((ext_vector_type(4)));
typedef short bf16x8 __attribute__((ext_vector_type(8)));
typedef unsigned short u16x8 __attribute__((ext_vector_type(8)));

#define AS1 __attribute__((address_space(1)))
#define AS3 __attribute__((address_space(3)))

__device__ __forceinline__ unsigned short f2bf(float f) {
  union { float f; uint32_t u; } v; v.f = f;
  uint32_t u = v.u;
  uint32_t r = (u + 0x7FFFu + ((u >> 16) & 1u)) >> 16;
  return (unsigned short)r;
}
__device__ __forceinline__ float bf2f(unsigned short s) {
  union { uint32_t u; float f; } v; v.u = ((uint32_t)s) << 16;
  return v.f;
}
// f32 -> OCP e4m3fn, RNE (hand-rolled; handles denormals & sign)
__device__ __forceinline__ unsigned char f2e4m3(float x) {
  float a = fabsf(x);
  unsigned s = (x < 0.f) ? 0x80u : 0u;
  if (a >= 448.f) return (unsigned char)(s | 0x7E);
  if (a < 0.015625f) {                      // below min normal 2^-6
    int q = (int)rintf(a * 512.f);          // units of 2^-9 (k=8 -> 2^-6, valid)
    return (unsigned char)(s | (unsigned)q);
  }
  union { float f; uint32_t u; } v; v.f = a;
  uint32_t b = v.u + 0x7FFFFu + ((v.u >> 20) & 1u);
  int e = (int)(b >> 23) - 127;
  if (e > 8) return (unsigned char)(s | 0x7E);
  return (unsigned char)(s | (unsigned)(((e + 7) << 3) | ((b >> 20) & 7u)));
}

// ---------------- prep: adj -> adjb(bf16) + adj8(fp8 x4096) + rowsum (blocks 0..4095)
// ----------------       x -> Xt8[s*32+f][j] fp8 (blocks 4096..8191)
__global__ __launch_bounds__(256) void k_prep(const float* __restrict__ adj,
                                              unsigned short* __restrict__ adjb,
                                              unsigned char* __restrict__ adj8,
                                              float* __restrict__ rowsum,
                                              const float* __restrict__ x,
                                              unsigned char* __restrict__ Xt8) {
  __shared__ float xl[64][33];
  __shared__ float ps[4];
  int tid = threadIdx.x;
  if (blockIdx.x < 4096) {
    int row = blockIdx.x;
    const float4* src = (const float4*)(adj + (size_t)row * 4096);
    ushort4* dst = (ushort4*)(adjb + (size_t)row * 4096);
    uchar4* dst8 = (uchar4*)(adj8 + (size_t)row * 4096);
    float sum = 0.f;
    #pragma unroll
    for (int q = 0; q < 4; ++q) {
      int idx = q * 256 + tid;
      float4 v = src[idx];
      ushort4 r;
      r.x = f2bf(v.x); r.y = f2bf(v.y); r.z = f2bf(v.z); r.w = f2bf(v.w);
      dst[idx] = r;
      uchar4 r8;
      r8.x = f2e4m3(v.x * 4096.f); r8.y = f2e4m3(v.y * 4096.f);
      r8.z = f2e4m3(v.z * 4096.f); r8.w = f2e4m3(v.w * 4096.f);
      dst8[idx] = r8;
      sum += (v.x + v.y) + (v.z + v.w);
    }
    #pragma unroll
    for (int off = 1; off < 64; off <<= 1) sum += __shfl_xor(sum, off);
    if ((tid & 63) == 0) ps[tid >> 6] = sum;
    __syncthreads();
    if (tid == 0) rowsum[row] = (ps[0] + ps[1]) + (ps[2] + ps[3]);
    return;
  }
  int bs = blockIdx.x - 4096;
  int s = bs >> 6, jb = (bs & 63) << 6;
  const float4* xg = (const float4*)(x + ((size_t)s * NN + jb) * FF);
  #pragma unroll
  for (int ii = 0; ii < 2; ++ii) {
    int idx = tid + ii * 256;
    float4 v = xg[idx];
    int j = idx >> 3, f = (idx & 7) << 2;
    xl[j][f] = v.x; xl[j][f + 1] = v.y; xl[j][f + 2] = v.z; xl[j][f + 3] = v.w;
  }
  __syncthreads();
  int f = tid >> 3, jc = tid & 7;
  unsigned int lo = 0, hi = 0;
  #pragma unroll
  for (int jj = 0; jj < 4; ++jj) lo |= ((unsigned int)f2e4m3(xl[jc * 8 + jj][f])) << (jj * 8);
  #pragma unroll
  for (int jj = 0; jj < 4; ++jj) hi |= ((unsigned int)f2e4m3(xl[jc * 8 + 4 + jj][f])) << (jj * 8);
  uint2 ov; ov.x = lo; ov.y = hi;
  *(uint2*)(Xt8 + (size_t)(s * 32 + f) * 4096 + jb + jc * 8) = ov;
}

// =====================================================================
// GEMM-AX fp8: C1 = (adj8 @ Xt8^T) * 2^-12.  M=4096 N=2048 K=4096.
// 128x256 tile, BK=64, 8 waves, FIVE 24KB LDS buffers, prefetch dist 4,
// vmcnt(9) counted (6/3/0 tail). fp8 rows = 64B, chunk-XOR swizzle
// chunk ^= (row&3)^((row>>2)&3) -> 2-way (free) on ds_read_b64.
// MFMA epilogue (round-11 proven): h=relu(C1@W1+rs*b1); B2t=h@W2+b2.
// =====================================================================
#define SBAR()   asm volatile("s_barrier" ::: "memory")
#define VMC9()   asm volatile("s_waitcnt vmcnt(9)" ::: "memory")
#define VMC6()   asm volatile("s_waitcnt vmcnt(6)" ::: "memory")
#define VMC3()   asm volatile("s_waitcnt vmcnt(3)" ::: "memory")
#define VMC0()   asm volatile("s_waitcnt vmcnt(0)" ::: "memory")

__global__ __launch_bounds__(512, 2) void k_gemmAX(
    const unsigned char* __restrict__ A8,
    const unsigned char* __restrict__ B8,
    const float* __restrict__ rowsum,
    const float* __restrict__ W1f,
    const float* __restrict__ b1f,
    const float* __restrict__ W2f,
    const float* __restrict__ b2f,
    unsigned short* __restrict__ B2t) {
  __shared__ __align__(16) char lds[122880];               // 5 x 24KB
  __shared__ __align__(16) unsigned short w1t[64 * 40];    // W1^T bf16, pad 40
  __shared__ float w2l[128];
  __shared__ float b1l[64];
  __shared__ float b2l[2];
  const int tid = threadIdx.x;
  const int wid = tid >> 6, l = tid & 63;
  const int wr2 = wid >> 2, wc2 = wid & 3;
  const int lc = l & 15, lq = l >> 4;

  // build w1t[h][f] = bf16(W1[f][h]); stage small weights
  {
    float4 v = ((const float4*)W1f)[tid];     // f = tid>>4, h = (tid&15)*4
    int f = tid >> 4, h = (tid & 15) * 4;
    w1t[(h + 0) * 40 + f] = f2bf(v.x);
    w1t[(h + 1) * 40 + f] = f2bf(v.y);
    w1t[(h + 2) * 40 + f] = f2bf(v.z);
    w1t[(h + 3) * 40 + f] = f2bf(v.w);
  }
  if (tid < 32) *(float4*)&w2l[tid * 4] = ((const float4*)W2f)[tid];
  if (tid < 16) *(float4*)&b1l[tid * 4] = ((const float4*)b1f)[tid];
  if (tid < 2) b2l[tid] = b2f[tid];
  __syncthreads();

  int bid = blockIdx.x;
  int swz = (bid & 7) * 32 + (bid >> 3);   // bijective XCD swizzle (256 = 8*32)
  const int i0 = (swz >> 3) * 128;         // 32 i-tiles
  const int c0 = (swz & 7) * 256;          // 8 sf-tiles

  // fragment-read lane constants (64B fp8 rows; chunk-XOR swizzle)
  const int aBase = (wr2 * 64 + lc) * 64;
  const int bBase = 8192 + (wc2 * 64 + lc) * 64;
  const int aswz = (lc & 3) ^ ((lc >> 2) & 3);
  const int ck0 = ((((lq >> 1)) ^ aswz) << 4) + (lq & 1) * 8;       // kk=0
  const int ck1 = (((2 + (lq >> 1)) ^ aswz) << 4) + (lq & 1) * 8;   // kk=1

  // staging lane constants: linear LDS dest, inverse-swizzled global source
  const int srow = wid * 16 + (l >> 2);
  const int sswz = (srow & 3) ^ ((srow >> 2) & 3);
  const int scol = (((l & 3) ^ sswz) << 4);
  const char* gA = (const char*)A8 + (size_t)(i0 + srow) * 4096 + scol;
  const char* gB = (const char*)B8 + (size_t)(c0 + srow) * 4096 + scol;
  char* ldsW = (char*)lds + wid * 1024;
  const char* ldsR = (const char*)lds;

  f32x4 acc[4][4];
  #pragma unroll
  for (int m = 0; m < 4; ++m)
    #pragma unroll
    for (int n = 0; n < 4; ++n) acc[m][n] = {0.f, 0.f, 0.f, 0.f};

  long afr[4][2], bfr[4][2];

#define STAGE3(KT, BOFS) do {                                                        \
    __builtin_amdgcn_global_load_lds((const AS1 void*)(gA + (KT) * 64),              \
        (AS3 void*)(ldsW + (BOFS)), 16, 0, 0);                                       \
    __builtin_amdgcn_global_load_lds((const AS1 void*)(gB + (KT) * 64),              \
        (AS3 void*)(ldsW + (BOFS) + 8192), 16, 0, 0);                                \
    __builtin_amdgcn_global_load_lds((const AS1 void*)(gB + 524288 + (KT) * 64),     \
        (AS3 void*)(ldsW + (BOFS) + 16384), 16, 0, 0);                               \
  } while (0)

#define READ_FR(BOFS) do {                                                           \
    _Pragma("unroll")                                                                \
    for (int _m = 0; _m < 4; ++_m) {                                                 \
      const char* _p = ldsR + (BOFS) + aBase + _m * 1024;                            \
      afr[_m][0] = *(const long*)(_p + ck0);                                         \
      afr[_m][1] = *(const long*)(_p + ck1);                                         \
    }                                                                                \
    _Pragma("unroll")                                                                \
    for (int _n = 0; _n < 4; ++_n) {                                                 \
      const char* _q = ldsR + (BOFS) + bBase + _n * 1024;                            \
      bfr[_n][0] = *(const long*)(_q + ck0);                                         \
      bfr[_n][1] = *(const long*)(_q + ck1);                                         \
    } } while (0)

#define MFMA32() do {                                                                \
    __builtin_amdgcn_s_setprio(1);                                                   \
    _Pragma("unroll")                                                                \
    for (int _kk = 0; _kk < 2; ++_kk)                                                \
      _Pragma("unroll")                                                              \
      for (int _m = 0; _m < 4; ++_m)                                                 \
        _Pragma("unroll")                                                            \
        for (int _n = 0; _n < 4; ++_n)                                               \
          acc[_m][_n] = __builtin_amdgcn_mfma_f32_16x16x32_fp8_fp8(                  \
              afr[_m][_kk], bfr[_n][_kk], acc[_m][_n], 0, 0, 0);                     \
    __builtin_amdgcn_s_setprio(0);                                                   \
  } while (0)

  // Prologue: tiles 0..3 -> bufs 0..3 (12 ops); vmcnt(9) completes tile 0.
  STAGE3(0, 0);
  STAGE3(1, 24576);
  STAGE3(2, 49152);
  STAGE3(3, 73728);
  VMC9();
  SBAR();

  int bR = 0, bS = 98304;
  for (int kt = 0; kt < 60; ++kt) {
    READ_FR(bR);
    STAGE3(kt + 4, bS);
    MFMA32();
    VMC9();                  // tile kt+1 complete (dist-4 pipeline, 9 = 3 tiles x 3 ops)
    SBAR();
    bR = (bR == 98304) ? 0 : bR + 24576;
    bS = (bS == 98304) ? 0 : bS + 24576;
  }
  // tail: no more stages; drain 6/3/0
  READ_FR(bR); MFMA32(); VMC6(); SBAR(); bR = (bR == 98304) ? 0 : bR + 24576;
  READ_FR(bR); MFMA32(); VMC3(); SBAR(); bR = (bR == 98304) ? 0 : bR + 24576;
  READ_FR(bR); MFMA32(); VMC0(); SBAR(); bR = (bR == 98304) ? 0 : bR + 24576;
  READ_FR(bR); MFMA32();
  __syncthreads();   // LDS now reusable

  // ---- acc (scaled by 2^-12) -> C1 tile bf16 in LDS [128 rows][264 u16] ----
  unsigned short* C1L = (unsigned short*)lds;
  {
    const int rb = wr2 * 64 + lq * 4;
    const int cbL = wc2 * 64 + lc;
    #pragma unroll
    for (int m = 0; m < 4; ++m)
      #pragma unroll
      for (int r = 0; r < 4; ++r) {
        const int row = rb + m * 16 + r;
        #pragma unroll
        for (int n = 0; n < 4; ++n)
          C1L[row * 264 + cbL + n * 16] = f2bf(acc[m][n][r] * 0.000244140625f);
      }
  }
  __syncthreads();

  // ---- MFMA GCN epilogue (round-11 proven): wave wid owns rows [wid*16, +16) ----
  {
    const f32x4 zacc = {0.f, 0.f, 0.f, 0.f};
    bf16x8 bw[4];
    float b1v[4], w2a[4], w2b[4];
    #pragma unroll
    for (int n = 0; n < 4; ++n) {
      const int h = n * 16 + lc;
      bw[n] = *(const bf16x8*)((const char*)w1t + h * 80 + lq * 16);
      b1v[n] = b1l[h];
      w2a[n] = w2l[h * 2];
      w2b[n] = w2l[h * 2 + 1];
    }
    const int rbase = wid * 16 + lq * 4;
    const float4 rs4 = *(const float4*)&rowsum[i0 + rbase];
    const float bo0 = b2l[0], bo1 = b2l[1];
    #pragma unroll
    for (int s = 0; s < 8; ++s) {
      bf16x8 afe = *(const bf16x8*)((const char*)C1L +
                     (wid * 16 + lc) * 528 + s * 64 + lq * 16);
      float o0r[4] = {0.f, 0.f, 0.f, 0.f};
      float o1r[4] = {0.f, 0.f, 0.f, 0.f};
      #pragma unroll
      for (int n = 0; n < 4; ++n) {
        f32x4 hq = __builtin_amdgcn_mfma_f32_16x16x32_bf16(afe, bw[n], zacc, 0, 0, 0);
        #pragma unroll
        for (int r = 0; r < 4; ++r) {
          float hv = hq[r] + rs4[r] * b1v[n];
          hv = hv > 0.f ? hv : 0.f;
          o0r[r] += hv * w2a[n];
          o1r[r] += hv * w2b[n];
        }
      }
      #pragma unroll
      for (int off = 1; off < 16; off <<= 1)
        #pragma unroll
        for (int r = 0; r < 4; ++r) {
          o0r[r] += __shfl_xor(o0r[r], off);
          o1r[r] += __shfl_xor(o1r[r], off);
        }
      if (lc == 0) {
        const int sg = (c0 >> 5) + s;
        #pragma unroll
        for (int r = 0; r < 4; ++r) {
          B2t[(size_t)(sg * 2 + 0) * 4096 + i0 + rbase + r] = f2bf(o0r[r] + bo0);
          B2t[(size_t)(sg * 2 + 1) * 4096 + i0 + rbase + r] = f2bf(o1r[r] + bo1);
        }
      }
    }
  }
}

// ---------------- shared MFMA GEMM core (m97-style, used by gemm2) ----------------
__device__ __forceinline__ void gemm_core(const unsigned short* __restrict__ A,
                                          const unsigned short* __restrict__ B,
                                          int i0, int c0, int k0base, int ksteps,
                                          f32x4 acc[4][4],
                                          unsigned short* Als, unsigned short* Bls) {
  const int tid = threadIdx.x;
  const int w = tid >> 6, l = tid & 63;
  const int srow = (l >> 2);
  const int scol = (l & 3) * 16;
  for (int kt = 0; kt < ksteps; ++kt) {
    int k0 = k0base + kt * 32;
    #pragma unroll
    for (int q = 0; q < 2; ++q) {
      int r = w * 32 + q * 16 + srow;
      const char* ga = (const char*)(A + (size_t)(i0 + r) * 4096 + k0) + scol;
      __builtin_amdgcn_global_load_lds(
          (const AS1 void*)ga,
          (AS3 void*)((char*)Als + w * 2048 + q * 1024), 16, 0, 0);
      const char* gb = (const char*)(B + (size_t)(c0 + r) * 4096 + k0) + scol;
      __builtin_amdgcn_global_load_lds(
          (const AS1 void*)gb,
          (AS3 void*)((char*)Bls + w * 2048 + q * 1024), 16, 0, 0);
    }
    __syncthreads();
    const int wr = w >> 1, wc = w & 1;
    bf16x8 af[4], bff[4];
    #pragma unroll
    for (int m = 0; m < 4; ++m)
      af[m] = *(const bf16x8*)(Als + (wr * 64 + m * 16 + (l & 15)) * 32 + (l >> 4) * 8);
    #pragma unroll
    for (int n = 0; n < 4; ++n)
      bff[n] = *(const bf16x8*)(Bls + (wc * 64 + n * 16 + (l & 15)) * 32 + (l >> 4) * 8);
    #pragma unroll
    for (int m = 0; m < 4; ++m)
      #pragma unroll
      for (int n = 0; n < 4; ++n)
        acc[m][n] = __builtin_amdgcn_mfma_f32_16x16x32_bf16(af[m], bff[n], acc[m][n], 0, 0, 0);
    __syncthreads();
  }
}

// ---------------- GEMM2 split-K: Gp[ks][i][c2] partial f32 ----------------
__global__ __launch_bounds__(256) void k_gemm2(const unsigned short* __restrict__ A,
                                               const unsigned short* __restrict__ B,
                                               float* __restrict__ Gp) {
  __shared__ unsigned short Als[128 * 32], Bls[128 * 32];
  int id = blockIdx.x;
  int bi = id & 31, ks = id >> 5;
  int i0 = bi * 128;
  f32x4 acc[4][4];
  #pragma unroll
  for (int m = 0; m < 4; ++m)
    #pragma unroll
    for (int n = 0; n < 4; ++n) acc[m][n] = {0.f, 0.f, 0.f, 0.f};
  gemm_core(A, B, i0, 0, ks * 512, 16, acc, Als, Bls);
  float* outp = Gp + (size_t)ks * 4096 * 128;
  int l = threadIdx.x & 63, w = threadIdx.x >> 6;
  int wr = w >> 1, wc = w & 1;
  int rbase = i0 + wr * 64 + (l >> 4) * 4;
  int cbase = wc * 64 + (l & 15);
  #pragma unroll
  for (int m = 0; m < 4; ++m)
    #pragma unroll
    for (int n = 0; n < 4; ++n)
      #pragma unroll
      for (int r = 0; r < 4; ++r)
        outp[(size_t)(rbase + m * 16 + r) * 128 + cbase + n * 16] = acc[m][n][r];
}

// ---------------- reduce split-K + log_softmax -> R[s][i*2+o] f32 ----------------
__global__ __launch_bounds__(256) void k_lsm(const float* __restrict__ Gp,
                                             float* __restrict__ Rm) {
  __shared__ float Gacc[32][130];
  int i0 = blockIdx.x * 32;
  int tid = threadIdx.x;
  float4 v[4];
  #pragma unroll
  for (int i = 0; i < 4; ++i) v[i] = {0.f, 0.f, 0.f, 0.f};
  for (int ks = 0; ks < 8; ++ks) {
    const float4* gp4 = ((const float4*)Gp) + (size_t)ks * 131072 + (size_t)i0 * 32;
    #pragma unroll
    for (int i = 0; i < 4; ++i) {
      float4 t = gp4[tid + i * 256];
      v[i].x += t.x; v[i].y += t.y; v[i].z += t.z; v[i].w += t.w;
    }
  }
  #pragma unroll
  for (int i = 0; i < 4; ++i) {
    int f4i = tid + i * 256, row = f4i >> 5, c = (f4i & 31) * 4;
    Gacc[row][c] = v[i].x; Gacc[row][c + 1] = v[i].y;
    Gacc[row][c + 2] = v[i].z; Gacc[row][c + 3] = v[i].w;
  }
  __syncthreads();
  #pragma unroll
  for (int j = 0; j < 8; ++j) {
    int p = j * 256 + tid;
    int ii = p & 31, s = p >> 5;
    float g0 = Gacc[ii][s * 2], g1 = Gacc[ii][s * 2 + 1];
    float m = fmaxf(g0, g1);
    float lse = m + logf(expf(g0 - m) + expf(g1 - m));
    float2 o_; o_.x = g0 - lse; o_.y = g1 - lse;
    *((float2*)(Rm + (size_t)s * 8192 + (size_t)(i0 + ii) * 2)) = o_;
  }
}

// ---------------- gi0 partial: part[ks][t][g] = R[t] . Wih0[g] over c-range ----------------
__global__ __launch_bounds__(256) void k_gi0(const float* __restrict__ Rm,
                                             const float* __restrict__ Wih0,
                                             float* __restrict__ part) {
  __shared__ float4 Wl[4 * 128];
  int gb = blockIdx.x % 48, ks = blockIdx.x / 48;
  int c0 = ks * 512;
  int tid = threadIdx.x;
  #pragma unroll
  for (int i = 0; i < 2; ++i) {
    int idx = tid + i * 256;
    int g = idx >> 7, c4 = idx & 127;
    Wl[g * 128 + c4] = ((const float4*)(Wih0 + (size_t)(gb * 4 + g) * 8192 + c0))[c4];
  }
  __syncthreads();
  int w = tid >> 6, lane = tid & 63;
  for (int pass = 0; pass < 16; ++pass) {
    int t = pass * 4 + w;
    float a0 = 0.f, a1 = 0.f, a2 = 0.f, a3 = 0.f;
    const float4* rg = (const float4*)(Rm + (size_t)t * 8192 + c0);
    #pragma unroll
    for (int i = 0; i < 2; ++i) {
      int c4 = i * 64 + lane;
      float4 r4 = rg[c4];
      float4 w0 = Wl[c4], w1 = Wl[128 + c4], w2 = Wl[256 + c4], w3 = Wl[384 + c4];
      a0 += r4.x * w0.x + r4.y * w0.y + r4.z * w0.z + r4.w * w0.w;
      a1 += r4.x * w1.x + r4.y * w1.y + r4.z * w1.z + r4.w * w1.w;
      a2 += r4.x * w2.x + r4.y * w2.y + r4.z * w2.z + r4.w * w2.w;
      a3 += r4.x * w3.x + r4.y * w3.y + r4.z * w3.z + r4.w * w3.w;
    }
    #pragma unroll
    for (int off = 1; off < 64; off <<= 1) {
      a0 += __shfl_xor(a0, off);
      a1 += __shfl_xor(a1, off);
      a2 += __shfl_xor(a2, off);
      a3 += __shfl_xor(a3, off);
    }
    if (lane == 0) {
      float4 o_; o_.x = a0; o_.y = a1; o_.z = a2; o_.w = a3;
      *((float4*)(part + ((size_t)ks * 64 + t) * 192 + gb * 4)) = o_;
    }
  }
}

__global__ __launch_bounds__(256) void k_gi0red(const float* __restrict__ part,
                                                const float* __restrict__ bih0,
                                                float* __restrict__ gi0) {
  int idx = blockIdx.x * 256 + threadIdx.x;
  if (idx < 12288) {
    float s_ = bih0[idx % 192];
    for (int ks = 0; ks < 16; ++ks) s_ += part[ks * 12288 + idx];
    gi0[idx] = s_;
  }
}

// =====================================================================
// MFMA GRU (unchanged — proven round 6)
// =====================================================================
__device__ __forceinline__ float fsigm(float x) {
  return __builtin_amdgcn_rcpf(1.f + __expf(-x));
}
__device__ __forceinline__ float ftanh(float x) {
  return 1.f - 2.f * __builtin_amdgcn_rcpf(1.f + __expf(2.f * x));
}

__global__ __launch_bounds__(384) void k_gru(const float* __restrict__ gi0,
                                             const float* __restrict__ Whh0,
                                             const float* __restrict__ bhh0,
                                             const float* __restrict__ Wih1,
                                             const float* __restrict__ Whh1,
                                             const float* __restrict__ bih1,
                                             const float* __restrict__ bhh1,
                                             float* __restrict__ out) {
  __shared__ float gil[64][192];
  __shared__ float gout[576];
  __shared__ __align__(16) unsigned short hv[2][64];
  const int tid = threadIdx.x;
  const int w = tid >> 6, l = tid & 63;
  const int matw = w >> 1, half = w & 1;
  const float* Wm = (matw == 0) ? Whh0 : (matw == 1 ? Wih1 : Whh1);
  const int mi = (matw == 2) ? 1 : 0;

  bf16x8 afr[6][2];
  #pragma unroll
  for (int rbi = 0; rbi < 6; ++rbi) {
    int g = (half * 6 + rbi) * 16 + (l & 15);
    #pragma unroll
    for (int kh = 0; kh < 2; ++kh) {
      int k0 = kh * 32 + (l >> 4) * 8;
      const float4* src = (const float4*)(Wm + (size_t)g * 64 + k0);
      float4 v0 = src[0], v1 = src[1];
      bf16x8 a;
      a[0] = (short)f2bf(v0.x); a[1] = (short)f2bf(v0.y);
      a[2] = (short)f2bf(v0.z); a[3] = (short)f2bf(v0.w);
      a[4] = (short)f2bf(v1.x); a[5] = (short)f2bf(v1.y);
      a[6] = (short)f2bf(v1.z); a[7] = (short)f2bf(v1.w);
      afr[rbi][kh] = a;
    }
  }
  {
    float4* gf = (float4*)&gil[0][0];
    const float4* gs = (const float4*)gi0;
    #pragma unroll
    for (int i = 0; i < 8; ++i) gf[i * 384 + tid] = gs[i * 384 + tid];
  }
  if (tid < 128) hv[tid >> 6][tid & 63] = 0;

  float hreg = 0.f;
  float bR = 0.f, bZ = 0.f, bNa = 0.f, bNb = 0.f;
  if (tid < 64) {
    bR = bhh0[tid]; bZ = bhh0[64 + tid]; bNa = bhh0[128 + tid];
  } else if (tid < 128) {
    int g = tid - 64;
    bR = bih1[g] + bhh1[g];
    bZ = bih1[64 + g] + bhh1[64 + g];
    bNa = bih1[128 + g];
    bNb = bhh1[128 + g];
  }
  asm volatile("s_waitcnt lgkmcnt(0)\n\ts_barrier" ::: "memory");

  const int gwb = matw * 192 + half * 96 + (l >> 4) * 4;
  const f32x4 zacc = {0.f, 0.f, 0.f, 0.f};

  for (int i = 0; i <= 64; ++i) {
    bf16x8 b0 = *(const bf16x8*)&hv[mi][(l >> 4) * 8];
    bf16x8 b1 = *(const bf16x8*)&hv[mi][32 + (l >> 4) * 8];
    #pragma unroll
    for (int rbi = 0; rbi < 6; ++rbi) {
      f32x4 a_ = __builtin_amdgcn_mfma_f32_16x16x32_bf16(afr[rbi][0], b0, zacc, 0, 0, 0);
      a_ = __builtin_amdgcn_mfma_f32_16x16x32_bf16(afr[rbi][1], b1, a_, 0, 0, 0);
      if (!(l & 15)) *(f32x4*)&gout[gwb + rbi * 16] = a_;
    }
    asm volatile("s_waitcnt lgkmcnt(0)\n\ts_barrier" ::: "memory");
    if (tid < 64) {
      if (i < 64) {
        float r = fsigm(gil[i][tid] + gout[tid] + bR);
        float z = fsigm(gil[i][64 + tid] + gout[64 + tid] + bZ);
        float n = ftanh(gil[i][128 + tid] + r * (gout[128 + tid] + bNa));
        hreg = (1.f - z) * n + z * hreg;
        hv[0][tid] = f2bf(hreg);
      }
    } else if (tid < 128 && i > 0) {
      int g = tid - 64;
      float r = fsigm(gout[192 + g] + gout[384 + g] + bR);
      float z = fsigm(gout[256 + g] + gout[448 + g] + bZ);
      float n = ftanh((gout[320 + g] + bNa) + r * (gout[512 + g] + bNb));
      hreg = (1.f - z) * n + z * hreg;
      hv[1][g] = f2bf(hreg);
      out[(i - 1) * 64 + g] = hreg;
    }
    asm volatile("s_waitcnt lgkmcnt(0)\n\ts_barrier" ::: "memory");
  }
  if (tid < 64) out[4096 + tid] = hreg;
  else if (tid < 128) out[4096 + 64 + (tid - 64)] = hreg;
}

extern "C" void kernel_launch(void* const* d_in, const int* in_sizes, int n_in,
                              void* d_out, int out_size, void* d_ws, size_t ws_size,
                              hipStream_t stream) {
  const float* x    = (const float*)d_in[0];
  const float* adj  = (const float*)d_in[1];
  const float* W1   = (const float*)d_in[2];
  const float* b1   = (const float*)d_in[3];
  const float* W2   = (const float*)d_in[4];
  const float* b2   = (const float*)d_in[5];
  const float* Wih0 = (const float*)d_in[6];
  const float* Whh0 = (const float*)d_in[7];
  const float* bih0 = (const float*)d_in[8];
  const float* bhh0 = (const float*)d_in[9];
  const float* Wih1 = (const float*)d_in[10];
  const float* Whh1 = (const float*)d_in[11];
  const float* bih1 = (const float*)d_in[12];
  const float* bhh1 = (const float*)d_in[13];
  float* out = (float*)d_out;

  char* ws = (char*)d_ws;
  unsigned short* adjb = (unsigned short*)ws;                      // 33.55MB (bf16, gemm2)
  unsigned char* adj8  = (unsigned char*)(ws + 33554432);          // 16.78MB (fp8 x4096)
  unsigned char* Xt8   = (unsigned char*)(ws + 50331648);          // 8.39MB  (fp8)
  float* rowsum        = (float*)(ws + 58720256);                  // 16KB
  float* Gp            = (float*)(ws + 58736640);                  // 16.78MB
  float* Rm            = (float*)(ws + 75513856);                  // 2MB
  float* part          = (float*)(ws + 77611008);                  // 768KB
  float* gi0           = (float*)(ws + 78397440);                  // 48KB
  unsigned short* B2t  = (unsigned short*)(ws + 78446592);         // 1MB

  k_prep<<<8192, 256, 0, stream>>>(adj, adjb, adj8, rowsum, x, Xt8);
  k_gemmAX<<<256, 512, 0, stream>>>(adj8, Xt8, rowsum, W1, b1, W2, b2, B2t);
  k_gemm2<<<256, 256, 0, stream>>>(adjb, B2t, Gp);
  k_lsm<<<128, 256, 0, stream>>>(Gp, Rm);
  k_gi0<<<768, 256, 0, stream>>>(Rm, Wih0, part);
  k_gi0red<<<48, 256, 0, stream>>>(part, bih0, gi0);
  k_gru<<<1, 384, 0, stream>>>(gi0, Whh0, bhh0, Wih1, Whh1, bih1, bhh1, out);
}

// Round 13
// 158.597 us; speedup vs baseline: 1.3992x; 1.0436x over previous
//
#include <hip/hip_runtime.h>
#include <stdint.h>

#define SS 64
#define NN 4096
#define FF 32
#define HH 64
#define OO 2
#define G3 192

typedef float f32x4 __attribute__((ext_vector_type(4)));
typedef short bf16x8 __attribute__((ext_vector_type(8)));
typedef unsigned short u16x8 __attribute__((ext_vector_type(8)));
typedef long longx2 __attribute__((ext_vector_type(2)));

#define AS1 __attribute__((address_space(1)))
#define AS3 __attribute__((address_space(3)))

__device__ __forceinline__ unsigned short f2bf(float f) {
  union { float f; uint32_t u; } v; v.f = f;
  uint32_t u = v.u;
  uint32_t r = (u + 0x7FFFu + ((u >> 16) & 1u)) >> 16;
  return (unsigned short)r;
}
__device__ __forceinline__ float bf2f(unsigned short s) {
  union { uint32_t u; float f; } v; v.u = ((uint32_t)s) << 16;
  return v.f;
}
// f32 -> OCP e4m3fn, RNE (hand-rolled; handles denormals & sign)
__device__ __forceinline__ unsigned char f2e4m3(float x) {
  float a = fabsf(x);
  unsigned s = (x < 0.f) ? 0x80u : 0u;
  if (a >= 448.f) return (unsigned char)(s | 0x7E);
  if (a < 0.015625f) {                      // below min normal 2^-6
    int q = (int)rintf(a * 512.f);          // units of 2^-9
    return (unsigned char)(s | (unsigned)q);
  }
  union { float f; uint32_t u; } v; v.f = a;
  uint32_t b = v.u + 0x7FFFFu + ((v.u >> 20) & 1u);
  int e = (int)(b >> 23) - 127;
  if (e > 8) return (unsigned char)(s | 0x7E);
  return (unsigned char)(s | (unsigned)(((e + 7) << 3) | ((b >> 20) & 7u)));
}

// ---------------- prep: adj -> adjb(bf16) + adj8(fp8 x4096, k-permuted) + rowsum
// ----------------       x -> Xt8[s*32+f][j] fp8 (k-permuted)
// k-permutation: within each 64B k-group, 8B block o -> position ((o&3)<<1)|(o>>2).
// New 16B chunk c = orig blocks {c, c+4} = k [c*8,+8) U [32+c*8,+8)  -> lane lq=c
// reads BOTH MFMA k-halves with ONE ds_read_b128 (round-6 proven conflict-free shape).
__global__ __launch_bounds__(256) void k_prep(const float* __restrict__ adj,
                                              unsigned short* __restrict__ adjb,
                                              unsigned char* __restrict__ adj8,
                                              float* __restrict__ rowsum,
                                              const float* __restrict__ x,
                                              unsigned char* __restrict__ Xt8) {
  __shared__ float xl[64][33];
  __shared__ float ps[4];
  int tid = threadIdx.x;
  if (blockIdx.x < 4096) {
    int row = blockIdx.x;
    const float4* src = (const float4*)(adj + (size_t)row * 4096);
    ushort4* dst = (ushort4*)(adjb + (size_t)row * 4096);
    uchar4* dst8 = (uchar4*)(adj8 + (size_t)row * 4096);
    float sum = 0.f;
    #pragma unroll
    for (int q = 0; q < 4; ++q) {
      int idx = q * 256 + tid;
      float4 v = src[idx];
      ushort4 r;
      r.x = f2bf(v.x); r.y = f2bf(v.y); r.z = f2bf(v.z); r.w = f2bf(v.w);
      dst[idx] = r;
      uchar4 r8;
      r8.x = f2e4m3(v.x * 4096.f); r8.y = f2e4m3(v.y * 4096.f);
      r8.z = f2e4m3(v.z * 4096.f); r8.w = f2e4m3(v.w * 4096.f);
      int o8 = (idx >> 1) & 7;
      int np = ((o8 & 3) << 1) | (o8 >> 2);
      int nidx = (idx & ~15) | (np << 1) | (idx & 1);
      dst8[nidx] = r8;
      sum += (v.x + v.y) + (v.z + v.w);
    }
    #pragma unroll
    for (int off = 1; off < 64; off <<= 1) sum += __shfl_xor(sum, off);
    if ((tid & 63) == 0) ps[tid >> 6] = sum;
    __syncthreads();
    if (tid == 0) rowsum[row] = (ps[0] + ps[1]) + (ps[2] + ps[3]);
    return;
  }
  int bs = blockIdx.x - 4096;
  int s = bs >> 6, jb = (bs & 63) << 6;
  const float4* xg = (const float4*)(x + ((size_t)s * NN + jb) * FF);
  #pragma unroll
  for (int ii = 0; ii < 2; ++ii) {
    int idx = tid + ii * 256;
    float4 v = xg[idx];
    int j = idx >> 3, f = (idx & 7) << 2;
    xl[j][f] = v.x; xl[j][f + 1] = v.y; xl[j][f + 2] = v.z; xl[j][f + 3] = v.w;
  }
  __syncthreads();
  int f = tid >> 3, jc = tid & 7;
  unsigned int lo = 0, hi = 0;
  #pragma unroll
  for (int jj = 0; jj < 4; ++jj) lo |= ((unsigned int)f2e4m3(xl[jc * 8 + jj][f])) << (jj * 8);
  #pragma unroll
  for (int jj = 0; jj < 4; ++jj) hi |= ((unsigned int)f2e4m3(xl[jc * 8 + 4 + jj][f])) << (jj * 8);
  uint2 ov; ov.x = lo; ov.y = hi;
  int np = ((jc & 3) << 1) | (jc >> 2);
  *(uint2*)(Xt8 + (size_t)(s * 32 + f) * 4096 + jb + np * 8) = ov;
}

// =====================================================================
// GEMM-AX fp8: C1 = (adj8 @ Xt8^T) * 2^-12.  M=4096 N=2048 K=4096.
// 128x256 tile, BK=64, 8 waves, FIVE 24KB LDS buffers, prefetch dist 4,
// vmcnt(9) counted (6/3/0 tail). Fragments: ONE ds_read_b128 per
// row-block (k-permuted global layout) with 4-chunk XOR swizzle ->
// conflict-free. MFMA epilogue: h=relu(C1@W1+rs*b1); B2t=h@W2+b2.
// =====================================================================
#define SBAR()   asm volatile("s_barrier" ::: "memory")
#define VMC9()   asm volatile("s_waitcnt vmcnt(9)" ::: "memory")
#define VMC6()   asm volatile("s_waitcnt vmcnt(6)" ::: "memory")
#define VMC3()   asm volatile("s_waitcnt vmcnt(3)" ::: "memory")
#define VMC0()   asm volatile("s_waitcnt vmcnt(0)" ::: "memory")

__global__ __launch_bounds__(512, 2) void k_gemmAX(
    const unsigned char* __restrict__ A8,
    const unsigned char* __restrict__ B8,
    const float* __restrict__ rowsum,
    const float* __restrict__ W1f,
    const float* __restrict__ b1f,
    const float* __restrict__ W2f,
    const float* __restrict__ b2f,
    unsigned short* __restrict__ B2t) {
  __shared__ __align__(16) char lds[122880];               // 5 x 24KB
  __shared__ __align__(16) unsigned short w1t[64 * 40];    // W1^T bf16, pad 40
  __shared__ float w2l[128];
  __shared__ float b1l[64];
  __shared__ float b2l[2];
  const int tid = threadIdx.x;
  const int wid = tid >> 6, l = tid & 63;
  const int wr2 = wid >> 2, wc2 = wid & 3;
  const int lc = l & 15, lq = l >> 4;

  // build w1t[h][f] = bf16(W1[f][h]); stage small weights
  {
    float4 v = ((const float4*)W1f)[tid];     // f = tid>>4, h = (tid&15)*4
    int f = tid >> 4, h = (tid & 15) * 4;
    w1t[(h + 0) * 40 + f] = f2bf(v.x);
    w1t[(h + 1) * 40 + f] = f2bf(v.y);
    w1t[(h + 2) * 40 + f] = f2bf(v.z);
    w1t[(h + 3) * 40 + f] = f2bf(v.w);
  }
  if (tid < 32) *(float4*)&w2l[tid * 4] = ((const float4*)W2f)[tid];
  if (tid < 16) *(float4*)&b1l[tid * 4] = ((const float4*)b1f)[tid];
  if (tid < 2) b2l[tid] = b2f[tid];
  __syncthreads();

  int bid = blockIdx.x;
  int swz = (bid & 7) * 32 + (bid >> 3);   // bijective XCD swizzle (256 = 8*32)
  const int i0 = (swz >> 3) * 128;         // 32 i-tiles
  const int c0 = (swz & 7) * 256;          // 8 sf-tiles

  // fragment-read lane constants (64B fp8 rows; 4-chunk XOR swizzle; b128)
  const int aBase = (wr2 * 64 + lc) * 64;
  const int bBase = 8192 + (wc2 * 64 + lc) * 64;
  const int aswz = (lc & 3) ^ ((lc >> 2) & 3);
  const int ckx = ((lq ^ aswz) << 4);

  // staging lane constants: linear LDS dest, inverse-swizzled global source
  const int srow = wid * 16 + (l >> 2);
  const int sswz = (srow & 3) ^ ((srow >> 2) & 3);
  const int scol = (((l & 3) ^ sswz) << 4);
  const char* gA = (const char*)A8 + (size_t)(i0 + srow) * 4096 + scol;
  const char* gB = (const char*)B8 + (size_t)(c0 + srow) * 4096 + scol;
  char* ldsW = (char*)lds + wid * 1024;
  const char* ldsR = (const char*)lds;

  f32x4 acc[4][4];
  #pragma unroll
  for (int m = 0; m < 4; ++m)
    #pragma unroll
    for (int n = 0; n < 4; ++n) acc[m][n] = {0.f, 0.f, 0.f, 0.f};

  longx2 afq[4], bfq[4];

#define STAGE3(KT, BOFS) do {                                                        \
    __builtin_amdgcn_global_load_lds((const AS1 void*)(gA + (KT) * 64),              \
        (AS3 void*)(ldsW + (BOFS)), 16, 0, 0);                                       \
    __builtin_amdgcn_global_load_lds((const AS1 void*)(gB + (KT) * 64),              \
        (AS3 void*)(ldsW + (BOFS) + 8192), 16, 0, 0);                                \
    __builtin_amdgcn_global_load_lds((const AS1 void*)(gB + 524288 + (KT) * 64),     \
        (AS3 void*)(ldsW + (BOFS) + 16384), 16, 0, 0);                               \
  } while (0)

#define READ_FR(BOFS) do {                                                           \
    _Pragma("unroll")                                                                \
    for (int _m = 0; _m < 4; ++_m)                                                   \
      afq[_m] = *(const longx2*)(ldsR + (BOFS) + aBase + _m * 1024 + ckx);           \
    _Pragma("unroll")                                                                \
    for (int _n = 0; _n < 4; ++_n)                                                   \
      bfq[_n] = *(const longx2*)(ldsR + (BOFS) + bBase + _n * 1024 + ckx);           \
  } while (0)

#define MFMA32() do {                                                                \
    __builtin_amdgcn_s_setprio(1);                                                   \
    _Pragma("unroll")                                                                \
    for (int _kk = 0; _kk < 2; ++_kk)                                                \
      _Pragma("unroll")                                                              \
      for (int _m = 0; _m < 4; ++_m)                                                 \
        _Pragma("unroll")                                                            \
        for (int _n = 0; _n < 4; ++_n)                                               \
          acc[_m][_n] = __builtin_amdgcn_mfma_f32_16x16x32_fp8_fp8(                  \
              afq[_m][_kk], bfq[_n][_kk], acc[_m][_n], 0, 0, 0);                     \
    __builtin_amdgcn_s_setprio(0);                                                   \
  } while (0)

  // Prologue: tiles 0..3 -> bufs 0..3 (12 ops); vmcnt(9) completes tile 0.
  STAGE3(0, 0);
  STAGE3(1, 24576);
  STAGE3(2, 49152);
  STAGE3(3, 73728);
  VMC9();
  SBAR();

  int bR = 0, bS = 98304;
  for (int kt = 0; kt < 60; ++kt) {
    READ_FR(bR);
    STAGE3(kt + 4, bS);
    MFMA32();
    VMC9();                  // tile kt+1 complete (dist-4 pipeline, 9 = 3 tiles x 3 ops)
    SBAR();
    bR = (bR == 98304) ? 0 : bR + 24576;
    bS = (bS == 98304) ? 0 : bS + 24576;
  }
  // tail: no more stages; drain 6/3/0
  READ_FR(bR); MFMA32(); VMC6(); SBAR(); bR = (bR == 98304) ? 0 : bR + 24576;
  READ_FR(bR); MFMA32(); VMC3(); SBAR(); bR = (bR == 98304) ? 0 : bR + 24576;
  READ_FR(bR); MFMA32(); VMC0(); SBAR(); bR = (bR == 98304) ? 0 : bR + 24576;
  READ_FR(bR); MFMA32();
  __syncthreads();   // LDS now reusable

  // ---- acc (scaled by 2^-12) -> C1 tile bf16 in LDS [128 rows][264 u16] ----
  unsigned short* C1L = (unsigned short*)lds;
  {
    const int rb = wr2 * 64 + lq * 4;
    const int cbL = wc2 * 64 + lc;
    #pragma unroll
    for (int m = 0; m < 4; ++m)
      #pragma unroll
      for (int r = 0; r < 4; ++r) {
        const int row = rb + m * 16 + r;
        #pragma unroll
        for (int n = 0; n < 4; ++n)
          C1L[row * 264 + cbL + n * 16] = f2bf(acc[m][n][r] * 0.000244140625f);
      }
  }
  __syncthreads();

  // ---- MFMA GCN epilogue (round-11 proven): wave wid owns rows [wid*16, +16) ----
  {
    const f32x4 zacc = {0.f, 0.f, 0.f, 0.f};
    bf16x8 bw[4];
    float b1v[4], w2a[4], w2b[4];
    #pragma unroll
    for (int n = 0; n < 4; ++n) {
      const int h = n * 16 + lc;
      bw[n] = *(const bf16x8*)((const char*)w1t + h * 80 + lq * 16);
      b1v[n] = b1l[h];
      w2a[n] = w2l[h * 2];
      w2b[n] = w2l[h * 2 + 1];
    }
    const int rbase = wid * 16 + lq * 4;
    const float4 rs4 = *(const float4*)&rowsum[i0 + rbase];
    const float bo0 = b2l[0], bo1 = b2l[1];
    #pragma unroll
    for (int s = 0; s < 8; ++s) {
      bf16x8 afe = *(const bf16x8*)((const char*)C1L +
                     (wid * 16 + lc) * 528 + s * 64 + lq * 16);
      float o0r[4] = {0.f, 0.f, 0.f, 0.f};
      float o1r[4] = {0.f, 0.f, 0.f, 0.f};
      #pragma unroll
      for (int n = 0; n < 4; ++n) {
        f32x4 hq = __builtin_amdgcn_mfma_f32_16x16x32_bf16(afe, bw[n], zacc, 0, 0, 0);
        #pragma unroll
        for (int r = 0; r < 4; ++r) {
          float hv = hq[r] + rs4[r] * b1v[n];
          hv = hv > 0.f ? hv : 0.f;
          o0r[r] += hv * w2a[n];
          o1r[r] += hv * w2b[n];
        }
      }
      #pragma unroll
      for (int off = 1; off < 16; off <<= 1)
        #pragma unroll
        for (int r = 0; r < 4; ++r) {
          o0r[r] += __shfl_xor(o0r[r], off);
          o1r[r] += __shfl_xor(o1r[r], off);
        }
      if (lc == 0) {
        const int sg = (c0 >> 5) + s;
        #pragma unroll
        for (int r = 0; r < 4; ++r) {
          B2t[(size_t)(sg * 2 + 0) * 4096 + i0 + rbase + r] = f2bf(o0r[r] + bo0);
          B2t[(size_t)(sg * 2 + 1) * 4096 + i0 + rbase + r] = f2bf(o1r[r] + bo1);
        }
      }
    }
  }
}

// ---------------- shared MFMA GEMM core (m97-style, used by gemm2) ----------------
__device__ __forceinline__ void gemm_core(const unsigned short* __restrict__ A,
                                          const unsigned short* __restrict__ B,
                                          int i0, int c0, int k0base, int ksteps,
                                          f32x4 acc[4][4],
                                          unsigned short* Als, unsigned short* Bls) {
  const int tid = threadIdx.x;
  const int w = tid >> 6, l = tid & 63;
  const int srow = (l >> 2);
  const int scol = (l & 3) * 16;
  for (int kt = 0; kt < ksteps; ++kt) {
    int k0 = k0base + kt * 32;
    #pragma unroll
    for (int q = 0; q < 2; ++q) {
      int r = w * 32 + q * 16 + srow;
      const char* ga = (const char*)(A + (size_t)(i0 + r) * 4096 + k0) + scol;
      __builtin_amdgcn_global_load_lds(
          (const AS1 void*)ga,
          (AS3 void*)((char*)Als + w * 2048 + q * 1024), 16, 0, 0);
      const char* gb = (const char*)(B + (size_t)(c0 + r) * 4096 + k0) + scol;
      __builtin_amdgcn_global_load_lds(
          (const AS1 void*)gb,
          (AS3 void*)((char*)Bls + w * 2048 + q * 1024), 16, 0, 0);
    }
    __syncthreads();
    const int wr = w >> 1, wc = w & 1;
    bf16x8 af[4], bff[4];
    #pragma unroll
    for (int m = 0; m < 4; ++m)
      af[m] = *(const bf16x8*)(Als + (wr * 64 + m * 16 + (l & 15)) * 32 + (l >> 4) * 8);
    #pragma unroll
    for (int n = 0; n < 4; ++n)
      bff[n] = *(const bf16x8*)(Bls + (wc * 64 + n * 16 + (l & 15)) * 32 + (l >> 4) * 8);
    #pragma unroll
    for (int m = 0; m < 4; ++m)
      #pragma unroll
      for (int n = 0; n < 4; ++n)
        acc[m][n] = __builtin_amdgcn_mfma_f32_16x16x32_bf16(af[m], bff[n], acc[m][n], 0, 0, 0);
    __syncthreads();
  }
}

// ---------------- GEMM2 split-K: Gp[ks][i][c2] partial f32 ----------------
__global__ __launch_bounds__(256) void k_gemm2(const unsigned short* __restrict__ A,
                                               const unsigned short* __restrict__ B,
                                               float* __restrict__ Gp) {
  __shared__ unsigned short Als[128 * 32], Bls[128 * 32];
  int id = blockIdx.x;
  int bi = id & 31, ks = id >> 5;
  int i0 = bi * 128;
  f32x4 acc[4][4];
  #pragma unroll
  for (int m = 0; m < 4; ++m)
    #pragma unroll
    for (int n = 0; n < 4; ++n) acc[m][n] = {0.f, 0.f, 0.f, 0.f};
  gemm_core(A, B, i0, 0, ks * 512, 16, acc, Als, Bls);
  float* outp = Gp + (size_t)ks * 4096 * 128;
  int l = threadIdx.x & 63, w = threadIdx.x >> 6;
  int wr = w >> 1, wc = w & 1;
  int rbase = i0 + wr * 64 + (l >> 4) * 4;
  int cbase = wc * 64 + (l & 15);
  #pragma unroll
  for (int m = 0; m < 4; ++m)
    #pragma unroll
    for (int n = 0; n < 4; ++n)
      #pragma unroll
      for (int r = 0; r < 4; ++r)
        outp[(size_t)(rbase + m * 16 + r) * 128 + cbase + n * 16] = acc[m][n][r];
}

// ---------------- reduce split-K + log_softmax -> R[s][i*2+o] f32 ----------------
__global__ __launch_bounds__(256) void k_lsm(const float* __restrict__ Gp,
                                             float* __restrict__ Rm) {
  __shared__ float Gacc[32][130];
  int i0 = blockIdx.x * 32;
  int tid = threadIdx.x;
  float4 v[4];
  #pragma unroll
  for (int i = 0; i < 4; ++i) v[i] = {0.f, 0.f, 0.f, 0.f};
  for (int ks = 0; ks < 8; ++ks) {
    const float4* gp4 = ((const float4*)Gp) + (size_t)ks * 131072 + (size_t)i0 * 32;
    #pragma unroll
    for (int i = 0; i < 4; ++i) {
      float4 t = gp4[tid + i * 256];
      v[i].x += t.x; v[i].y += t.y; v[i].z += t.z; v[i].w += t.w;
    }
  }
  #pragma unroll
  for (int i = 0; i < 4; ++i) {
    int f4i = tid + i * 256, row = f4i >> 5, c = (f4i & 31) * 4;
    Gacc[row][c] = v[i].x; Gacc[row][c + 1] = v[i].y;
    Gacc[row][c + 2] = v[i].z; Gacc[row][c + 3] = v[i].w;
  }
  __syncthreads();
  #pragma unroll
  for (int j = 0; j < 8; ++j) {
    int p = j * 256 + tid;
    int ii = p & 31, s = p >> 5;
    float g0 = Gacc[ii][s * 2], g1 = Gacc[ii][s * 2 + 1];
    float m = fmaxf(g0, g1);
    float lse = m + logf(expf(g0 - m) + expf(g1 - m));
    float2 o_; o_.x = g0 - lse; o_.y = g1 - lse;
    *((float2*)(Rm + (size_t)s * 8192 + (size_t)(i0 + ii) * 2)) = o_;
  }
}

// ---------------- gi0 partial: part[ks][t][g] = R[t] . Wih0[g] over c-range ----------------
__global__ __launch_bounds__(256) void k_gi0(const float* __restrict__ Rm,
                                             const float* __restrict__ Wih0,
                                             float* __restrict__ part) {
  __shared__ float4 Wl[4 * 128];
  int gb = blockIdx.x % 48, ks = blockIdx.x / 48;
  int c0 = ks * 512;
  int tid = threadIdx.x;
  #pragma unroll
  for (int i = 0; i < 2; ++i) {
    int idx = tid + i * 256;
    int g = idx >> 7, c4 = idx & 127;
    Wl[g * 128 + c4] = ((const float4*)(Wih0 + (size_t)(gb * 4 + g) * 8192 + c0))[c4];
  }
  __syncthreads();
  int w = tid >> 6, lane = tid & 63;
  for (int pass = 0; pass < 16; ++pass) {
    int t = pass * 4 + w;
    float a0 = 0.f, a1 = 0.f, a2 = 0.f, a3 = 0.f;
    const float4* rg = (const float4*)(Rm + (size_t)t * 8192 + c0);
    #pragma unroll
    for (int i = 0; i < 2; ++i) {
      int c4 = i * 64 + lane;
      float4 r4 = rg[c4];
      float4 w0 = Wl[c4], w1 = Wl[128 + c4], w2 = Wl[256 + c4], w3 = Wl[384 + c4];
      a0 += r4.x * w0.x + r4.y * w0.y + r4.z * w0.z + r4.w * w0.w;
      a1 += r4.x * w1.x + r4.y * w1.y + r4.z * w1.z + r4.w * w1.w;
      a2 += r4.x * w2.x + r4.y * w2.y + r4.z * w2.z + r4.w * w2.w;
      a3 += r4.x * w3.x + r4.y * w3.y + r4.z * w3.z + r4.w * w3.w;
    }
    #pragma unroll
    for (int off = 1; off < 64; off <<= 1) {
      a0 += __shfl_xor(a0, off);
      a1 += __shfl_xor(a1, off);
      a2 += __shfl_xor(a2, off);
      a3 += __shfl_xor(a3, off);
    }
    if (lane == 0) {
      float4 o_; o_.x = a0; o_.y = a1; o_.z = a2; o_.w = a3;
      *((float4*)(part + ((size_t)ks * 64 + t) * 192 + gb * 4)) = o_;
    }
  }
}

__global__ __launch_bounds__(256) void k_gi0red(const float* __restrict__ part,
                                                const float* __restrict__ bih0,
                                                float* __restrict__ gi0) {
  int idx = blockIdx.x * 256 + threadIdx.x;
  if (idx < 12288) {
    float s_ = bih0[idx % 192];
    for (int ks = 0; ks < 16; ++ks) s_ += part[ks * 12288 + idx];
    gi0[idx] = s_;
  }
}

// =====================================================================
// MFMA GRU (unchanged — proven round 6)
// =====================================================================
__device__ __forceinline__ float fsigm(float x) {
  return __builtin_amdgcn_rcpf(1.f + __expf(-x));
}
__device__ __forceinline__ float ftanh(float x) {
  return 1.f - 2.f * __builtin_amdgcn_rcpf(1.f + __expf(2.f * x));
}

__global__ __launch_bounds__(384) void k_gru(const float* __restrict__ gi0,
                                             const float* __restrict__ Whh0,
                                             const float* __restrict__ bhh0,
                                             const float* __restrict__ Wih1,
                                             const float* __restrict__ Whh1,
                                             const float* __restrict__ bih1,
                                             const float* __restrict__ bhh1,
                                             float* __restrict__ out) {
  __shared__ float gil[64][192];
  __shared__ float gout[576];
  __shared__ __align__(16) unsigned short hv[2][64];
  const int tid = threadIdx.x;
  const int w = tid >> 6, l = tid & 63;
  const int matw = w >> 1, half = w & 1;
  const float* Wm = (matw == 0) ? Whh0 : (matw == 1 ? Wih1 : Whh1);
  const int mi = (matw == 2) ? 1 : 0;

  bf16x8 afr[6][2];
  #pragma unroll
  for (int rbi = 0; rbi < 6; ++rbi) {
    int g = (half * 6 + rbi) * 16 + (l & 15);
    #pragma unroll
    for (int kh = 0; kh < 2; ++kh) {
      int k0 = kh * 32 + (l >> 4) * 8;
      const float4* src = (const float4*)(Wm + (size_t)g * 64 + k0);
      float4 v0 = src[0], v1 = src[1];
      bf16x8 a;
      a[0] = (short)f2bf(v0.x); a[1] = (short)f2bf(v0.y);
      a[2] = (short)f2bf(v0.z); a[3] = (short)f2bf(v0.w);
      a[4] = (short)f2bf(v1.x); a[5] = (short)f2bf(v1.y);
      a[6] = (short)f2bf(v1.z); a[7] = (short)f2bf(v1.w);
      afr[rbi][kh] = a;
    }
  }
  {
    float4* gf = (float4*)&gil[0][0];
    const float4* gs = (const float4*)gi0;
    #pragma unroll
    for (int i = 0; i < 8; ++i) gf[i * 384 + tid] = gs[i * 384 + tid];
  }
  if (tid < 128) hv[tid >> 6][tid & 63] = 0;

  float hreg = 0.f;
  float bR = 0.f, bZ = 0.f, bNa = 0.f, bNb = 0.f;
  if (tid < 64) {
    bR = bhh0[tid]; bZ = bhh0[64 + tid]; bNa = bhh0[128 + tid];
  } else if (tid < 128) {
    int g = tid - 64;
    bR = bih1[g] + bhh1[g];
    bZ = bih1[64 + g] + bhh1[64 + g];
    bNa = bih1[128 + g];
    bNb = bhh1[128 + g];
  }
  asm volatile("s_waitcnt lgkmcnt(0)\n\ts_barrier" ::: "memory");

  const int gwb = matw * 192 + half * 96 + (l >> 4) * 4;
  const f32x4 zacc = {0.f, 0.f, 0.f, 0.f};

  for (int i = 0; i <= 64; ++i) {
    bf16x8 b0 = *(const bf16x8*)&hv[mi][(l >> 4) * 8];
    bf16x8 b1 = *(const bf16x8*)&hv[mi][32 + (l >> 4) * 8];
    #pragma unroll
    for (int rbi = 0; rbi < 6; ++rbi) {
      f32x4 a_ = __builtin_amdgcn_mfma_f32_16x16x32_bf16(afr[rbi][0], b0, zacc, 0, 0, 0);
      a_ = __builtin_amdgcn_mfma_f32_16x16x32_bf16(afr[rbi][1], b1, a_, 0, 0, 0);
      if (!(l & 15)) *(f32x4*)&gout[gwb + rbi * 16] = a_;
    }
    asm volatile("s_waitcnt lgkmcnt(0)\n\ts_barrier" ::: "memory");
    if (tid < 64) {
      if (i < 64) {
        float r = fsigm(gil[i][tid] + gout[tid] + bR);
        float z = fsigm(gil[i][64 + tid] + gout[64 + tid] + bZ);
        float n = ftanh(gil[i][128 + tid] + r * (gout[128 + tid] + bNa));
        hreg = (1.f - z) * n + z * hreg;
        hv[0][tid] = f2bf(hreg);
      }
    } else if (tid < 128 && i > 0) {
      int g = tid - 64;
      float r = fsigm(gout[192 + g] + gout[384 + g] + bR);
      float z = fsigm(gout[256 + g] + gout[448 + g] + bZ);
      float n = ftanh((gout[320 + g] + bNa) + r * (gout[512 + g] + bNb));
      hreg = (1.f - z) * n + z * hreg;
      hv[1][g] = f2bf(hreg);
      out[(i - 1) * 64 + g] = hreg;
    }
    asm volatile("s_waitcnt lgkmcnt(0)\n\ts_barrier" ::: "memory");
  }
  if (tid < 64) out[4096 + tid] = hreg;
  else if (tid < 128) out[4096 + 64 + (tid - 64)] = hreg;
}

extern "C" void kernel_launch(void* const* d_in, const int* in_sizes, int n_in,
                              void* d_out, int out_size, void* d_ws, size_t ws_size,
                              hipStream_t stream) {
  const float* x    = (const float*)d_in[0];
  const float* adj  = (const float*)d_in[1];
  const float* W1   = (const float*)d_in[2];
  const float* b1   = (const float*)d_in[3];
  const float* W2   = (const float*)d_in[4];
  const float* b2   = (const float*)d_in[5];
  const float* Wih0 = (const float*)d_in[6];
  const float* Whh0 = (const float*)d_in[7];
  const float* bih0 = (const float*)d_in[8];
  const float* bhh0 = (const float*)d_in[9];
  const float* Wih1 = (const float*)d_in[10];
  const float* Whh1 = (const float*)d_in[11];
  const float* bih1 = (const float*)d_in[12];
  const float* bhh1 = (const float*)d_in[13];
  float* out = (float*)d_out;

  char* ws = (char*)d_ws;
  unsigned short* adjb = (unsigned short*)ws;                      // 33.55MB (bf16, gemm2)
  unsigned char* adj8  = (unsigned char*)(ws + 33554432);          // 16.78MB (fp8 x4096, k-perm)
  unsigned char* Xt8   = (unsigned char*)(ws + 50331648);          // 8.39MB  (fp8, k-perm)
  float* rowsum        = (float*)(ws + 58720256);                  // 16KB
  float* Gp            = (float*)(ws + 58736640);                  // 16.78MB
  float* Rm            = (float*)(ws + 75513856);                  // 2MB
  float* part          = (float*)(ws + 77611008);                  // 768KB
  float* gi0           = (float*)(ws + 78397440);                  // 48KB
  unsigned short* B2t  = (unsigned short*)(ws + 78446592);         // 1MB

  k_prep<<<8192, 256, 0, stream>>>(adj, adjb, adj8, rowsum, x, Xt8);
  k_gemmAX<<<256, 512, 0, stream>>>(adj8, Xt8, rowsum, W1, b1, W2, b2, B2t);
  k_gemm2<<<256, 256, 0, stream>>>(adjb, B2t, Gp);
  k_lsm<<<128, 256, 0, stream>>>(Gp, Rm);
  k_gi0<<<768, 256, 0, stream>>>(Rm, Wih0, part);
  k_gi0red<<<48, 256, 0, stream>>>(part, bih0, gi0);
  k_gru<<<1, 384, 0, stream>>>(gi0, Whh0, bhh0, Wih1, Whh1, bih1, bhh1, out);
}

// Round 14
// 151.506 us; speedup vs baseline: 1.4647x; 1.0468x over previous
//
#include <hip/hip_runtime.h>
#include <stdint.h>

#define SS 64
#define NN 4096
#define FF 32
#define HH 64
#define OO 2
#define G3 192

typedef float f32x4 __attribute__((ext_vector_type(4)));
typedef short bf16x8 __attribute__((ext_vector_type(8)));
typedef unsigned short u16x8 __attribute__((ext_vector_type(8)));
typedef long longx2 __attribute__((ext_vector_type(2)));

#define AS1 __attribute__((address_space(1)))
#define AS3 __attribute__((address_space(3)))

__device__ __forceinline__ unsigned short f2bf(float f) {
  union { float f; uint32_t u; } v; v.f = f;
  uint32_t u = v.u;
  uint32_t r = (u + 0x7FFFu + ((u >> 16) & 1u)) >> 16;
  return (unsigned short)r;
}
__device__ __forceinline__ float bf2f(unsigned short s) {
  union { uint32_t u; float f; } v; v.u = ((uint32_t)s) << 16;
  return v.f;
}
// f32 -> OCP e4m3fn, RNE (hand-rolled; handles denormals & sign)
__device__ __forceinline__ unsigned char f2e4m3(float x) {
  float a = fabsf(x);
  unsigned s = (x < 0.f) ? 0x80u : 0u;
  if (a >= 448.f) return (unsigned char)(s | 0x7E);
  if (a < 0.015625f) {                      // below min normal 2^-6
    int q = (int)rintf(a * 512.f);          // units of 2^-9
    return (unsigned char)(s | (unsigned)q);
  }
  union { float f; uint32_t u; } v; v.f = a;
  uint32_t b = v.u + 0x7FFFFu + ((v.u >> 20) & 1u);
  int e = (int)(b >> 23) - 127;
  if (e > 8) return (unsigned char)(s | 0x7E);
  return (unsigned char)(s | (unsigned)(((e + 7) << 3) | ((b >> 20) & 7u)));
}
// k-permutation within a 64B group (8B block o -> ((o&3)<<1)|(o>>2))
__device__ __forceinline__ int kperm_idx(int i) {
  int o8 = (i >> 3) & 7;
  int np = ((o8 & 3) << 1) | (o8 >> 2);
  return (i & ~63) | (np << 3) | (i & 7);
}

// ---------------- prep: adj -> adj8(fp8 x4096, k-permuted) + rowsum (blocks 0..4095)
// ----------------       x -> Xt8[s*32+f][j] fp8 (k-permuted)
__global__ __launch_bounds__(256) void k_prep(const float* __restrict__ adj,
                                              unsigned char* __restrict__ adj8,
                                              float* __restrict__ rowsum,
                                              const float* __restrict__ x,
                                              unsigned char* __restrict__ Xt8) {
  __shared__ float xl[64][33];
  __shared__ float ps[4];
  int tid = threadIdx.x;
  if (blockIdx.x < 4096) {
    int row = blockIdx.x;
    const float4* src = (const float4*)(adj + (size_t)row * 4096);
    uchar4* dst8 = (uchar4*)(adj8 + (size_t)row * 4096);
    float sum = 0.f;
    #pragma unroll
    for (int q = 0; q < 4; ++q) {
      int idx = q * 256 + tid;
      float4 v = src[idx];
      uchar4 r8;
      r8.x = f2e4m3(v.x * 4096.f); r8.y = f2e4m3(v.y * 4096.f);
      r8.z = f2e4m3(v.z * 4096.f); r8.w = f2e4m3(v.w * 4096.f);
      int o8 = (idx >> 1) & 7;
      int np = ((o8 & 3) << 1) | (o8 >> 2);
      int nidx = (idx & ~15) | (np << 1) | (idx & 1);
      dst8[nidx] = r8;
      sum += (v.x + v.y) + (v.z + v.w);
    }
    #pragma unroll
    for (int off = 1; off < 64; off <<= 1) sum += __shfl_xor(sum, off);
    if ((tid & 63) == 0) ps[tid >> 6] = sum;
    __syncthreads();
    if (tid == 0) rowsum[row] = (ps[0] + ps[1]) + (ps[2] + ps[3]);
    return;
  }
  int bs = blockIdx.x - 4096;
  int s = bs >> 6, jb = (bs & 63) << 6;
  const float4* xg = (const float4*)(x + ((size_t)s * NN + jb) * FF);
  #pragma unroll
  for (int ii = 0; ii < 2; ++ii) {
    int idx = tid + ii * 256;
    float4 v = xg[idx];
    int j = idx >> 3, f = (idx & 7) << 2;
    xl[j][f] = v.x; xl[j][f + 1] = v.y; xl[j][f + 2] = v.z; xl[j][f + 3] = v.w;
  }
  __syncthreads();
  int f = tid >> 3, jc = tid & 7;
  unsigned int lo = 0, hi = 0;
  #pragma unroll
  for (int jj = 0; jj < 4; ++jj) lo |= ((unsigned int)f2e4m3(xl[jc * 8 + jj][f])) << (jj * 8);
  #pragma unroll
  for (int jj = 0; jj < 4; ++jj) hi |= ((unsigned int)f2e4m3(xl[jc * 8 + 4 + jj][f])) << (jj * 8);
  uint2 ov; ov.x = lo; ov.y = hi;
  int np = ((jc & 3) << 1) | (jc >> 2);
  *(uint2*)(Xt8 + (size_t)(s * 32 + f) * 4096 + jb + np * 8) = ov;
}

// =====================================================================
// GEMM-AX fp8 (round-13 proven loop) + MFMA GCN epilogue.
// Output B2t8: fp8, x2^12, k-permuted along i (gemm2's K dimension).
// =====================================================================
#define SBAR()   asm volatile("s_barrier" ::: "memory")
#define VMC9()   asm volatile("s_waitcnt vmcnt(9)" ::: "memory")
#define VMC6()   asm volatile("s_waitcnt vmcnt(6)" ::: "memory")
#define VMC4()   asm volatile("s_waitcnt vmcnt(4)" ::: "memory")
#define VMC3()   asm volatile("s_waitcnt vmcnt(3)" ::: "memory")
#define VMC0()   asm volatile("s_waitcnt vmcnt(0)" ::: "memory")

__global__ __launch_bounds__(512, 2) void k_gemmAX(
    const unsigned char* __restrict__ A8,
    const unsigned char* __restrict__ B8,
    const float* __restrict__ rowsum,
    const float* __restrict__ W1f,
    const float* __restrict__ b1f,
    const float* __restrict__ W2f,
    const float* __restrict__ b2f,
    unsigned char* __restrict__ B2t8) {
  __shared__ __align__(16) char lds[122880];               // 5 x 24KB
  __shared__ __align__(16) unsigned short w1t[64 * 40];    // W1^T bf16, pad 40
  __shared__ float w2l[128];
  __shared__ float b1l[64];
  __shared__ float b2l[2];
  const int tid = threadIdx.x;
  const int wid = tid >> 6, l = tid & 63;
  const int wr2 = wid >> 2, wc2 = wid & 3;
  const int lc = l & 15, lq = l >> 4;

  {
    float4 v = ((const float4*)W1f)[tid];
    int f = tid >> 4, h = (tid & 15) * 4;
    w1t[(h + 0) * 40 + f] = f2bf(v.x);
    w1t[(h + 1) * 40 + f] = f2bf(v.y);
    w1t[(h + 2) * 40 + f] = f2bf(v.z);
    w1t[(h + 3) * 40 + f] = f2bf(v.w);
  }
  if (tid < 32) *(float4*)&w2l[tid * 4] = ((const float4*)W2f)[tid];
  if (tid < 16) *(float4*)&b1l[tid * 4] = ((const float4*)b1f)[tid];
  if (tid < 2) b2l[tid] = b2f[tid];
  __syncthreads();

  int bid = blockIdx.x;
  int swz = (bid & 7) * 32 + (bid >> 3);
  const int i0 = (swz >> 3) * 128;
  const int c0 = (swz & 7) * 256;

  const int aBase = (wr2 * 64 + lc) * 64;
  const int bBase = 8192 + (wc2 * 64 + lc) * 64;
  const int aswz = (lc & 3) ^ ((lc >> 2) & 3);
  const int ckx = ((lq ^ aswz) << 4);

  const int srow = wid * 16 + (l >> 2);
  const int sswz = (srow & 3) ^ ((srow >> 2) & 3);
  const int scol = (((l & 3) ^ sswz) << 4);
  const char* gA = (const char*)A8 + (size_t)(i0 + srow) * 4096 + scol;
  const char* gB = (const char*)B8 + (size_t)(c0 + srow) * 4096 + scol;
  char* ldsW = (char*)lds + wid * 1024;
  const char* ldsR = (const char*)lds;

  f32x4 acc[4][4];
  #pragma unroll
  for (int m = 0; m < 4; ++m)
    #pragma unroll
    for (int n = 0; n < 4; ++n) acc[m][n] = {0.f, 0.f, 0.f, 0.f};

  longx2 afq[4], bfq[4];

#define STAGE3(KT, BOFS) do {                                                        \
    __builtin_amdgcn_global_load_lds((const AS1 void*)(gA + (KT) * 64),              \
        (AS3 void*)(ldsW + (BOFS)), 16, 0, 0);                                       \
    __builtin_amdgcn_global_load_lds((const AS1 void*)(gB + (KT) * 64),              \
        (AS3 void*)(ldsW + (BOFS) + 8192), 16, 0, 0);                                \
    __builtin_amdgcn_global_load_lds((const AS1 void*)(gB + 524288 + (KT) * 64),     \
        (AS3 void*)(ldsW + (BOFS) + 16384), 16, 0, 0);                               \
  } while (0)

#define READ_FR(BOFS) do {                                                           \
    _Pragma("unroll")                                                                \
    for (int _m = 0; _m < 4; ++_m)                                                   \
      afq[_m] = *(const longx2*)(ldsR + (BOFS) + aBase + _m * 1024 + ckx);           \
    _Pragma("unroll")                                                                \
    for (int _n = 0; _n < 4; ++_n)                                                   \
      bfq[_n] = *(const longx2*)(ldsR + (BOFS) + bBase + _n * 1024 + ckx);           \
  } while (0)

#define MFMA32() do {                                                                \
    __builtin_amdgcn_s_setprio(1);                                                   \
    _Pragma("unroll")                                                                \
    for (int _kk = 0; _kk < 2; ++_kk)                                                \
      _Pragma("unroll")                                                              \
      for (int _m = 0; _m < 4; ++_m)                                                 \
        _Pragma("unroll")                                                            \
        for (int _n = 0; _n < 4; ++_n)                                               \
          acc[_m][_n] = __builtin_amdgcn_mfma_f32_16x16x32_fp8_fp8(                  \
              afq[_m][_kk], bfq[_n][_kk], acc[_m][_n], 0, 0, 0);                     \
    __builtin_amdgcn_s_setprio(0);                                                   \
  } while (0)

  STAGE3(0, 0);
  STAGE3(1, 24576);
  STAGE3(2, 49152);
  STAGE3(3, 73728);
  VMC9();
  SBAR();

  int bR = 0, bS = 98304;
  for (int kt = 0; kt < 60; ++kt) {
    READ_FR(bR);
    STAGE3(kt + 4, bS);
    MFMA32();
    VMC9();
    SBAR();
    bR = (bR == 98304) ? 0 : bR + 24576;
    bS = (bS == 98304) ? 0 : bS + 24576;
  }
  READ_FR(bR); MFMA32(); VMC6(); SBAR(); bR = (bR == 98304) ? 0 : bR + 24576;
  READ_FR(bR); MFMA32(); VMC3(); SBAR(); bR = (bR == 98304) ? 0 : bR + 24576;
  READ_FR(bR); MFMA32(); VMC0(); SBAR(); bR = (bR == 98304) ? 0 : bR + 24576;
  READ_FR(bR); MFMA32();
  __syncthreads();

  // ---- acc (x 2^-12) -> C1 tile bf16 in LDS [128 rows][264 u16] ----
  unsigned short* C1L = (unsigned short*)lds;
  {
    const int rb = wr2 * 64 + lq * 4;
    const int cbL = wc2 * 64 + lc;
    #pragma unroll
    for (int m = 0; m < 4; ++m)
      #pragma unroll
      for (int r = 0; r < 4; ++r) {
        const int row = rb + m * 16 + r;
        #pragma unroll
        for (int n = 0; n < 4; ++n)
          C1L[row * 264 + cbL + n * 16] = f2bf(acc[m][n][r] * 0.000244140625f);
      }
  }
  __syncthreads();

  // ---- MFMA GCN epilogue; B2t8 = fp8(val * 2^12), k-permuted along i ----
  {
    const f32x4 zacc = {0.f, 0.f, 0.f, 0.f};
    bf16x8 bw[4];
    float b1v[4], w2a[4], w2b[4];
    #pragma unroll
    for (int n = 0; n < 4; ++n) {
      const int h = n * 16 + lc;
      bw[n] = *(const bf16x8*)((const char*)w1t + h * 80 + lq * 16);
      b1v[n] = b1l[h];
      w2a[n] = w2l[h * 2];
      w2b[n] = w2l[h * 2 + 1];
    }
    const int rbase = wid * 16 + lq * 4;
    const float4 rs4 = *(const float4*)&rowsum[i0 + rbase];
    const float bo0 = b2l[0], bo1 = b2l[1];
    #pragma unroll
    for (int s = 0; s < 8; ++s) {
      bf16x8 afe = *(const bf16x8*)((const char*)C1L +
                     (wid * 16 + lc) * 528 + s * 64 + lq * 16);
      float o0r[4] = {0.f, 0.f, 0.f, 0.f};
      float o1r[4] = {0.f, 0.f, 0.f, 0.f};
      #pragma unroll
      for (int n = 0; n < 4; ++n) {
        f32x4 hq = __builtin_amdgcn_mfma_f32_16x16x32_bf16(afe, bw[n], zacc, 0, 0, 0);
        #pragma unroll
        for (int r = 0; r < 4; ++r) {
          float hv = hq[r] + rs4[r] * b1v[n];
          hv = hv > 0.f ? hv : 0.f;
          o0r[r] += hv * w2a[n];
          o1r[r] += hv * w2b[n];
        }
      }
      #pragma unroll
      for (int off = 1; off < 16; off <<= 1)
        #pragma unroll
        for (int r = 0; r < 4; ++r) {
          o0r[r] += __shfl_xor(o0r[r], off);
          o1r[r] += __shfl_xor(o1r[r], off);
        }
      if (lc == 0) {
        const int sg = (c0 >> 5) + s;
        #pragma unroll
        for (int r = 0; r < 4; ++r) {
          const int ip = kperm_idx(i0 + rbase + r);
          B2t8[(size_t)(sg * 2 + 0) * 4096 + ip] = f2e4m3((o0r[r] + bo0) * 4096.f);
          B2t8[(size_t)(sg * 2 + 1) * 4096 + ip] = f2e4m3((o1r[r] + bo1) * 4096.f);
        }
      }
    }
  }
}

// =====================================================================
// GEMM2 fp8 split-K: Gp[ks][i][c2] = (adj8 @ B2t8^T) * 2^-24 over K-range.
// 128x128 tile, 4 waves (2x2), 8 BK=64 tiles, 3x16KB buffers, dist-2,
// counted vmcnt(4). Same proven fragment/staging geometry as gemmAX.
// =====================================================================
__global__ __launch_bounds__(256) void k_gemm2f8(
    const unsigned char* __restrict__ A8,
    const unsigned char* __restrict__ B8,
    float* __restrict__ Gp) {
  __shared__ __align__(16) char lds[49152];   // 3 x 16KB
  const int tid = threadIdx.x;
  const int wid = tid >> 6, l = tid & 63;
  const int wr = wid >> 1, wc = wid & 1;
  const int lc = l & 15, lq = l >> 4;
  const int bi = blockIdx.x & 31, ks = blockIdx.x >> 5;
  const int i0 = bi * 128;
  const size_t kbase = (size_t)ks * 512;

  const int aBase = (wr * 64 + lc) * 64;
  const int bBase = 8192 + (wc * 64 + lc) * 64;
  const int aswz = (lc & 3) ^ ((lc >> 2) & 3);
  const int ckx = ((lq ^ aswz) << 4);

  const int srow = wid * 16 + (l >> 2);          // 0..63
  const int sswz = (srow & 3) ^ ((srow >> 2) & 3);
  const int scol = (((l & 3) ^ sswz) << 4);
  const char* gA = (const char*)A8 + (size_t)(i0 + srow) * 4096 + kbase + scol;
  const char* gB = (const char*)B8 + (size_t)srow * 4096 + kbase + scol;
  char* ldsW = (char*)lds + wid * 1024;
  const char* ldsR = (const char*)lds;

  f32x4 acc[4][4];
  #pragma unroll
  for (int m = 0; m < 4; ++m)
    #pragma unroll
    for (int n = 0; n < 4; ++n) acc[m][n] = {0.f, 0.f, 0.f, 0.f};

  longx2 afq[4], bfq[4];

#define G2STAGE(KT, BOFS) do {                                                       \
    __builtin_amdgcn_global_load_lds((const AS1 void*)(gA + (KT) * 64),              \
        (AS3 void*)(ldsW + (BOFS)), 16, 0, 0);                                       \
    __builtin_amdgcn_global_load_lds((const AS1 void*)(gA + 262144 + (KT) * 64),     \
        (AS3 void*)(ldsW + (BOFS) + 4096), 16, 0, 0);                                \
    __builtin_amdgcn_global_load_lds((const AS1 void*)(gB + (KT) * 64),              \
        (AS3 void*)(ldsW + (BOFS) + 8192), 16, 0, 0);                                \
    __builtin_amdgcn_global_load_lds((const AS1 void*)(gB + 262144 + (KT) * 64),     \
        (AS3 void*)(ldsW + (BOFS) + 12288), 16, 0, 0);                               \
  } while (0)

#define G2READ(BOFS) do {                                                            \
    _Pragma("unroll")                                                                \
    for (int _m = 0; _m < 4; ++_m)                                                   \
      afq[_m] = *(const longx2*)(ldsR + (BOFS) + aBase + _m * 1024 + ckx);           \
    _Pragma("unroll")                                                                \
    for (int _n = 0; _n < 4; ++_n)                                                   \
      bfq[_n] = *(const longx2*)(ldsR + (BOFS) + bBase + _n * 1024 + ckx);           \
  } while (0)

#define G2MFMA() do {                                                                \
    __builtin_amdgcn_s_setprio(1);                                                   \
    _Pragma("unroll")                                                                \
    for (int _kk = 0; _kk < 2; ++_kk)                                                \
      _Pragma("unroll")                                                              \
      for (int _m = 0; _m < 4; ++_m)                                                 \
        _Pragma("unroll")                                                            \
        for (int _n = 0; _n < 4; ++_n)                                               \
          acc[_m][_n] = __builtin_amdgcn_mfma_f32_16x16x32_fp8_fp8(                  \
              afq[_m][_kk], bfq[_n][_kk], acc[_m][_n], 0, 0, 0);                     \
    __builtin_amdgcn_s_setprio(0);                                                   \
  } while (0)

  G2STAGE(0, 0);
  G2STAGE(1, 16384);
  VMC4();
  SBAR();

  int bR = 0, bS = 32768;
  for (int kt = 0; kt < 6; ++kt) {
    G2READ(bR);
    G2STAGE(kt + 2, bS);
    G2MFMA();
    VMC4();
    SBAR();
    bR = (bR == 32768) ? 0 : bR + 16384;
    bS = (bS == 32768) ? 0 : bS + 16384;
  }
  G2READ(bR); G2MFMA(); VMC0(); SBAR(); bR = (bR == 32768) ? 0 : bR + 16384;
  G2READ(bR); G2MFMA();

  float* outp = Gp + (size_t)ks * 524288;
  const int rbase = i0 + wr * 64 + lq * 4;
  const int cbase = wc * 64 + lc;
  #pragma unroll
  for (int m = 0; m < 4; ++m)
    #pragma unroll
    for (int n = 0; n < 4; ++n)
      #pragma unroll
      for (int r = 0; r < 4; ++r)
        outp[(size_t)(rbase + m * 16 + r) * 128 + cbase + n * 16] =
            acc[m][n][r] * 5.9604644775390625e-8f;   // 2^-24
}

// ---------------- reduce split-K + log_softmax -> R[s][i*2+o] f32 ----------------
__global__ __launch_bounds__(256) void k_lsm(const float* __restrict__ Gp,
                                             float* __restrict__ Rm) {
  __shared__ float Gacc[32][130];
  int i0 = blockIdx.x * 32;
  int tid = threadIdx.x;
  float4 v[4];
  #pragma unroll
  for (int i = 0; i < 4; ++i) v[i] = {0.f, 0.f, 0.f, 0.f};
  for (int ks = 0; ks < 8; ++ks) {
    const float4* gp4 = ((const float4*)Gp) + (size_t)ks * 131072 + (size_t)i0 * 32;
    #pragma unroll
    for (int i = 0; i < 4; ++i) {
      float4 t = gp4[tid + i * 256];
      v[i].x += t.x; v[i].y += t.y; v[i].z += t.z; v[i].w += t.w;
    }
  }
  #pragma unroll
  for (int i = 0; i < 4; ++i) {
    int f4i = tid + i * 256, row = f4i >> 5, c = (f4i & 31) * 4;
    Gacc[row][c] = v[i].x; Gacc[row][c + 1] = v[i].y;
    Gacc[row][c + 2] = v[i].z; Gacc[row][c + 3] = v[i].w;
  }
  __syncthreads();
  #pragma unroll
  for (int j = 0; j < 8; ++j) {
    int p = j * 256 + tid;
    int ii = p & 31, s = p >> 5;
    float g0 = Gacc[ii][s * 2], g1 = Gacc[ii][s * 2 + 1];
    float m = fmaxf(g0, g1);
    float lse = m + logf(expf(g0 - m) + expf(g1 - m));
    float2 o_; o_.x = g0 - lse; o_.y = g1 - lse;
    *((float2*)(Rm + (size_t)s * 8192 + (size_t)(i0 + ii) * 2)) = o_;
  }
}

// ---------------- gi0 partial: part[ks][t][g] = R[t] . Wih0[g] over c-range ----------------
__global__ __launch_bounds__(256) void k_gi0(const float* __restrict__ Rm,
                                             const float* __restrict__ Wih0,
                                             float* __restrict__ part) {
  __shared__ float4 Wl[4 * 128];
  int gb = blockIdx.x % 48, ks = blockIdx.x / 48;
  int c0 = ks * 512;
  int tid = threadIdx.x;
  #pragma unroll
  for (int i = 0; i < 2; ++i) {
    int idx = tid + i * 256;
    int g = idx >> 7, c4 = idx & 127;
    Wl[g * 128 + c4] = ((const float4*)(Wih0 + (size_t)(gb * 4 + g) * 8192 + c0))[c4];
  }
  __syncthreads();
  int w = tid >> 6, lane = tid & 63;
  for (int pass = 0; pass < 16; ++pass) {
    int t = pass * 4 + w;
    float a0 = 0.f, a1 = 0.f, a2 = 0.f, a3 = 0.f;
    const float4* rg = (const float4*)(Rm + (size_t)t * 8192 + c0);
    #pragma unroll
    for (int i = 0; i < 2; ++i) {
      int c4 = i * 64 + lane;
      float4 r4 = rg[c4];
      float4 w0 = Wl[c4], w1 = Wl[128 + c4], w2 = Wl[256 + c4], w3 = Wl[384 + c4];
      a0 += r4.x * w0.x + r4.y * w0.y + r4.z * w0.z + r4.w * w0.w;
      a1 += r4.x * w1.x + r4.y * w1.y + r4.z * w1.z + r4.w * w1.w;
      a2 += r4.x * w2.x + r4.y * w2.y + r4.z * w2.z + r4.w * w2.w;
      a3 += r4.x * w3.x + r4.y * w3.y + r4.z * w3.z + r4.w * w3.w;
    }
    #pragma unroll
    for (int off = 1; off < 64; off <<= 1) {
      a0 += __shfl_xor(a0, off);
      a1 += __shfl_xor(a1, off);
      a2 += __shfl_xor(a2, off);
      a3 += __shfl_xor(a3, off);
    }
    if (lane == 0) {
      float4 o_; o_.x = a0; o_.y = a1; o_.z = a2; o_.w = a3;
      *((float4*)(part + ((size_t)ks * 64 + t) * 192 + gb * 4)) = o_;
    }
  }
}

__global__ __launch_bounds__(256) void k_gi0red(const float* __restrict__ part,
                                                const float* __restrict__ bih0,
                                                float* __restrict__ gi0) {
  int idx = blockIdx.x * 256 + threadIdx.x;
  if (idx < 12288) {
    float s_ = bih0[idx % 192];
    for (int ks = 0; ks < 16; ++ks) s_ += part[ks * 12288 + idx];
    gi0[idx] = s_;
  }
}

// =====================================================================
// MFMA GRU (unchanged — proven round 6)
// =====================================================================
__device__ __forceinline__ float fsigm(float x) {
  return __builtin_amdgcn_rcpf(1.f + __expf(-x));
}
__device__ __forceinline__ float ftanh(float x) {
  return 1.f - 2.f * __builtin_amdgcn_rcpf(1.f + __expf(2.f * x));
}

__global__ __launch_bounds__(384) void k_gru(const float* __restrict__ gi0,
                                             const float* __restrict__ Whh0,
                                             const float* __restrict__ bhh0,
                                             const float* __restrict__ Wih1,
                                             const float* __restrict__ Whh1,
                                             const float* __restrict__ bih1,
                                             const float* __restrict__ bhh1,
                                             float* __restrict__ out) {
  __shared__ float gil[64][192];
  __shared__ float gout[576];
  __shared__ __align__(16) unsigned short hv[2][64];
  const int tid = threadIdx.x;
  const int w = tid >> 6, l = tid & 63;
  const int matw = w >> 1, half = w & 1;
  const float* Wm = (matw == 0) ? Whh0 : (matw == 1 ? Wih1 : Whh1);
  const int mi = (matw == 2) ? 1 : 0;

  bf16x8 afr[6][2];
  #pragma unroll
  for (int rbi = 0; rbi < 6; ++rbi) {
    int g = (half * 6 + rbi) * 16 + (l & 15);
    #pragma unroll
    for (int kh = 0; kh < 2; ++kh) {
      int k0 = kh * 32 + (l >> 4) * 8;
      const float4* src = (const float4*)(Wm + (size_t)g * 64 + k0);
      float4 v0 = src[0], v1 = src[1];
      bf16x8 a;
      a[0] = (short)f2bf(v0.x); a[1] = (short)f2bf(v0.y);
      a[2] = (short)f2bf(v0.z); a[3] = (short)f2bf(v0.w);
      a[4] = (short)f2bf(v1.x); a[5] = (short)f2bf(v1.y);
      a[6] = (short)f2bf(v1.z); a[7] = (short)f2bf(v1.w);
      afr[rbi][kh] = a;
    }
  }
  {
    float4* gf = (float4*)&gil[0][0];
    const float4* gs = (const float4*)gi0;
    #pragma unroll
    for (int i = 0; i < 8; ++i) gf[i * 384 + tid] = gs[i * 384 + tid];
  }
  if (tid < 128) hv[tid >> 6][tid & 63] = 0;

  float hreg = 0.f;
  float bR = 0.f, bZ = 0.f, bNa = 0.f, bNb = 0.f;
  if (tid < 64) {
    bR = bhh0[tid]; bZ = bhh0[64 + tid]; bNa = bhh0[128 + tid];
  } else if (tid < 128) {
    int g = tid - 64;
    bR = bih1[g] + bhh1[g];
    bZ = bih1[64 + g] + bhh1[64 + g];
    bNa = bih1[128 + g];
    bNb = bhh1[128 + g];
  }
  asm volatile("s_waitcnt lgkmcnt(0)\n\ts_barrier" ::: "memory");

  const int gwb = matw * 192 + half * 96 + (l >> 4) * 4;
  const f32x4 zacc = {0.f, 0.f, 0.f, 0.f};

  for (int i = 0; i <= 64; ++i) {
    bf16x8 b0 = *(const bf16x8*)&hv[mi][(l >> 4) * 8];
    bf16x8 b1 = *(const bf16x8*)&hv[mi][32 + (l >> 4) * 8];
    #pragma unroll
    for (int rbi = 0; rbi < 6; ++rbi) {
      f32x4 a_ = __builtin_amdgcn_mfma_f32_16x16x32_bf16(afr[rbi][0], b0, zacc, 0, 0, 0);
      a_ = __builtin_amdgcn_mfma_f32_16x16x32_bf16(afr[rbi][1], b1, a_, 0, 0, 0);
      if (!(l & 15)) *(f32x4*)&gout[gwb + rbi * 16] = a_;
    }
    asm volatile("s_waitcnt lgkmcnt(0)\n\ts_barrier" ::: "memory");
    if (tid < 64) {
      if (i < 64) {
        float r = fsigm(gil[i][tid] + gout[tid] + bR);
        float z = fsigm(gil[i][64 + tid] + gout[64 + tid] + bZ);
        float n = ftanh(gil[i][128 + tid] + r * (gout[128 + tid] + bNa));
        hreg = (1.f - z) * n + z * hreg;
        hv[0][tid] = f2bf(hreg);
      }
    } else if (tid < 128 && i > 0) {
      int g = tid - 64;
      float r = fsigm(gout[192 + g] + gout[384 + g] + bR);
      float z = fsigm(gout[256 + g] + gout[448 + g] + bZ);
      float n = ftanh((gout[320 + g] + bNa) + r * (gout[512 + g] + bNb));
      hreg = (1.f - z) * n + z * hreg;
      hv[1][g] = f2bf(hreg);
      out[(i - 1) * 64 + g] = hreg;
    }
    asm volatile("s_waitcnt lgkmcnt(0)\n\ts_barrier" ::: "memory");
  }
  if (tid < 64) out[4096 + tid] = hreg;
  else if (tid < 128) out[4096 + 64 + (tid - 64)] = hreg;
}

extern "C" void kernel_launch(void* const* d_in, const int* in_sizes, int n_in,
                              void* d_out, int out_size, void* d_ws, size_t ws_size,
                              hipStream_t stream) {
  const float* x    = (const float*)d_in[0];
  const float* adj  = (const float*)d_in[1];
  const float* W1   = (const float*)d_in[2];
  const float* b1   = (const float*)d_in[3];
  const float* W2   = (const float*)d_in[4];
  const float* b2   = (const float*)d_in[5];
  const float* Wih0 = (const float*)d_in[6];
  const float* Whh0 = (const float*)d_in[7];
  const float* bih0 = (const float*)d_in[8];
  const float* bhh0 = (const float*)d_in[9];
  const float* Wih1 = (const float*)d_in[10];
  const float* Whh1 = (const float*)d_in[11];
  const float* bih1 = (const float*)d_in[12];
  const float* bhh1 = (const float*)d_in[13];
  float* out = (float*)d_out;

  char* ws = (char*)d_ws;
  unsigned char* adj8  = (unsigned char*)ws;                       // 16.78MB (fp8 x2^12, k-perm)
  unsigned char* Xt8   = (unsigned char*)(ws + 16777216);          // 8.39MB  (fp8, k-perm)
  float* rowsum        = (float*)(ws + 25165824);                  // 16KB
  float* Gp            = (float*)(ws + 25182208);                  // 16.78MB
  float* Rm            = (float*)(ws + 41959424);                  // 2MB
  float* part          = (float*)(ws + 44056576);                  // 768KB
  float* gi0           = (float*)(ws + 44843008);                  // 48KB
  unsigned char* B2t8  = (unsigned char*)(ws + 44892160);          // 512KB (fp8 x2^12, k-perm)

  k_prep<<<8192, 256, 0, stream>>>(adj, adj8, rowsum, x, Xt8);
  k_gemmAX<<<256, 512, 0, stream>>>(adj8, Xt8, rowsum, W1, b1, W2, b2, B2t8);
  k_gemm2f8<<<256, 256, 0, stream>>>(adj8, B2t8, Gp);
  k_lsm<<<128, 256, 0, stream>>>(Gp, Rm);
  k_gi0<<<768, 256, 0, stream>>>(Rm, Wih0, part);
  k_gi0red<<<48, 256, 0, stream>>>(part, bih0, gi0);
  k_gru<<<1, 384, 0, stream>>>(gi0, Whh0, bhh0, Wih1, Whh1, bih1, bhh1, out);
}

// Round 15
// 148.923 us; speedup vs baseline: 1.4901x; 1.0173x over previous
//
#include <hip/hip_runtime.h>
#include <stdint.h>

#define SS 64
#define NN 4096
#define FF 32
#define HH 64
#define OO 2
#define G3 192

typedef float f32x4 __attribute__((ext_vector_type(4)));
typedef short bf16x8 __attribute__((ext_vector_type(8)));
typedef unsigned short u16x8 __attribute__((ext_vector_type(8)));
typedef long longx2 __attribute__((ext_vector_type(2)));

#define AS1 __attribute__((address_space(1)))
#define AS3 __attribute__((address_space(3)))

__device__ __forceinline__ unsigned short f2bf(float f) {
  union { float f; uint32_t u; } v; v.f = f;
  uint32_t u = v.u;
  uint32_t r = (u + 0x7FFFu + ((u >> 16) & 1u)) >> 16;
  return (unsigned short)r;
}
__device__ __forceinline__ float bf2f(unsigned short s) {
  union { uint32_t u; float f; } v; v.u = ((uint32_t)s) << 16;
  return v.f;
}
// f32 -> OCP e4m3fn, RNE
__device__ __forceinline__ unsigned char f2e4m3(float x) {
  float a = fabsf(x);
  unsigned s = (x < 0.f) ? 0x80u : 0u;
  if (a >= 448.f) return (unsigned char)(s | 0x7E);
  if (a < 0.015625f) {
    int q = (int)rintf(a * 512.f);
    return (unsigned char)(s | (unsigned)q);
  }
  union { float f; uint32_t u; } v; v.f = a;
  uint32_t b = v.u + 0x7FFFFu + ((v.u >> 20) & 1u);
  int e = (int)(b >> 23) - 127;
  if (e > 8) return (unsigned char)(s | 0x7E);
  return (unsigned char)(s | (unsigned)(((e + 7) << 3) | ((b >> 20) & 7u)));
}
// k-permutation within a 128B group: 8B block b (0..15) -> ((b&7)<<1)|(b>>3).
// 16B chunk c then holds orig blocks {c, c+8} (k c*8..+8  U  64+c*8..+8).
__device__ __forceinline__ int kperm128(int i) {   // i = byte index
  int b = (i >> 3) & 15;
  int np = ((b & 7) << 1) | (b >> 3);
  return (i & ~127) | (np << 3) | (i & 7);
}

// ---------------- prep: adj -> adj8(fp8 x4096, 128B k-perm) + rowsum (blocks 0..4095)
// ----------------       x -> Xt8[s*32+f][j] fp8 (128B k-perm)
__global__ __launch_bounds__(256) void k_prep(const float* __restrict__ adj,
                                              unsigned char* __restrict__ adj8,
                                              float* __restrict__ rowsum,
                                              const float* __restrict__ x,
                                              unsigned char* __restrict__ Xt8) {
  __shared__ float xl[64][33];
  __shared__ float ps[4];
  int tid = threadIdx.x;
  if (blockIdx.x < 4096) {
    int row = blockIdx.x;
    const float4* src = (const float4*)(adj + (size_t)row * 4096);
    uchar4* dst8 = (uchar4*)(adj8 + (size_t)row * 4096);
    float sum = 0.f;
    #pragma unroll
    for (int q = 0; q < 4; ++q) {
      int idx = q * 256 + tid;              // uchar4 (4B) units
      float4 v = src[idx];
      uchar4 r8;
      r8.x = f2e4m3(v.x * 4096.f); r8.y = f2e4m3(v.y * 4096.f);
      r8.z = f2e4m3(v.z * 4096.f); r8.w = f2e4m3(v.w * 4096.f);
      int b = (idx >> 1) & 15;              // 8B block within 128B group
      int np = ((b & 7) << 1) | (b >> 3);
      int nidx = (idx & ~31) | (np << 1) | (idx & 1);
      dst8[nidx] = r8;
      sum += (v.x + v.y) + (v.z + v.w);
    }
    #pragma unroll
    for (int off = 1; off < 64; off <<= 1) sum += __shfl_xor(sum, off);
    if ((tid & 63) == 0) ps[tid >> 6] = sum;
    __syncthreads();
    if (tid == 0) rowsum[row] = (ps[0] + ps[1]) + (ps[2] + ps[3]);
    return;
  }
  int bs = blockIdx.x - 4096;
  int s = bs >> 6, jb = (bs & 63) << 6;
  const float4* xg = (const float4*)(x + ((size_t)s * NN + jb) * FF);
  #pragma unroll
  for (int ii = 0; ii < 2; ++ii) {
    int idx = tid + ii * 256;
    float4 v = xg[idx];
    int j = idx >> 3, f = (idx & 7) << 2;
    xl[j][f] = v.x; xl[j][f + 1] = v.y; xl[j][f + 2] = v.z; xl[j][f + 3] = v.w;
  }
  __syncthreads();
  int f = tid >> 3, jc = tid & 7;
  unsigned int lo = 0, hi = 0;
  #pragma unroll
  for (int jj = 0; jj < 4; ++jj) lo |= ((unsigned int)f2e4m3(xl[jc * 8 + jj][f])) << (jj * 8);
  #pragma unroll
  for (int jj = 0; jj < 4; ++jj) hi |= ((unsigned int)f2e4m3(xl[jc * 8 + 4 + jj][f])) << (jj * 8);
  uint2 ov; ov.x = lo; ov.y = hi;
  // block b = jc + 8*((jb>>6)&1) within 128B group -> np = (jc<<1)|hi_half
  int np = (jc << 1) | ((jb >> 6) & 1);
  *(uint2*)(Xt8 + (size_t)(s * 32 + f) * 4096 + (jb & ~127) + np * 8) = ov;
}

// =====================================================================
// GEMM-AX fp8, BK=128 (128B rows, 8 chunks): round-6 proven conflict-free
// b128 read shape (chunk lq^(lc&7) and (4+lq)^(lc&7)). 3x48KB buffers,
// 6 gload_lds/stage (128 k), dist-2, vmcnt(6), 1 barrier / 128 k.
// MFMA epilogue -> B2t8 fp8 x2^12, 128B k-perm along i.
// =====================================================================
#define SBAR()   asm volatile("s_barrier" ::: "memory")
#define VMC8()   asm volatile("s_waitcnt vmcnt(8)" ::: "memory")
#define VMC6()   asm volatile("s_waitcnt vmcnt(6)" ::: "memory")
#define VMC0()   asm volatile("s_waitcnt vmcnt(0)" ::: "memory")

__global__ __launch_bounds__(512, 2) void k_gemmAX(
    const unsigned char* __restrict__ A8,
    const unsigned char* __restrict__ B8,
    const float* __restrict__ rowsum,
    const float* __restrict__ W1f,
    const float* __restrict__ b1f,
    const float* __restrict__ W2f,
    const float* __restrict__ b2f,
    unsigned char* __restrict__ B2t8) {
  __shared__ __align__(16) char lds[147456];               // 3 x 48KB
  __shared__ __align__(16) unsigned short w1t[64 * 40];    // W1^T bf16, pad 40
  __shared__ float w2l[128];
  __shared__ float b1l[64];
  __shared__ float b2l[2];
  const int tid = threadIdx.x;
  const int wid = tid >> 6, l = tid & 63;
  const int wr2 = wid >> 2, wc2 = wid & 3;
  const int lc = l & 15, lq = l >> 4;

  {
    float4 v = ((const float4*)W1f)[tid];
    int f = tid >> 4, h = (tid & 15) * 4;
    w1t[(h + 0) * 40 + f] = f2bf(v.x);
    w1t[(h + 1) * 40 + f] = f2bf(v.y);
    w1t[(h + 2) * 40 + f] = f2bf(v.z);
    w1t[(h + 3) * 40 + f] = f2bf(v.w);
  }
  if (tid < 32) *(float4*)&w2l[tid * 4] = ((const float4*)W2f)[tid];
  if (tid < 16) *(float4*)&b1l[tid * 4] = ((const float4*)b1f)[tid];
  if (tid < 2) b2l[tid] = b2f[tid];
  __syncthreads();

  int bid = blockIdx.x;
  int swz = (bid & 7) * 32 + (bid >> 3);
  const int i0 = (swz >> 3) * 128;
  const int c0 = (swz & 7) * 256;

  // fragment-read lane constants (128B rows, 8 chunks, round-6 XOR)
  const int aBase = (wr2 * 64 + lc) * 128;
  const int bBase = 16384 + (wc2 * 64 + lc) * 128;
  const int cLo = ((lq ^ (lc & 7)) << 4);          // orig chunk lq   (kk 0,2)
  const int cHi = (((4 + lq) ^ (lc & 7)) << 4);    // orig chunk lq+4 (kk 1,3)

  // staging: 6 ops x 8KB; op covers 64 rows (8 lanes/row), linear LDS dest
  const int srow = wid * 8 + (l >> 3);             // 0..63
  const int scol = (((l & 7) ^ (srow & 7)) << 4);
  const char* gA = (const char*)A8 + (size_t)(i0 + srow) * 4096 + scol;
  const char* gB = (const char*)B8 + (size_t)(c0 + srow) * 4096 + scol;
  char* ldsW = (char*)lds + wid * 1024;
  const char* ldsR = (const char*)lds;

  f32x4 acc[4][4];
  #pragma unroll
  for (int m = 0; m < 4; ++m)
    #pragma unroll
    for (int n = 0; n < 4; ++n) acc[m][n] = {0.f, 0.f, 0.f, 0.f};

  longx2 afq[4], bfq[4];

#define STAGE6(KT, BOFS) do {                                                        \
    __builtin_amdgcn_global_load_lds((const AS1 void*)(gA + (KT) * 128),             \
        (AS3 void*)(ldsW + (BOFS)), 16, 0, 0);                                       \
    __builtin_amdgcn_global_load_lds((const AS1 void*)(gA + 262144 + (KT) * 128),    \
        (AS3 void*)(ldsW + (BOFS) + 8192), 16, 0, 0);                                \
    __builtin_amdgcn_global_load_lds((const AS1 void*)(gB + (KT) * 128),             \
        (AS3 void*)(ldsW + (BOFS) + 16384), 16, 0, 0);                               \
    __builtin_amdgcn_global_load_lds((const AS1 void*)(gB + 262144 + (KT) * 128),    \
        (AS3 void*)(ldsW + (BOFS) + 24576), 16, 0, 0);                               \
    __builtin_amdgcn_global_load_lds((const AS1 void*)(gB + 524288 + (KT) * 128),    \
        (AS3 void*)(ldsW + (BOFS) + 32768), 16, 0, 0);                               \
    __builtin_amdgcn_global_load_lds((const AS1 void*)(gB + 786432 + (KT) * 128),    \
        (AS3 void*)(ldsW + (BOFS) + 40960), 16, 0, 0);                               \
  } while (0)

#define READ_CH(BOFS, CK) do {                                                       \
    _Pragma("unroll")                                                                \
    for (int _m = 0; _m < 4; ++_m)                                                   \
      afq[_m] = *(const longx2*)(ldsR + (BOFS) + aBase + _m * 2048 + (CK));          \
    _Pragma("unroll")                                                                \
    for (int _n = 0; _n < 4; ++_n)                                                   \
      bfq[_n] = *(const longx2*)(ldsR + (BOFS) + bBase + _n * 2048 + (CK));          \
  } while (0)

#define MFMA2K() do {                                                                \
    __builtin_amdgcn_s_setprio(1);                                                   \
    _Pragma("unroll")                                                                \
    for (int _kk = 0; _kk < 2; ++_kk)                                                \
      _Pragma("unroll")                                                              \
      for (int _m = 0; _m < 4; ++_m)                                                 \
        _Pragma("unroll")                                                            \
        for (int _n = 0; _n < 4; ++_n)                                               \
          acc[_m][_n] = __builtin_amdgcn_mfma_f32_16x16x32_fp8_fp8(                  \
              afq[_m][_kk], bfq[_n][_kk], acc[_m][_n], 0, 0, 0);                     \
    __builtin_amdgcn_s_setprio(0);                                                   \
  } while (0)

  // Prologue: tiles 0,1 -> bufs 0,1 (12 ops); vmcnt(6) completes tile 0.
  STAGE6(0, 0);
  STAGE6(1, 49152);
  VMC6();
  SBAR();

  int bR = 0, bS = 98304;
  for (int kt = 0; kt < 30; ++kt) {
    READ_CH(bR, cLo);
    STAGE6(kt + 2, bS);
    MFMA2K();
    READ_CH(bR, cHi);
    MFMA2K();
    VMC6();                  // tile kt+1 complete (dist-2, 6 ops/tile)
    SBAR();
    bR = (bR == 98304) ? 0 : bR + 49152;
    bS = (bS == 98304) ? 0 : bS + 49152;
  }
  // tail
  READ_CH(bR, cLo); MFMA2K(); READ_CH(bR, cHi); MFMA2K();
  VMC0(); SBAR(); bR = (bR == 98304) ? 0 : bR + 49152;
  READ_CH(bR, cLo); MFMA2K(); READ_CH(bR, cHi); MFMA2K();
  __syncthreads();   // LDS now reusable

  // ---- acc (x 2^-12) -> C1 tile bf16 in LDS [128 rows][264 u16] ----
  unsigned short* C1L = (unsigned short*)lds;
  {
    const int rb = wr2 * 64 + lq * 4;
    const int cbL = wc2 * 64 + lc;
    #pragma unroll
    for (int m = 0; m < 4; ++m)
      #pragma unroll
      for (int r = 0; r < 4; ++r) {
        const int row = rb + m * 16 + r;
        #pragma unroll
        for (int n = 0; n < 4; ++n)
          C1L[row * 264 + cbL + n * 16] = f2bf(acc[m][n][r] * 0.000244140625f);
      }
  }
  __syncthreads();

  // ---- MFMA GCN epilogue; B2t8 = fp8(val * 2^12), 128B k-perm along i ----
  {
    const f32x4 zacc = {0.f, 0.f, 0.f, 0.f};
    bf16x8 bw[4];
    float b1v[4], w2a[4], w2b[4];
    #pragma unroll
    for (int n = 0; n < 4; ++n) {
      const int h = n * 16 + lc;
      bw[n] = *(const bf16x8*)((const char*)w1t + h * 80 + lq * 16);
      b1v[n] = b1l[h];
      w2a[n] = w2l[h * 2];
      w2b[n] = w2l[h * 2 + 1];
    }
    const int rbase = wid * 16 + lq * 4;
    const float4 rs4 = *(const float4*)&rowsum[i0 + rbase];
    const float bo0 = b2l[0], bo1 = b2l[1];
    #pragma unroll
    for (int s = 0; s < 8; ++s) {
      bf16x8 afe = *(const bf16x8*)((const char*)C1L +
                     (wid * 16 + lc) * 528 + s * 64 + lq * 16);
      float o0r[4] = {0.f, 0.f, 0.f, 0.f};
      float o1r[4] = {0.f, 0.f, 0.f, 0.f};
      #pragma unroll
      for (int n = 0; n < 4; ++n) {
        f32x4 hq = __builtin_amdgcn_mfma_f32_16x16x32_bf16(afe, bw[n], zacc, 0, 0, 0);
        #pragma unroll
        for (int r = 0; r < 4; ++r) {
          float hv = hq[r] + rs4[r] * b1v[n];
          hv = hv > 0.f ? hv : 0.f;
          o0r[r] += hv * w2a[n];
          o1r[r] += hv * w2b[n];
        }
      }
      #pragma unroll
      for (int off = 1; off < 16; off <<= 1)
        #pragma unroll
        for (int r = 0; r < 4; ++r) {
          o0r[r] += __shfl_xor(o0r[r], off);
          o1r[r] += __shfl_xor(o1r[r], off);
        }
      if (lc == 0) {
        const int sg = (c0 >> 5) + s;
        #pragma unroll
        for (int r = 0; r < 4; ++r) {
          const int ip = kperm128(i0 + rbase + r);
          B2t8[(size_t)(sg * 2 + 0) * 4096 + ip] = f2e4m3((o0r[r] + bo0) * 4096.f);
          B2t8[(size_t)(sg * 2 + 1) * 4096 + ip] = f2e4m3((o1r[r] + bo1) * 4096.f);
        }
      }
    }
  }
}

// =====================================================================
// GEMM2 fp8 split-K, BK=128: Gp[ks][i][c2] = (adj8 @ B2t8^T) * 2^-24.
// 128x128 tile, 4 waves, K=512 -> 4 tiles of 128; 3x32KB buffers,
// dist-2, vmcnt(8) (8 ops/stage). Same conflict-free read geometry.
// =====================================================================
__global__ __launch_bounds__(256) void k_gemm2f8(
    const unsigned char* __restrict__ A8,
    const unsigned char* __restrict__ B8,
    float* __restrict__ Gp) {
  __shared__ __align__(16) char lds[98304];   // 3 x 32KB
  const int tid = threadIdx.x;
  const int wid = tid >> 6, l = tid & 63;
  const int wr = wid >> 1, wc = wid & 1;
  const int lc = l & 15, lq = l >> 4;
  const int bi = blockIdx.x & 31, ks = blockIdx.x >> 5;
  const int i0 = bi * 128;
  const size_t kbase = (size_t)ks * 512;

  const int aBase = (wr * 64 + lc) * 128;
  const int bBase = 16384 + (wc * 64 + lc) * 128;
  const int cLo = ((lq ^ (lc & 7)) << 4);
  const int cHi = (((4 + lq) ^ (lc & 7)) << 4);

  const int srow = wid * 8 + (l >> 3);          // 0..31
  const int scol = (((l & 7) ^ (srow & 7)) << 4);
  const char* gA = (const char*)A8 + (size_t)(i0 + srow) * 4096 + kbase + scol;
  const char* gB = (const char*)B8 + (size_t)srow * 4096 + kbase + scol;
  char* ldsW = (char*)lds + wid * 1024;
  const char* ldsR = (const char*)lds;

  f32x4 acc[4][4];
  #pragma unroll
  for (int m = 0; m < 4; ++m)
    #pragma unroll
    for (int n = 0; n < 4; ++n) acc[m][n] = {0.f, 0.f, 0.f, 0.f};

  longx2 afq[4], bfq[4];

#define G2STAGE(KT, BOFS) do {                                                       \
    __builtin_amdgcn_global_load_lds((const AS1 void*)(gA + (KT) * 128),             \
        (AS3 void*)(ldsW + (BOFS)), 16, 0, 0);                                       \
    __builtin_amdgcn_global_load_lds((const AS1 void*)(gA + 131072 + (KT) * 128),    \
        (AS3 void*)(ldsW + (BOFS) + 4096), 16, 0, 0);                                \
    __builtin_amdgcn_global_load_lds((const AS1 void*)(gA + 262144 + (KT) * 128),    \
        (AS3 void*)(ldsW + (BOFS) + 8192), 16, 0, 0);                                \
    __builtin_amdgcn_global_load_lds((const AS1 void*)(gA + 393216 + (KT) * 128),    \
        (AS3 void*)(ldsW + (BOFS) + 12288), 16, 0, 0);                               \
    __builtin_amdgcn_global_load_lds((const AS1 void*)(gB + (KT) * 128),             \
        (AS3 void*)(ldsW + (BOFS) + 16384), 16, 0, 0);                               \
    __builtin_amdgcn_global_load_lds((const AS1 void*)(gB + 131072 + (KT) * 128),    \
        (AS3 void*)(ldsW + (BOFS) + 20480), 16, 0, 0);                               \
    __builtin_amdgcn_global_load_lds((const AS1 void*)(gB + 262144 + (KT) * 128),    \
        (AS3 void*)(ldsW + (BOFS) + 24576), 16, 0, 0);                               \
    __builtin_amdgcn_global_load_lds((const AS1 void*)(gB + 393216 + (KT) * 128),    \
        (AS3 void*)(ldsW + (BOFS) + 28672), 16, 0, 0);                               \
  } while (0)

#define G2READ(BOFS, CK) do {                                                        \
    _Pragma("unroll")                                                                \
    for (int _m = 0; _m < 4; ++_m)                                                   \
      afq[_m] = *(const longx2*)(ldsR + (BOFS) + aBase + _m * 2048 + (CK));          \
    _Pragma("unroll")                                                                \
    for (int _n = 0; _n < 4; ++_n)                                                   \
      bfq[_n] = *(const longx2*)(ldsR + (BOFS) + bBase + _n * 2048 + (CK));          \
  } while (0)

#define G2MFMA() do {                                                                \
    __builtin_amdgcn_s_setprio(1);                                                   \
    _Pragma("unroll")                                                                \
    for (int _kk = 0; _kk < 2; ++_kk)                                                \
      _Pragma("unroll")                                                              \
      for (int _m = 0; _m < 4; ++_m)                                                 \
        _Pragma("unroll")                                                            \
        for (int _n = 0; _n < 4; ++_n)                                               \
          acc[_m][_n] = __builtin_amdgcn_mfma_f32_16x16x32_fp8_fp8(                  \
              afq[_m][_kk], bfq[_n][_kk], acc[_m][_n], 0, 0, 0);                     \
    __builtin_amdgcn_s_setprio(0);                                                   \
  } while (0)

  G2STAGE(0, 0);
  G2STAGE(1, 32768);
  VMC8();
  SBAR();

  // kt=0: read t0(buf0), stage t2(buf2)
  G2READ(0, cLo); G2STAGE(2, 65536); G2MFMA(); G2READ(0, cHi); G2MFMA();
  VMC8(); SBAR();
  // kt=1: read t1(buf1), stage t3(buf0)
  G2READ(32768, cLo); G2STAGE(3, 0); G2MFMA(); G2READ(32768, cHi); G2MFMA();
  VMC8(); SBAR();
  // kt=2: read t2(buf2)
  G2READ(65536, cLo); G2MFMA(); G2READ(65536, cHi); G2MFMA();
  VMC0(); SBAR();
  // kt=3: read t3(buf0)
  G2READ(0, cLo); G2MFMA(); G2READ(0, cHi); G2MFMA();

  float* outp = Gp + (size_t)ks * 524288;
  const int rbase = i0 + wr * 64 + lq * 4;
  const int cbase = wc * 64 + lc;
  #pragma unroll
  for (int m = 0; m < 4; ++m)
    #pragma unroll
    for (int n = 0; n < 4; ++n)
      #pragma unroll
      for (int r = 0; r < 4; ++r)
        outp[(size_t)(rbase + m * 16 + r) * 128 + cbase + n * 16] =
            acc[m][n][r] * 5.9604644775390625e-8f;   // 2^-24
}

// ---------------- reduce split-K + log_softmax -> R[s][i*2+o] f32 ----------------
__global__ __launch_bounds__(256) void k_lsm(const float* __restrict__ Gp,
                                             float* __restrict__ Rm) {
  __shared__ float Gacc[32][130];
  int i0 = blockIdx.x * 32;
  int tid = threadIdx.x;
  float4 v[4];
  #pragma unroll
  for (int i = 0; i < 4; ++i) v[i] = {0.f, 0.f, 0.f, 0.f};
  for (int ks = 0; ks < 8; ++ks) {
    const float4* gp4 = ((const float4*)Gp) + (size_t)ks * 131072 + (size_t)i0 * 32;
    #pragma unroll
    for (int i = 0; i < 4; ++i) {
      float4 t = gp4[tid + i * 256];
      v[i].x += t.x; v[i].y += t.y; v[i].z += t.z; v[i].w += t.w;
    }
  }
  #pragma unroll
  for (int i = 0; i < 4; ++i) {
    int f4i = tid + i * 256, row = f4i >> 5, c = (f4i & 31) * 4;
    Gacc[row][c] = v[i].x; Gacc[row][c + 1] = v[i].y;
    Gacc[row][c + 2] = v[i].z; Gacc[row][c + 3] = v[i].w;
  }
  __syncthreads();
  #pragma unroll
  for (int j = 0; j < 8; ++j) {
    int p = j * 256 + tid;
    int ii = p & 31, s = p >> 5;
    float g0 = Gacc[ii][s * 2], g1 = Gacc[ii][s * 2 + 1];
    float m = fmaxf(g0, g1);
    float lse = m + logf(expf(g0 - m) + expf(g1 - m));
    float2 o_; o_.x = g0 - lse; o_.y = g1 - lse;
    *((float2*)(Rm + (size_t)s * 8192 + (size_t)(i0 + ii) * 2)) = o_;
  }
}

// ---------------- gi0 partial: part[ks][t][g] = R[t] . Wih0[g] over c-range ----------------
__global__ __launch_bounds__(256) void k_gi0(const float* __restrict__ Rm,
                                             const float* __restrict__ Wih0,
                                             float* __restrict__ part) {
  __shared__ float4 Wl[4 * 128];
  int gb = blockIdx.x % 48, ks = blockIdx.x / 48;
  int c0 = ks * 512;
  int tid = threadIdx.x;
  #pragma unroll
  for (int i = 0; i < 2; ++i) {
    int idx = tid + i * 256;
    int g = idx >> 7, c4 = idx & 127;
    Wl[g * 128 + c4] = ((const float4*)(Wih0 + (size_t)(gb * 4 + g) * 8192 + c0))[c4];
  }
  __syncthreads();
  int w = tid >> 6, lane = tid & 63;
  for (int pass = 0; pass < 16; ++pass) {
    int t = pass * 4 + w;
    float a0 = 0.f, a1 = 0.f, a2 = 0.f, a3 = 0.f;
    const float4* rg = (const float4*)(Rm + (size_t)t * 8192 + c0);
    #pragma unroll
    for (int i = 0; i < 2; ++i) {
      int c4 = i * 64 + lane;
      float4 r4 = rg[c4];
      float4 w0 = Wl[c4], w1 = Wl[128 + c4], w2 = Wl[256 + c4], w3 = Wl[384 + c4];
      a0 += r4.x * w0.x + r4.y * w0.y + r4.z * w0.z + r4.w * w0.w;
      a1 += r4.x * w1.x + r4.y * w1.y + r4.z * w1.z + r4.w * w1.w;
      a2 += r4.x * w2.x + r4.y * w2.y + r4.z * w2.z + r4.w * w2.w;
      a3 += r4.x * w3.x + r4.y * w3.y + r4.z * w3.z + r4.w * w3.w;
    }
    #pragma unroll
    for (int off = 1; off < 64; off <<= 1) {
      a0 += __shfl_xor(a0, off);
      a1 += __shfl_xor(a1, off);
      a2 += __shfl_xor(a2, off);
      a3 += __shfl_xor(a3, off);
    }
    if (lane == 0) {
      float4 o_; o_.x = a0; o_.y = a1; o_.z = a2; o_.w = a3;
      *((float4*)(part + ((size_t)ks * 64 + t) * 192 + gb * 4)) = o_;
    }
  }
}

__global__ __launch_bounds__(256) void k_gi0red(const float* __restrict__ part,
                                                const float* __restrict__ bih0,
                                                float* __restrict__ gi0) {
  int idx = blockIdx.x * 256 + threadIdx.x;
  if (idx < 12288) {
    float s_ = bih0[idx % 192];
    for (int ks = 0; ks < 16; ++ks) s_ += part[ks * 12288 + idx];
    gi0[idx] = s_;
  }
}

// =====================================================================
// MFMA GRU (unchanged — proven round 6)
// =====================================================================
__device__ __forceinline__ float fsigm(float x) {
  return __builtin_amdgcn_rcpf(1.f + __expf(-x));
}
__device__ __forceinline__ float ftanh(float x) {
  return 1.f - 2.f * __builtin_amdgcn_rcpf(1.f + __expf(2.f * x));
}

__global__ __launch_bounds__(384) void k_gru(const float* __restrict__ gi0,
                                             const float* __restrict__ Whh0,
                                             const float* __restrict__ bhh0,
                                             const float* __restrict__ Wih1,
                                             const float* __restrict__ Whh1,
                                             const float* __restrict__ bih1,
                                             const float* __restrict__ bhh1,
                                             float* __restrict__ out) {
  __shared__ float gil[64][192];
  __shared__ float gout[576];
  __shared__ __align__(16) unsigned short hv[2][64];
  const int tid = threadIdx.x;
  const int w = tid >> 6, l = tid & 63;
  const int matw = w >> 1, half = w & 1;
  const float* Wm = (matw == 0) ? Whh0 : (matw == 1 ? Wih1 : Whh1);
  const int mi = (matw == 2) ? 1 : 0;

  bf16x8 afr[6][2];
  #pragma unroll
  for (int rbi = 0; rbi < 6; ++rbi) {
    int g = (half * 6 + rbi) * 16 + (l & 15);
    #pragma unroll
    for (int kh = 0; kh < 2; ++kh) {
      int k0 = kh * 32 + (l >> 4) * 8;
      const float4* src = (const float4*)(Wm + (size_t)g * 64 + k0);
      float4 v0 = src[0], v1 = src[1];
      bf16x8 a;
      a[0] = (short)f2bf(v0.x); a[1] = (short)f2bf(v0.y);
      a[2] = (short)f2bf(v0.z); a[3] = (short)f2bf(v0.w);
      a[4] = (short)f2bf(v1.x); a[5] = (short)f2bf(v1.y);
      a[6] = (short)f2bf(v1.z); a[7] = (short)f2bf(v1.w);
      afr[rbi][kh] = a;
    }
  }
  {
    float4* gf = (float4*)&gil[0][0];
    const float4* gs = (const float4*)gi0;
    #pragma unroll
    for (int i = 0; i < 8; ++i) gf[i * 384 + tid] = gs[i * 384 + tid];
  }
  if (tid < 128) hv[tid >> 6][tid & 63] = 0;

  float hreg = 0.f;
  float bR = 0.f, bZ = 0.f, bNa = 0.f, bNb = 0.f;
  if (tid < 64) {
    bR = bhh0[tid]; bZ = bhh0[64 + tid]; bNa = bhh0[128 + tid];
  } else if (tid < 128) {
    int g = tid - 64;
    bR = bih1[g] + bhh1[g];
    bZ = bih1[64 + g] + bhh1[64 + g];
    bNa = bih1[128 + g];
    bNb = bhh1[128 + g];
  }
  asm volatile("s_waitcnt lgkmcnt(0)\n\ts_barrier" ::: "memory");

  const int gwb = matw * 192 + half * 96 + (l >> 4) * 4;
  const f32x4 zacc = {0.f, 0.f, 0.f, 0.f};

  for (int i = 0; i <= 64; ++i) {
    bf16x8 b0 = *(const bf16x8*)&hv[mi][(l >> 4) * 8];
    bf16x8 b1 = *(const bf16x8*)&hv[mi][32 + (l >> 4) * 8];
    #pragma unroll
    for (int rbi = 0; rbi < 6; ++rbi) {
      f32x4 a_ = __builtin_amdgcn_mfma_f32_16x16x32_bf16(afr[rbi][0], b0, zacc, 0, 0, 0);
      a_ = __builtin_amdgcn_mfma_f32_16x16x32_bf16(afr[rbi][1], b1, a_, 0, 0, 0);
      if (!(l & 15)) *(f32x4*)&gout[gwb + rbi * 16] = a_;
    }
    asm volatile("s_waitcnt lgkmcnt(0)\n\ts_barrier" ::: "memory");
    if (tid < 64) {
      if (i < 64) {
        float r = fsigm(gil[i][tid] + gout[tid] + bR);
        float z = fsigm(gil[i][64 + tid] + gout[64 + tid] + bZ);
        float n = ftanh(gil[i][128 + tid] + r * (gout[128 + tid] + bNa));
        hreg = (1.f - z) * n + z * hreg;
        hv[0][tid] = f2bf(hreg);
      }
    } else if (tid < 128 && i > 0) {
      int g = tid - 64;
      float r = fsigm(gout[192 + g] + gout[384 + g] + bR);
      float z = fsigm(gout[256 + g] + gout[448 + g] + bZ);
      float n = ftanh((gout[320 + g] + bNa) + r * (gout[512 + g] + bNb));
      hreg = (1.f - z) * n + z * hreg;
      hv[1][g] = f2bf(hreg);
      out[(i - 1) * 64 + g] = hreg;
    }
    asm volatile("s_waitcnt lgkmcnt(0)\n\ts_barrier" ::: "memory");
  }
  if (tid < 64) out[4096 + tid] = hreg;
  else if (tid < 128) out[4096 + 64 + (tid - 64)] = hreg;
}

extern "C" void kernel_launch(void* const* d_in, const int* in_sizes, int n_in,
                              void* d_out, int out_size, void* d_ws, size_t ws_size,
                              hipStream_t stream) {
  const float* x    = (const float*)d_in[0];
  const float* adj  = (const float*)d_in[1];
  const float* W1   = (const float*)d_in[2];
  const float* b1   = (const float*)d_in[3];
  const float* W2   = (const float*)d_in[4];
  const float* b2   = (const float*)d_in[5];
  const float* Wih0 = (const float*)d_in[6];
  const float* Whh0 = (const float*)d_in[7];
  const float* bih0 = (const float*)d_in[8];
  const float* bhh0 = (const float*)d_in[9];
  const float* Wih1 = (const float*)d_in[10];
  const float* Whh1 = (const float*)d_in[11];
  const float* bih1 = (const float*)d_in[12];
  const float* bhh1 = (const float*)d_in[13];
  float* out = (float*)d_out;

  char* ws = (char*)d_ws;
  unsigned char* adj8  = (unsigned char*)ws;                       // 16.78MB (fp8 x2^12, 128B k-perm)
  unsigned char* Xt8   = (unsigned char*)(ws + 16777216);          // 8.39MB  (fp8, 128B k-perm)
  float* rowsum        = (float*)(ws + 25165824);                  // 16KB
  float* Gp            = (float*)(ws + 25182208);                  // 16.78MB
  float* Rm            = (float*)(ws + 41959424);                  // 2MB
  float* part          = (float*)(ws + 44056576);                  // 768KB
  float* gi0           = (float*)(ws + 44843008);                  // 48KB
  unsigned char* B2t8  = (unsigned char*)(ws + 44892160);          // 512KB (fp8 x2^12, 128B k-perm)

  k_prep<<<8192, 256, 0, stream>>>(adj, adj8, rowsum, x, Xt8);
  k_gemmAX<<<256, 512, 0, stream>>>(adj8, Xt8, rowsum, W1, b1, W2, b2, B2t8);
  k_gemm2f8<<<256, 256, 0, stream>>>(adj8, B2t8, Gp);
  k_lsm<<<128, 256, 0, stream>>>(Gp, Rm);
  k_gi0<<<768, 256, 0, stream>>>(Rm, Wih0, part);
  k_gi0red<<<48, 256, 0, stream>>>(part, bih0, gi0);
  k_gru<<<1, 384, 0, stream>>>(gi0, Whh0, bhh0, Wih1, Whh1, bih1, bhh1, out);
}